// Round 13
// baseline (74.876 us; speedup 1.0000x reference)
//
#include <hip/hip_runtime.h>

// Problem constants (match reference)
#define HWPX (512*512)      // pixels per batch
#define NB 2                // batches
#define NL 512              // EH*EW light directions (table rows)
#define NLS 480             // shadeable lights: phi=0 row (32 dirs) has coeff sin(0)=0
#define NPAIR 240           // light pairs
#define GPAIR 60            // pairs per wave-group (4 groups)
#define PXPT 4              // pixels per thread
#define NBLK 2048           // k_fused grid
constexpr float PI_F = 3.14159265358979323846f;
constexpr float INV_SQRT2 = 0.70710678118654752f;

typedef float f2 __attribute__((ext_vector_type(2)));

// ws layout (bytes):
//   [0]      float scale : (1/gmax64), written by k_gmax
//   [256]    float tabq[2][240][12] : LIGHT-PAIRED table:
//            {hx0,hx1, hy0,hy1, hz0,hz1, e00,e01, e10,e11, e20,e21}
//   [32768]  float blockmax[2048] : per-block max of r64 (plain stores, no atomics)
//
// Identities:
//  * (relu(s)/max)^64 == relu(s)^64 * (1/max)^64, |s|<=1 -> accumulate
//    UNNORMALIZED, and since x^64 is monotone on [0,1], track the max in the
//    r64 domain: gmax64 = max over all relu(s)^64. finalize multiplies by
//    1/gmax64. No pow in finalize, no atomics anywhere.
//  * phi=0 row: coeff==0 -> only matters for the max; h=(0,r2,r2) ->
//    s=relu((ny+nz)*r2), seeded via one-time ^64.
//
// R12 change: R4-R11 all showed wall = busy + ~17us regardless of mix and
// occupancy. Suspect: 2048 lockstep same-cacheline atomicMax ops draining
// serially at dispatch end. This round: per-block max -> distinct slots
// (plain store), tiny k_gmax (1 block) reduces 2048 and emits the scale.

__global__ void k_setup(const float* __restrict__ env,
                        float* __restrict__ tabq) {
    int m = threadIdx.x;            // 512 threads, one per light dir
    int p = m >> 5;                 // phi index (EH=16)
    int t = m & 31;                 // theta index (EW=32)
    if (p < 1) return;              // phi=0: zero coeff, handled analytically
    float phi = (float)p * (PI_F / 16.0f);
    float th  = (float)t * (2.0f * PI_F / 32.0f);
    float sp = sinf(phi), cp = cosf(phi);
    float st = sinf(th),  ct = cosf(th);
    // l = (st*sp, cp, -ct*sp); h = l + view(0,0,1), normalized
    float hx = st * sp;
    float hy = cp;
    float hz = 1.0f - ct * sp;
    float inv = rsqrtf(hx * hx + hy * hy + hz * hz);
    hx *= inv; hy *= inv; hz *= inv;
    float c = sp * (1.0f / 60.0f);  // solid-angle coeff and the /60 folded in
    int ms = m - 32;                // shadeable index 0..479
    int j = ms >> 1;                // pair index (pairs never straddle groups)
    int slot = ms & 1;
    #pragma unroll
    for (int b = 0; b < NB; ++b) {
        const float* e = env + ((size_t)(b * NL + m)) * 3;
        float* dst = tabq + ((size_t)(b * NPAIR + j)) * 12 + slot;
        dst[0]  = hx;
        dst[2]  = hy;
        dst[4]  = hz;
        dst[6]  = e[0] * c;
        dst[8]  = e[1] * c;
        dst[10] = e[2] * c;
    }
}

__device__ __forceinline__ void load_normal(const float* __restrict__ normal, size_t pix,
                                            float& nx, float& ny, float& nz) {
    const float* p = normal + pix * 3;
    float c0 = p[0], c1 = p[1], c2 = p[2];
    // channel-reversed, [0,1] -> [-1,1], L2 normalize
    float x = (c2 - 0.5f) * 2.0f;
    float y = (c1 - 0.5f) * 2.0f;
    float z = (c0 - 0.5f) * 2.0f;
    float d2 = x * x + y * y + z * z;
    float inv = d2 > 0.0f ? rsqrtf(d2) : 0.0f;
    nx = x * inv; ny = y * inv; nz = z * inv;
}

__device__ __forceinline__ float pow64(float r) {
    float r2  = r * r;
    float r4  = r2 * r2;
    float r8  = r4 * r4;
    float r16 = r8 * r8;
    float r32 = r16 * r16;
    return r32 * r32;
}

// 256 threads = 4 waves; wave g handles light pairs [g*60,(g+1)*60) for the
// SAME 64x4 pixels. 2048 blocks.
__global__ __launch_bounds__(256) void k_fused(const float* __restrict__ normal,
                                               const float* __restrict__ tabq,
                                               float* __restrict__ out,
                                               float* __restrict__ blockmax) {
    __shared__ float smem[NPAIR * 12];             // 11.25KB table; merge aliases it
    __shared__ float swmax[4];                     // per-wave partial max (r64 domain)

    int tid = threadIdx.x;
    int bid = blockIdx.x;
    int bpb = HWPX / 256;                          // 1024 blocks per batch
    int b = bid / bpb;
    int g = tid >> 6;                              // wave-group = light quarter
    int li = tid & 63;                             // pixel lane
    int base_in_b = (bid % bpb) * 256 + li;

    // stage light table: 720 float4s, coalesced
    {
        const float4* gp = reinterpret_cast<const float4*>(tabq + (size_t)b * NPAIR * 12);
        float4* sp4 = reinterpret_cast<float4*>(smem);
        sp4[tid]       = gp[tid];
        sp4[tid + 256] = gp[tid + 256];
        if (tid < 208) sp4[tid + 512] = gp[tid + 512];
    }

    // load 4 normals; hoist f2 splats (loop-invariant)
    float nxs[PXPT], nys[PXPT], nzs[PXPT];
    #pragma unroll
    for (int k = 0; k < PXPT; ++k)
        load_normal(normal, (size_t)b * HWPX + base_in_b + k * 64,
                    nxs[k], nys[k], nzs[k]);
    f2 nx2[PXPT], ny2[PXPT], nz2[PXPT];
    #pragma unroll
    for (int k = 0; k < PXPT; ++k) {
        nx2[k] = f2{nxs[k], nxs[k]};
        ny2[k] = f2{nys[k], nys[k]};
        nz2[k] = f2{nzs[k], nzs[k]};
    }

    // phi=0 light max seed (group 0 only), in r64 domain
    float mx64 = 0.0f;
    if (g == 0) {
        #pragma unroll
        for (int k = 0; k < PXPT; ++k) {
            float s0 = fmaxf((nys[k] + nzs[k]) * INV_SQRT2, 0.0f);
            mx64 = fmaxf(mx64, pow64(s0));
        }
    }

    __syncthreads();

    f2 a0[PXPT], a1[PXPT], a2[PXPT];               // per-px, per-light-slot partials
    #pragma unroll
    for (int k = 0; k < PXPT; ++k) { a0[k] = f2{0,0}; a1[k] = f2{0,0}; a2[k] = f2{0,0}; }

    const float4* Tg = reinterpret_cast<const float4*>(smem) + (size_t)g * (GPAIR * 3);
    #pragma unroll 4
    for (int j = 0; j < GPAIR; ++j) {
        float4 A = Tg[j * 3 + 0];                  // {hx0,hx1,hy0,hy1}
        float4 B = Tg[j * 3 + 1];                  // {hz0,hz1,e00,e01}
        float4 C = Tg[j * 3 + 2];                  // {e10,e11,e20,e21}
        f2 hx2 = {A.x, A.y}, hy2 = {A.z, A.w}, hz2 = {B.x, B.y};
        f2 e02 = {B.z, B.w}, e12 = {C.x, C.y}, e22 = {C.z, C.w};

        #pragma unroll
        for (int k = 0; k < PXPT; ++k) {
            f2 s = __builtin_elementwise_fma(nx2[k], hx2,
                   __builtin_elementwise_fma(ny2[k], hy2, nz2[k] * hz2));
            float sx = fmaxf(s.x, 0.0f);           // relu
            float sy = fmaxf(s.y, 0.0f);
            f2 r = {sx, sy};
            f2 r2  = r * r;
            f2 r4  = r2 * r2;
            f2 r8  = r4 * r4;
            f2 r16 = r8 * r8;
            f2 r32 = r16 * r16;
            f2 r64 = r32 * r32;
            mx64 = fmaxf(mx64, fmaxf(r64.x, r64.y));   // v_max3, r64 domain
            a0[k] = __builtin_elementwise_fma(r64, e02, a0[k]);
            a1[k] = __builtin_elementwise_fma(r64, e12, a1[k]);
            a2[k] = __builtin_elementwise_fma(r64, e22, a2[k]);
        }
    }

    // collapse light-slot halves
    float b0[PXPT], b1[PXPT], b2[PXPT];
    #pragma unroll
    for (int k = 0; k < PXPT; ++k) {
        b0[k] = a0[k].x + a0[k].y;
        b1[k] = a1[k].x + a1[k].y;
        b2[k] = a2[k].x + a2[k].y;
    }

    // wave-64 max reduce (r64 domain)
    #pragma unroll
    for (int off = 32; off > 0; off >>= 1)
        mx64 = fmaxf(mx64, __shfl_xor(mx64, off));
    if (li == 0) swmax[g] = mx64;

    __syncthreads();   // all table reads done; smem now reusable as merge buffer

    // groups 1..3 deposit partials: stride 13 dwords (odd -> conflict-free)
    if (g > 0) {
        float* dst = smem + (size_t)(g - 1) * (64 * 13) + li * 13;
        #pragma unroll
        for (int k = 0; k < PXPT; ++k) {
            dst[k]     = b0[k];
            dst[k + 4] = b1[k];
            dst[k + 8] = b2[k];
        }
    }
    __syncthreads();

    if (tid == 0) {
        float bm = fmaxf(fmaxf(swmax[0], swmax[1]), fmaxf(swmax[2], swmax[3]));
        blockmax[bid] = bm;                        // plain store, distinct slot
    }

    if (g == 0) {
        #pragma unroll
        for (int gg = 0; gg < 3; ++gg) {
            const float* src = smem + (size_t)gg * (64 * 13) + li * 13;
            #pragma unroll
            for (int k = 0; k < PXPT; ++k) {
                b0[k] += src[k];
                b1[k] += src[k + 4];
                b2[k] += src[k + 8];
            }
        }
        // unnormalized sums to out[b][c][h][w]; finalize scales by 1/gmax64
        float* ob = out + (size_t)b * 3 * HWPX;
        #pragma unroll
        for (int k = 0; k < PXPT; ++k) {
            int p = base_in_b + k * 64;
            ob[0 * HWPX + p] = b0[k];
            ob[1 * HWPX + p] = b1[k];
            ob[2 * HWPX + p] = b2[k];
        }
    }
}

// 1 block: reduce 2048 block-maxes -> scale = 1/gmax64
__global__ __launch_bounds__(256) void k_gmax(const float* __restrict__ blockmax,
                                              float* __restrict__ scale) {
    __shared__ float sm[4];
    int t = threadIdx.x;
    float m = 0.0f;
    #pragma unroll
    for (int i = 0; i < NBLK / 256; ++i)
        m = fmaxf(m, blockmax[t + i * 256]);
    #pragma unroll
    for (int off = 32; off > 0; off >>= 1)
        m = fmaxf(m, __shfl_xor(m, off));
    if ((t & 63) == 0) sm[t >> 6] = m;
    __syncthreads();
    if (t == 0) {
        m = fmaxf(fmaxf(sm[0], sm[1]), fmaxf(sm[2], sm[3]));
        *scale = 1.0f / m;                         // 1/gmax64
    }
}

__global__ __launch_bounds__(256) void k_finalize(float* __restrict__ out,
                                                  const float* __restrict__ scale) {
    float scl = *scale;                             // uniform scalar load
    int i = blockIdx.x * 256 + (int)threadIdx.x;    // over float4s
    float4* o = reinterpret_cast<float4*>(out);
    float4 v = o[i];
    v.x *= scl; v.y *= scl; v.z *= scl; v.w *= scl;
    o[i] = v;
}

extern "C" void kernel_launch(void* const* d_in, const int* in_sizes, int n_in,
                              void* d_out, int out_size, void* d_ws, size_t ws_size,
                              hipStream_t stream) {
    const float* env    = (const float*)d_in[0];   // (B,16,32,3) f32
    const float* normal = (const float*)d_in[1];   // (B,512,512,3) f32
    float* out = (float*)d_out;                    // (B,3,512,512) f32

    char* ws = (char*)d_ws;
    float* scale = (float*)ws;
    float* tabq = (float*)(ws + 256);
    float* blockmax = (float*)(ws + 32768);

    int fblocks = (NB * 3 * HWPX) / (4 * 256);     // 1536 (float4 granularity)

    hipLaunchKernelGGL(k_setup, dim3(1), dim3(NL), 0, stream, env, tabq);
    hipLaunchKernelGGL(k_fused, dim3(NBLK), dim3(256), 0, stream, normal, tabq, out, blockmax);
    hipLaunchKernelGGL(k_gmax, dim3(1), dim3(256), 0, stream, blockmax, scale);
    hipLaunchKernelGGL(k_finalize, dim3(fblocks), dim3(256), 0, stream, out, scale);
}

// Round 14
// 73.854 us; speedup vs baseline: 1.0138x; 1.0138x over previous
//
#include <hip/hip_runtime.h>

// Problem constants (match reference)
#define HWPX (512*512)      // pixels per batch
#define NB 2                // batches
#define NL 512              // EH*EW light directions (table rows)
#define NLS 480             // shadeable lights: phi=0 row (32 dirs) has coeff sin(0)=0
#define NPAIR 240           // light pairs
#define GPAIR 60            // pairs per wave-group (4 groups)
#define PXPT 4              // pixels per thread
#define NBLK 2048           // k_fused grid
constexpr float PI_F = 3.14159265358979323846f;
constexpr float INV_SQRT2 = 0.70710678118654752f;

typedef float f2 __attribute__((ext_vector_type(2)));

// ws layout (bytes):
//   [0]      float scale : (1/gmax64), written by k_gmax
//   [256]    float tabq[2][240][12] : LIGHT-PAIRED table:
//            {hx0,hx1, hy0,hy1, hz0,hz1, e00,e01, e10,e11, e20,e21}
//   [32768]  float blockmax[2048] : per-block max of r64 (plain stores)
//
// Identities:
//  * (relu(s)/max)^64 == relu(s)^64 * (1/max)^64, |s|<=1 -> accumulate
//    UNNORMALIZED; x^64 monotone on [0,1] -> track max in r64 domain;
//    finalize multiplies by 1/gmax64.
//  * phi=0 row: coeff==0 -> only matters for max; h=(0,r2,r2) ->
//    s=relu((ny+nz)*r2), seeded via one-time ^64.
//
// R13 change: the table base depends only on (batch, wave-group) -> force it
// wave-uniform via readfirstlane so table reads go through the SCALAR pipe
// (s_load, K$-resident 12KB) instead of LDS. No staging, no ds_read in the
// hot loop, 1 barrier instead of 3. VOP3P ops take the 64-bit SGPR pairs
// directly as the single scalar operand.

__global__ void k_setup(const float* __restrict__ env,
                        float* __restrict__ tabq) {
    int m = threadIdx.x;            // 512 threads, one per light dir
    int p = m >> 5;                 // phi index (EH=16)
    int t = m & 31;                 // theta index (EW=32)
    if (p < 1) return;              // phi=0: zero coeff, handled analytically
    float phi = (float)p * (PI_F / 16.0f);
    float th  = (float)t * (2.0f * PI_F / 32.0f);
    float sp = sinf(phi), cp = cosf(phi);
    float st = sinf(th),  ct = cosf(th);
    // l = (st*sp, cp, -ct*sp); h = l + view(0,0,1), normalized
    float hx = st * sp;
    float hy = cp;
    float hz = 1.0f - ct * sp;
    float inv = rsqrtf(hx * hx + hy * hy + hz * hz);
    hx *= inv; hy *= inv; hz *= inv;
    float c = sp * (1.0f / 60.0f);  // solid-angle coeff and the /60 folded in
    int ms = m - 32;                // shadeable index 0..479
    int j = ms >> 1;                // pair index (pairs never straddle groups)
    int slot = ms & 1;
    #pragma unroll
    for (int b = 0; b < NB; ++b) {
        const float* e = env + ((size_t)(b * NL + m)) * 3;
        float* dst = tabq + ((size_t)(b * NPAIR + j)) * 12 + slot;
        dst[0]  = hx;
        dst[2]  = hy;
        dst[4]  = hz;
        dst[6]  = e[0] * c;
        dst[8]  = e[1] * c;
        dst[10] = e[2] * c;
    }
}

__device__ __forceinline__ void load_normal(const float* __restrict__ normal, size_t pix,
                                            float& nx, float& ny, float& nz) {
    const float* p = normal + pix * 3;
    float c0 = p[0], c1 = p[1], c2 = p[2];
    // channel-reversed, [0,1] -> [-1,1], L2 normalize
    float x = (c2 - 0.5f) * 2.0f;
    float y = (c1 - 0.5f) * 2.0f;
    float z = (c0 - 0.5f) * 2.0f;
    float d2 = x * x + y * y + z * z;
    float inv = d2 > 0.0f ? rsqrtf(d2) : 0.0f;
    nx = x * inv; ny = y * inv; nz = z * inv;
}

__device__ __forceinline__ float pow64(float r) {
    float r2  = r * r;
    float r4  = r2 * r2;
    float r8  = r4 * r4;
    float r16 = r8 * r8;
    float r32 = r16 * r16;
    return r32 * r32;
}

// 256 threads = 4 waves; wave g handles light pairs [g*60,(g+1)*60) for the
// SAME 64x4 pixels. 2048 blocks.
__global__ __launch_bounds__(256) void k_fused(const float* __restrict__ normal,
                                               const float* __restrict__ tabq,
                                               float* __restrict__ out,
                                               float* __restrict__ blockmax) {
    __shared__ float smerge[3 * 64 * 13];          // ~10KB merge buffer
    __shared__ float swmax[4];                     // per-wave partial max (r64 domain)

    int tid = threadIdx.x;
    int bid = blockIdx.x;
    int bpb = HWPX / 256;                          // 1024 blocks per batch
    int b = bid / bpb;
    int g = tid >> 6;                              // wave-group = light quarter
    int li = tid & 63;                             // pixel lane
    int base_in_b = (bid % bpb) * 256 + li;

    // wave-uniform table base -> SGPR -> scalar loads (s_load) in the loop
    int toff = __builtin_amdgcn_readfirstlane((b * NPAIR + g * GPAIR) * 12);
    const float* Tw = tabq + toff;

    // load 4 normals; hoist f2 splats (loop-invariant)
    float nxs[PXPT], nys[PXPT], nzs[PXPT];
    #pragma unroll
    for (int k = 0; k < PXPT; ++k)
        load_normal(normal, (size_t)b * HWPX + base_in_b + k * 64,
                    nxs[k], nys[k], nzs[k]);
    f2 nx2[PXPT], ny2[PXPT], nz2[PXPT];
    #pragma unroll
    for (int k = 0; k < PXPT; ++k) {
        nx2[k] = f2{nxs[k], nxs[k]};
        ny2[k] = f2{nys[k], nys[k]};
        nz2[k] = f2{nzs[k], nzs[k]};
    }

    // phi=0 light max seed (group 0 only), in r64 domain
    float mx64 = 0.0f;
    if (g == 0) {
        #pragma unroll
        for (int k = 0; k < PXPT; ++k) {
            float s0 = fmaxf((nys[k] + nzs[k]) * INV_SQRT2, 0.0f);
            mx64 = fmaxf(mx64, pow64(s0));
        }
    }

    f2 a0[PXPT], a1[PXPT], a2[PXPT];               // per-px, per-light-slot partials
    #pragma unroll
    for (int k = 0; k < PXPT; ++k) { a0[k] = f2{0,0}; a1[k] = f2{0,0}; a2[k] = f2{0,0}; }

    #pragma unroll 4
    for (int j = 0; j < GPAIR; ++j) {
        // 12 consecutive dwords at SGPR base + compile-time offset
        const f2* P = reinterpret_cast<const f2*>(Tw + j * 12);
        f2 hx2 = P[0];                             // {hx0,hx1}
        f2 hy2 = P[1];                             // {hy0,hy1}
        f2 hz2 = P[2];                             // {hz0,hz1}
        f2 e02 = P[3];                             // {e00,e01}
        f2 e12 = P[4];                             // {e10,e11}
        f2 e22 = P[5];                             // {e20,e21}

        #pragma unroll
        for (int k = 0; k < PXPT; ++k) {
            f2 s = __builtin_elementwise_fma(nx2[k], hx2,
                   __builtin_elementwise_fma(ny2[k], hy2, nz2[k] * hz2));
            float sx = fmaxf(s.x, 0.0f);           // relu
            float sy = fmaxf(s.y, 0.0f);
            f2 r = {sx, sy};
            f2 r2  = r * r;
            f2 r4  = r2 * r2;
            f2 r8  = r4 * r4;
            f2 r16 = r8 * r8;
            f2 r32 = r16 * r16;
            f2 r64 = r32 * r32;
            mx64 = fmaxf(mx64, fmaxf(r64.x, r64.y));   // v_max3, r64 domain
            a0[k] = __builtin_elementwise_fma(r64, e02, a0[k]);
            a1[k] = __builtin_elementwise_fma(r64, e12, a1[k]);
            a2[k] = __builtin_elementwise_fma(r64, e22, a2[k]);
        }
    }

    // collapse light-slot halves
    float b0[PXPT], b1[PXPT], b2[PXPT];
    #pragma unroll
    for (int k = 0; k < PXPT; ++k) {
        b0[k] = a0[k].x + a0[k].y;
        b1[k] = a1[k].x + a1[k].y;
        b2[k] = a2[k].x + a2[k].y;
    }

    // wave-64 max reduce (r64 domain)
    #pragma unroll
    for (int off = 32; off > 0; off >>= 1)
        mx64 = fmaxf(mx64, __shfl_xor(mx64, off));
    if (li == 0) swmax[g] = mx64;

    // groups 1..3 deposit partials: stride 13 dwords (odd -> conflict-free)
    if (g > 0) {
        float* dst = smerge + (size_t)(g - 1) * (64 * 13) + li * 13;
        #pragma unroll
        for (int k = 0; k < PXPT; ++k) {
            dst[k]     = b0[k];
            dst[k + 4] = b1[k];
            dst[k + 8] = b2[k];
        }
    }
    __syncthreads();                               // single barrier

    if (tid == 0) {
        float bm = fmaxf(fmaxf(swmax[0], swmax[1]), fmaxf(swmax[2], swmax[3]));
        blockmax[bid] = bm;                        // plain store, distinct slot
    }

    if (g == 0) {
        #pragma unroll
        for (int gg = 0; gg < 3; ++gg) {
            const float* src = smerge + (size_t)gg * (64 * 13) + li * 13;
            #pragma unroll
            for (int k = 0; k < PXPT; ++k) {
                b0[k] += src[k];
                b1[k] += src[k + 4];
                b2[k] += src[k + 8];
            }
        }
        // unnormalized sums to out[b][c][h][w]; finalize scales by 1/gmax64
        float* ob = out + (size_t)b * 3 * HWPX;
        #pragma unroll
        for (int k = 0; k < PXPT; ++k) {
            int p = base_in_b + k * 64;
            ob[0 * HWPX + p] = b0[k];
            ob[1 * HWPX + p] = b1[k];
            ob[2 * HWPX + p] = b2[k];
        }
    }
}

// 1 block: reduce 2048 block-maxes -> scale = 1/gmax64
__global__ __launch_bounds__(256) void k_gmax(const float* __restrict__ blockmax,
                                              float* __restrict__ scale) {
    __shared__ float sm[4];
    int t = threadIdx.x;
    float m = 0.0f;
    #pragma unroll
    for (int i = 0; i < NBLK / 256; ++i)
        m = fmaxf(m, blockmax[t + i * 256]);
    #pragma unroll
    for (int off = 32; off > 0; off >>= 1)
        m = fmaxf(m, __shfl_xor(m, off));
    if ((t & 63) == 0) sm[t >> 6] = m;
    __syncthreads();
    if (t == 0) {
        m = fmaxf(fmaxf(sm[0], sm[1]), fmaxf(sm[2], sm[3]));
        *scale = 1.0f / m;                         // 1/gmax64
    }
}

__global__ __launch_bounds__(256) void k_finalize(float* __restrict__ out,
                                                  const float* __restrict__ scale) {
    float scl = *scale;                             // uniform scalar load
    int i = blockIdx.x * 256 + (int)threadIdx.x;    // over float4s
    float4* o = reinterpret_cast<float4*>(out);
    float4 v = o[i];
    v.x *= scl; v.y *= scl; v.z *= scl; v.w *= scl;
    o[i] = v;
}

extern "C" void kernel_launch(void* const* d_in, const int* in_sizes, int n_in,
                              void* d_out, int out_size, void* d_ws, size_t ws_size,
                              hipStream_t stream) {
    const float* env    = (const float*)d_in[0];   // (B,16,32,3) f32
    const float* normal = (const float*)d_in[1];   // (B,512,512,3) f32
    float* out = (float*)d_out;                    // (B,3,512,512) f32

    char* ws = (char*)d_ws;
    float* scale = (float*)ws;
    float* tabq = (float*)(ws + 256);
    float* blockmax = (float*)(ws + 32768);

    int fblocks = (NB * 3 * HWPX) / (4 * 256);     // 1536 (float4 granularity)

    hipLaunchKernelGGL(k_setup, dim3(1), dim3(NL), 0, stream, env, tabq);
    hipLaunchKernelGGL(k_fused, dim3(NBLK), dim3(256), 0, stream, normal, tabq, out, blockmax);
    hipLaunchKernelGGL(k_gmax, dim3(1), dim3(256), 0, stream, blockmax, scale);
    hipLaunchKernelGGL(k_finalize, dim3(fblocks), dim3(256), 0, stream, out, scale);
}

// Round 15
// 60.804 us; speedup vs baseline: 1.2314x; 1.2146x over previous
//
#include <hip/hip_runtime.h>
#include <math.h>

// Problem constants (match reference)
#define HWPX (512*512)      // pixels per batch
#define NB 2                // batches
#define NL 512              // EH*EW light directions (table rows)
#define NLS 480             // shadeable lights: phi=0 row (32 dirs) has coeff sin(0)=0
#define NPAIR 240           // light pairs
#define GPAIR 60            // pairs per wave-group (4 groups)
#define NBLK 2048           // k_max / k_lookup grid
// radiance-field table (lat-long in the lights' (phi,theta) parametrization)
#define NPH 192
#define NTH 384
#define ROWS (NPH + 1)                 // 193 (row NPH = phi=pi)
#define COLS (NTH + 1)                 // 385 (col NTH duplicates col 0: theta wrap)
#define NODES (ROWS * COLS)            // 74305 per batch
#define BPB_BUILD 581                  // ceil(NODES/128)
#define NODESTRIDE (BPB_BUILD * 128)   // 74368 padded per-batch stride
constexpr float PI_F = 3.14159265358979323846f;
constexpr float INV_SQRT2 = 0.70710678118654752f;

typedef float f2 __attribute__((ext_vector_type(2)));

// ws layout (bytes):
//   [0]      float scale (k_gmax output)
//   [256]    float tabq[2][240][12] light-paired table {hx0,hx1,hy0,hy1,hz0,hz1,e00,e01,e10,e11,e20,e21}
//   [24576]  float blockmax[2048]
//   [32768]  float4 table[2][NODESTRIDE]  (~2.38 MB radiance field, if ws allows)
//
// New formulation: light(px) = F_b(n(px)), F_b(n) = sum_m (relu(n.h_m)/max)^64 e_m
// is a spherical function whose sharpest feature is the cos^64 lobe (sigma~7.2deg).
// Tabulate F on a 192x384 lat-long grid (Delta=0.94deg -> bilinear err ~0.4% rel)
// and render by 4-tap lookup. Exact global max via a cheap dot+max pass.
// Fallback (ws too small): R13 exact path.

__global__ void k_setup(const float* __restrict__ env,
                        float* __restrict__ tabq) {
    int m = threadIdx.x;            // 512 threads, one per light dir
    int p = m >> 5;                 // phi index (EH=16)
    int t = m & 31;                 // theta index (EW=32)
    if (p < 1) return;              // phi=0: zero coeff, handled analytically
    float phi = (float)p * (PI_F / 16.0f);
    float th  = (float)t * (2.0f * PI_F / 32.0f);
    float sp = sinf(phi), cp = cosf(phi);
    float st = sinf(th),  ct = cosf(th);
    float hx = st * sp;
    float hy = cp;
    float hz = 1.0f - ct * sp;
    float inv = rsqrtf(hx * hx + hy * hy + hz * hz);
    hx *= inv; hy *= inv; hz *= inv;
    float c = sp * (1.0f / 60.0f);
    int ms = m - 32;
    int j = ms >> 1;
    int slot = ms & 1;
    #pragma unroll
    for (int b = 0; b < NB; ++b) {
        const float* e = env + ((size_t)(b * NL + m)) * 3;
        float* dst = tabq + ((size_t)(b * NPAIR + j)) * 12 + slot;
        dst[0]  = hx;
        dst[2]  = hy;
        dst[4]  = hz;
        dst[6]  = e[0] * c;
        dst[8]  = e[1] * c;
        dst[10] = e[2] * c;
    }
}

__device__ __forceinline__ void load_normal(const float* __restrict__ normal, size_t pix,
                                            float& nx, float& ny, float& nz) {
    const float* p = normal + pix * 3;
    float c0 = p[0], c1 = p[1], c2 = p[2];
    float x = (c2 - 0.5f) * 2.0f;
    float y = (c1 - 0.5f) * 2.0f;
    float z = (c0 - 0.5f) * 2.0f;
    float d2 = x * x + y * y + z * z;
    float inv = d2 > 0.0f ? rsqrtf(d2) : 0.0f;
    nx = x * inv; ny = y * inv; nz = z * inv;
}

__device__ __forceinline__ float pow64(float r) {
    float r2  = r * r;
    float r4  = r2 * r2;
    float r8  = r4 * r4;
    float r16 = r8 * r8;
    float r32 = r16 * r16;
    return r32 * r32;
}

// ---------- Pass 1: exact global max of relu(n.h) (dot + max3 only) ----------
__global__ __launch_bounds__(256) void k_max(const float* __restrict__ normal,
                                             const float* __restrict__ tabq,
                                             float* __restrict__ blockmax) {
    __shared__ float swmax[4];
    int tid = threadIdx.x, bid = blockIdx.x;
    int bpb = HWPX / 256;                          // 1024
    int b = bid / bpb;
    int g = tid >> 6;
    int li = tid & 63;
    int base_in_b = (bid % bpb) * 256 + li;

    int toff = __builtin_amdgcn_readfirstlane((b * NPAIR + g * GPAIR) * 12);
    const float* Tw = tabq + toff;

    float nxs[4], nys[4], nzs[4];
    #pragma unroll
    for (int k = 0; k < 4; ++k)
        load_normal(normal, (size_t)b * HWPX + base_in_b + k * 64,
                    nxs[k], nys[k], nzs[k]);
    f2 nx2[4], ny2[4], nz2[4];
    #pragma unroll
    for (int k = 0; k < 4; ++k) {
        nx2[k] = f2{nxs[k], nxs[k]};
        ny2[k] = f2{nys[k], nys[k]};
        nz2[k] = f2{nzs[k], nzs[k]};
    }

    float mx = 0.0f;
    if (g == 0) {                                  // phi=0 light: h=(0,r2,r2)
        #pragma unroll
        for (int k = 0; k < 4; ++k)
            mx = fmaxf(mx, (nys[k] + nzs[k]) * INV_SQRT2);
    }

    #pragma unroll 8
    for (int j = 0; j < GPAIR; ++j) {
        const f2* P = reinterpret_cast<const f2*>(Tw + j * 12);
        f2 hx2 = P[0], hy2 = P[1], hz2 = P[2];
        #pragma unroll
        for (int k = 0; k < 4; ++k) {
            f2 s = __builtin_elementwise_fma(nx2[k], hx2,
                   __builtin_elementwise_fma(ny2[k], hy2, nz2[k] * hz2));
            mx = fmaxf(mx, fmaxf(s.x, s.y));       // -> v_max3
        }
    }

    #pragma unroll
    for (int off = 32; off > 0; off >>= 1)
        mx = fmaxf(mx, __shfl_xor(mx, off));
    if (li == 0) swmax[g] = mx;
    __syncthreads();
    if (tid == 0)
        blockmax[bid] = fmaxf(fmaxf(swmax[0], swmax[1]), fmaxf(swmax[2], swmax[3]));
}

// ---------- Pass 2: reduce 2048 block maxes -> scale = 1/m ----------
__global__ __launch_bounds__(256) void k_gmax(const float* __restrict__ blockmax,
                                              float* __restrict__ scale) {
    __shared__ float sm[4];
    int t = threadIdx.x;
    float m = 0.0f;
    #pragma unroll
    for (int i = 0; i < NBLK / 256; ++i)
        m = fmaxf(m, blockmax[t + i * 256]);
    #pragma unroll
    for (int off = 32; off > 0; off >>= 1)
        m = fmaxf(m, __shfl_xor(m, off));
    if ((t & 63) == 0) sm[t >> 6] = m;
    __syncthreads();
    if (t == 0) {
        m = fmaxf(fmaxf(sm[0], sm[1]), fmaxf(sm[2], sm[3]));
        *scale = 1.0f / m;
    }
}

// ---------- Pass 3: build radiance table on the lat-long grid ----------
// Block: 256 thr = 4 waves (light quarters) x 64 lanes x 2 dirs. 1162 blocks.
__global__ __launch_bounds__(256) void k_build(const float* __restrict__ tabq,
                                               const float* __restrict__ scale,
                                               float4* __restrict__ table) {
    __shared__ float smerge[3 * 64 * 7];
    int tid = threadIdx.x, bid = blockIdx.x;
    int b = bid / BPB_BUILD;
    int blk = bid % BPB_BUILD;
    int g = tid >> 6;
    int li = tid & 63;
    int node0 = blk * 128 + li;

    float invmax = *scale;
    int toff = __builtin_amdgcn_readfirstlane((b * NPAIR + g * GPAIR) * 12);
    const float* Tw = tabq + toff;

    // 2 grid dirs per thread, invmax folded in
    f2 nx2[2], ny2[2], nz2[2];
    #pragma unroll
    for (int k = 0; k < 2; ++k) {
        int node = node0 + k * 64;                 // may overrun NODES (harmless)
        int i = node / COLS;
        int j = node - i * COLS;
        float phi = (float)i * (PI_F / (float)NPH);
        float th  = (float)j * (2.0f * PI_F / (float)NTH);
        float spv, cpv, stv, ctv;
        sincosf(phi, &spv, &cpv);
        sincosf(th, &stv, &ctv);
        float dx = stv * spv * invmax;
        float dy = cpv * invmax;
        float dz = -ctv * spv * invmax;
        nx2[k] = f2{dx, dx}; ny2[k] = f2{dy, dy}; nz2[k] = f2{dz, dz};
    }

    f2 a0[2], a1[2], a2[2];
    #pragma unroll
    for (int k = 0; k < 2; ++k) { a0[k] = f2{0,0}; a1[k] = f2{0,0}; a2[k] = f2{0,0}; }

    #pragma unroll 4
    for (int j = 0; j < GPAIR; ++j) {
        const f2* P = reinterpret_cast<const f2*>(Tw + j * 12);
        f2 hx2 = P[0], hy2 = P[1], hz2 = P[2];
        f2 e02 = P[3], e12 = P[4], e22 = P[5];
        #pragma unroll
        for (int k = 0; k < 2; ++k) {
            f2 s = __builtin_elementwise_fma(nx2[k], hx2,
                   __builtin_elementwise_fma(ny2[k], hy2, nz2[k] * hz2));
            float sx = fmaxf(s.x, 0.0f);
            float sy = fmaxf(s.y, 0.0f);
            f2 r = {sx, sy};
            f2 r2  = r * r;
            f2 r4  = r2 * r2;
            f2 r8  = r4 * r4;
            f2 r16 = r8 * r8;
            f2 r32 = r16 * r16;
            f2 r64 = r32 * r32;
            a0[k] = __builtin_elementwise_fma(r64, e02, a0[k]);
            a1[k] = __builtin_elementwise_fma(r64, e12, a1[k]);
            a2[k] = __builtin_elementwise_fma(r64, e22, a2[k]);
        }
    }

    float b0[2], b1[2], b2[2];
    #pragma unroll
    for (int k = 0; k < 2; ++k) {
        b0[k] = a0[k].x + a0[k].y;
        b1[k] = a1[k].x + a1[k].y;
        b2[k] = a2[k].x + a2[k].y;
    }

    if (g > 0) {                                   // deposit partials (stride 7: odd)
        float* dst = smerge + (size_t)(g - 1) * (64 * 7) + li * 7;
        #pragma unroll
        for (int k = 0; k < 2; ++k) {
            dst[k * 3 + 0] = b0[k];
            dst[k * 3 + 1] = b1[k];
            dst[k * 3 + 2] = b2[k];
        }
    }
    __syncthreads();

    if (g == 0) {
        #pragma unroll
        for (int gg = 0; gg < 3; ++gg) {
            const float* src = smerge + (size_t)gg * (64 * 7) + li * 7;
            #pragma unroll
            for (int k = 0; k < 2; ++k) {
                b0[k] += src[k * 3 + 0];
                b1[k] += src[k * 3 + 1];
                b2[k] += src[k * 3 + 2];
            }
        }
        #pragma unroll
        for (int k = 0; k < 2; ++k) {
            int node = node0 + k * 64;
            if (node < NODES) {
                float4 v; v.x = b0[k]; v.y = b1[k]; v.z = b2[k]; v.w = 0.0f;
                table[(size_t)b * NODESTRIDE + node] = v;
            }
        }
    }
}

// ---------- Pass 4: per-pixel bilinear lookup ----------
__global__ __launch_bounds__(256) void k_lookup(const float* __restrict__ normal,
                                                const float4* __restrict__ table,
                                                float* __restrict__ out) {
    int tid = threadIdx.x, bid = blockIdx.x;
    int b = bid >> 10;                             // 1024 blocks per batch
    int pix_in_b = (bid & 1023) * 256 + tid;

    float nx, ny, nz;
    load_normal(normal, (size_t)b * HWPX + pix_in_b, nx, ny, nz);

    float phi = acosf(fminf(fmaxf(ny, -1.0f), 1.0f));      // [0,pi]
    float th  = atan2f(nx, -nz);                           // (-pi,pi]
    float fi = phi * ((float)NPH / PI_F);                  // [0, NPH]
    float t  = th * (0.5f / PI_F);                         // (-0.5, 0.5]
    float fj = (t - floorf(t)) * (float)NTH;               // [0, NTH]

    int i0 = (int)fi; i0 = i0 > (NPH - 1) ? (NPH - 1) : i0;
    int j0 = (int)fj; j0 = j0 > (NTH - 1) ? (NTH - 1) : j0;
    float wi = fi - (float)i0;
    float wj = fj - (float)j0;

    const float4* Tb = table + (size_t)b * NODESTRIDE;
    int idx = i0 * COLS + j0;
    float4 t00 = Tb[idx];
    float4 t01 = Tb[idx + 1];
    float4 t10 = Tb[idx + COLS];
    float4 t11 = Tb[idx + COLS + 1];

    float w00 = (1.0f - wi) * (1.0f - wj);
    float w01 = (1.0f - wi) * wj;
    float w10 = wi * (1.0f - wj);
    float w11 = wi * wj;
    float r0 = t00.x * w00 + t01.x * w01 + t10.x * w10 + t11.x * w11;
    float r1 = t00.y * w00 + t01.y * w01 + t10.y * w10 + t11.y * w11;
    float r2 = t00.z * w00 + t01.z * w01 + t10.z * w10 + t11.z * w11;

    float* ob = out + (size_t)b * 3 * HWPX;
    ob[0 * HWPX + pix_in_b] = r0;
    ob[1 * HWPX + pix_in_b] = r1;
    ob[2 * HWPX + pix_in_b] = r2;
}

// ---------- Fallback exact path (R13), used only if ws too small ----------
__global__ __launch_bounds__(256) void k_fused_fb(const float* __restrict__ normal,
                                                  const float* __restrict__ tabq,
                                                  float* __restrict__ out,
                                                  float* __restrict__ blockmax) {
    __shared__ float smerge[3 * 64 * 13];
    __shared__ float swmax[4];
    int tid = threadIdx.x, bid = blockIdx.x;
    int bpb = HWPX / 256;
    int b = bid / bpb;
    int g = tid >> 6;
    int li = tid & 63;
    int base_in_b = (bid % bpb) * 256 + li;
    int toff = __builtin_amdgcn_readfirstlane((b * NPAIR + g * GPAIR) * 12);
    const float* Tw = tabq + toff;

    float nxs[4], nys[4], nzs[4];
    #pragma unroll
    for (int k = 0; k < 4; ++k)
        load_normal(normal, (size_t)b * HWPX + base_in_b + k * 64, nxs[k], nys[k], nzs[k]);
    f2 nx2[4], ny2[4], nz2[4];
    #pragma unroll
    for (int k = 0; k < 4; ++k) {
        nx2[k] = f2{nxs[k], nxs[k]};
        ny2[k] = f2{nys[k], nys[k]};
        nz2[k] = f2{nzs[k], nzs[k]};
    }
    float mx64 = 0.0f;
    if (g == 0) {
        #pragma unroll
        for (int k = 0; k < 4; ++k) {
            float s0 = fmaxf((nys[k] + nzs[k]) * INV_SQRT2, 0.0f);
            mx64 = fmaxf(mx64, pow64(s0));
        }
    }
    f2 a0[4], a1[4], a2[4];
    #pragma unroll
    for (int k = 0; k < 4; ++k) { a0[k] = f2{0,0}; a1[k] = f2{0,0}; a2[k] = f2{0,0}; }
    #pragma unroll 4
    for (int j = 0; j < GPAIR; ++j) {
        const f2* P = reinterpret_cast<const f2*>(Tw + j * 12);
        f2 hx2 = P[0], hy2 = P[1], hz2 = P[2];
        f2 e02 = P[3], e12 = P[4], e22 = P[5];
        #pragma unroll
        for (int k = 0; k < 4; ++k) {
            f2 s = __builtin_elementwise_fma(nx2[k], hx2,
                   __builtin_elementwise_fma(ny2[k], hy2, nz2[k] * hz2));
            float sx = fmaxf(s.x, 0.0f);
            float sy = fmaxf(s.y, 0.0f);
            f2 r = {sx, sy};
            f2 r2  = r * r;
            f2 r4  = r2 * r2;
            f2 r8  = r4 * r4;
            f2 r16 = r8 * r8;
            f2 r32 = r16 * r16;
            f2 r64 = r32 * r32;
            mx64 = fmaxf(mx64, fmaxf(r64.x, r64.y));
            a0[k] = __builtin_elementwise_fma(r64, e02, a0[k]);
            a1[k] = __builtin_elementwise_fma(r64, e12, a1[k]);
            a2[k] = __builtin_elementwise_fma(r64, e22, a2[k]);
        }
    }
    float b0[4], b1[4], b2[4];
    #pragma unroll
    for (int k = 0; k < 4; ++k) {
        b0[k] = a0[k].x + a0[k].y;
        b1[k] = a1[k].x + a1[k].y;
        b2[k] = a2[k].x + a2[k].y;
    }
    #pragma unroll
    for (int off = 32; off > 0; off >>= 1)
        mx64 = fmaxf(mx64, __shfl_xor(mx64, off));
    if (li == 0) swmax[g] = mx64;
    if (g > 0) {
        float* dst = smerge + (size_t)(g - 1) * (64 * 13) + li * 13;
        #pragma unroll
        for (int k = 0; k < 4; ++k) {
            dst[k] = b0[k]; dst[k + 4] = b1[k]; dst[k + 8] = b2[k];
        }
    }
    __syncthreads();
    if (tid == 0)
        blockmax[bid] = fmaxf(fmaxf(swmax[0], swmax[1]), fmaxf(swmax[2], swmax[3]));
    if (g == 0) {
        #pragma unroll
        for (int gg = 0; gg < 3; ++gg) {
            const float* src = smerge + (size_t)gg * (64 * 13) + li * 13;
            #pragma unroll
            for (int k = 0; k < 4; ++k) {
                b0[k] += src[k]; b1[k] += src[k + 4]; b2[k] += src[k + 8];
            }
        }
        float* ob = out + (size_t)b * 3 * HWPX;
        #pragma unroll
        for (int k = 0; k < 4; ++k) {
            int p = base_in_b + k * 64;
            ob[0 * HWPX + p] = b0[k];
            ob[1 * HWPX + p] = b1[k];
            ob[2 * HWPX + p] = b2[k];
        }
    }
}

__global__ __launch_bounds__(256) void k_finalize(float* __restrict__ out,
                                                  const float* __restrict__ scale) {
    float scl = *scale;
    int i = blockIdx.x * 256 + (int)threadIdx.x;
    float4* o = reinterpret_cast<float4*>(out);
    float4 v = o[i];
    v.x *= scl; v.y *= scl; v.z *= scl; v.w *= scl;
    o[i] = v;
}

extern "C" void kernel_launch(void* const* d_in, const int* in_sizes, int n_in,
                              void* d_out, int out_size, void* d_ws, size_t ws_size,
                              hipStream_t stream) {
    const float* env    = (const float*)d_in[0];   // (B,16,32,3) f32
    const float* normal = (const float*)d_in[1];   // (B,512,512,3) f32
    float* out = (float*)d_out;                    // (B,3,512,512) f32

    char* ws = (char*)d_ws;
    float* scale = (float*)ws;
    float* tabq = (float*)(ws + 256);
    float* blockmax = (float*)(ws + 24576);
    float4* table = (float4*)(ws + 32768);

    size_t need = 32768 + (size_t)NB * NODESTRIDE * 16;   // ~2.41 MB

    hipLaunchKernelGGL(k_setup, dim3(1), dim3(NL), 0, stream, env, tabq);

    if (ws_size >= need) {
        hipLaunchKernelGGL(k_max, dim3(NBLK), dim3(256), 0, stream, normal, tabq, blockmax);
        hipLaunchKernelGGL(k_gmax, dim3(1), dim3(256), 0, stream, blockmax, scale);
        hipLaunchKernelGGL(k_build, dim3(NB * BPB_BUILD), dim3(256), 0, stream, tabq, scale, table);
        hipLaunchKernelGGL(k_lookup, dim3(NBLK), dim3(256), 0, stream, normal, table, out);
    } else {
        // exact fallback (R13 path)
        int fblocks = (NB * 3 * HWPX) / (4 * 256);
        hipLaunchKernelGGL(k_fused_fb, dim3(NBLK), dim3(256), 0, stream, normal, tabq, out, blockmax);
        hipLaunchKernelGGL(k_gmax, dim3(1), dim3(256), 0, stream, blockmax, scale);
        hipLaunchKernelGGL(k_finalize, dim3(fblocks), dim3(256), 0, stream, out, scale);
    }
}

// Round 16
// 50.148 us; speedup vs baseline: 1.4931x; 1.2125x over previous
//
#include <hip/hip_runtime.h>
#include <math.h>

// Problem constants (match reference)
#define HWPX (512*512)      // pixels per batch
#define NB 2                // batches
#define NL 512              // EH*EW light directions
#define NLS 480             // shadeable lights (phi=0 row: coeff 0)
#define NPAIR 240
#define GPAIR 60
#define NBLK 2048
// radiance-field table (lat-long in the lights' (phi,theta) parametrization)
#define NPH 192
#define NTH 384
#define ROWS (NPH + 1)
#define COLS (NTH + 1)
#define NODES (ROWS * COLS)            // 74305 per batch
#define BPB_BUILD 581
#define NODESTRIDE (BPB_BUILD * 128)   // 74368
constexpr float PI_F = 3.14159265358979323846f;
constexpr float INV_SQRT2 = 0.70710678118654752f;

typedef float f2 __attribute__((ext_vector_type(2)));

// ws layout (bytes):
//   [0]      float scale
//   [256]    float tabq[2][240][12]  (23040 B) light-paired shading table
//   [24576]  float4 hvec[512]        (8 KB)    unit half-vectors, ALL 512 lights
//   [32768]  float blockmax[2048]    (8 KB)    -- dead before k_build writes --
//   [32768]  float4 table[2][NODESTRIDE]       (~2.38 MB, aliases blockmax)
//   need = 32768 + NB*NODESTRIDE*16 = 2412544 (same as R14)
//
// Pipeline: setup -> max2 (inverted candidate search) -> gmax (scale=pow64(1/m))
//           -> build (UNNORMALIZED F table) -> lookup (bilinear * scale).
// Max inversion: argmax light satisfies h ~ n; generating l = 2*nz*n - v
// (reflection). Exact (fi,fj) from l; candidates = 4x4 box + 15-cell ring
// around the singular cell (8,0) (covers all equatorial h's / nz<0 pixels).
// Same h values as brute force -> bit-identical global max.

__global__ void k_setup(const float* __restrict__ env,
                        float* __restrict__ tabq,
                        float4* __restrict__ hvec) {
    int m = threadIdx.x;            // 512 threads
    int p = m >> 5;
    int t = m & 31;
    float phi = (float)p * (PI_F / 16.0f);
    float th  = (float)t * (2.0f * PI_F / 32.0f);
    float sp = sinf(phi), cp = cosf(phi);
    float st = sinf(th),  ct = cosf(th);
    float hx = st * sp;
    float hy = cp;
    float hz = 1.0f - ct * sp;
    float inv = rsqrtf(hx * hx + hy * hy + hz * hz);
    hx *= inv; hy *= inv; hz *= inv;
    float4 hv; hv.x = hx; hv.y = hy; hv.z = hz; hv.w = 0.0f;
    hvec[m] = hv;                   // all lights, incl. phi=0 row
    if (p < 1) return;              // phi=0: zero shading coeff
    float c = sp * (1.0f / 60.0f);
    int ms = m - 32;
    int j = ms >> 1;
    int slot = ms & 1;
    #pragma unroll
    for (int b = 0; b < NB; ++b) {
        const float* e = env + ((size_t)(b * NL + m)) * 3;
        float* dst = tabq + ((size_t)(b * NPAIR + j)) * 12 + slot;
        dst[0]  = hx;
        dst[2]  = hy;
        dst[4]  = hz;
        dst[6]  = e[0] * c;
        dst[8]  = e[1] * c;
        dst[10] = e[2] * c;
    }
}

__device__ __forceinline__ void load_normal(const float* __restrict__ normal, size_t pix,
                                            float& nx, float& ny, float& nz) {
    const float* p = normal + pix * 3;
    float c0 = p[0], c1 = p[1], c2 = p[2];
    float x = (c2 - 0.5f) * 2.0f;
    float y = (c1 - 0.5f) * 2.0f;
    float z = (c0 - 0.5f) * 2.0f;
    float d2 = x * x + y * y + z * z;
    float inv = d2 > 0.0f ? rsqrtf(d2) : 0.0f;
    nx = x * inv; ny = y * inv; nz = z * inv;
}

__device__ __forceinline__ float pow64(float r) {
    float r2  = r * r;
    float r4  = r2 * r2;
    float r8  = r4 * r4;
    float r16 = r8 * r8;
    float r32 = r16 * r16;
    return r32 * r32;
}

// ---------- Pass 1: per-pixel max via inverted candidate search ----------
__global__ __launch_bounds__(256) void k_max2(const float* __restrict__ normal,
                                              const float4* __restrict__ hvec,
                                              float* __restrict__ blockmax) {
    __shared__ float4 sh[NL];                      // 8 KB half-vector table
    __shared__ float swmax[4];
    int tid = threadIdx.x, bid = blockIdx.x;
    int b = bid >> 10;
    int pix_in_b = (bid & 1023) * 256 + tid;

    sh[tid]       = hvec[tid];
    sh[tid + 256] = hvec[tid + 256];

    float nx, ny, nz;
    load_normal(normal, (size_t)b * HWPX + pix_in_b, nx, ny, nz);
    __syncthreads();

    // invert: l = 2*nz*n - v  (reflection of view about h=n)
    float lx = 2.0f * nz * nx;
    float ly = 2.0f * nz * ny;
    float lz = 2.0f * nz * nz - 1.0f;
    float fi = acosf(fminf(fmaxf(ly, -1.0f), 1.0f)) * (16.0f / PI_F);  // [0,16]
    float th = atan2f(lx, -lz);
    float tt = th * (0.5f / PI_F);
    float fj = (tt - floorf(tt)) * 32.0f;                              // [0,32)

    int i0 = (int)floorf(fi) - 1;
    int j0 = (int)floorf(fj) - 1;

    float mx = 0.0f;                               // relu'd max seed
    #pragma unroll
    for (int di = 0; di < 4; ++di) {
        int i = i0 + di;
        i = i < 0 ? 0 : (i > 15 ? 15 : i);
        #pragma unroll
        for (int dj = 0; dj < 4; ++dj) {
            int j = (j0 + dj) & 31;
            float4 h = sh[i * 32 + j];
            mx = fmaxf(mx, fmaf(nx, h.x, fmaf(ny, h.y, nz * h.z)));
        }
    }
    // singular ring around (8,0): covers equatorial h's (nz<0 pixels)
    #pragma unroll
    for (int di = 0; di < 3; ++di) {
        int i = 7 + di;
        #pragma unroll
        for (int dj = 0; dj < 5; ++dj) {
            int j = (30 + dj) & 31;
            float4 h = sh[i * 32 + j];
            mx = fmaxf(mx, fmaf(nx, h.x, fmaf(ny, h.y, nz * h.z)));
        }
    }

    #pragma unroll
    for (int off = 32; off > 0; off >>= 1)
        mx = fmaxf(mx, __shfl_xor(mx, off));
    if ((tid & 63) == 0) swmax[tid >> 6] = mx;
    __syncthreads();
    if (tid == 0)
        blockmax[bid] = fmaxf(fmaxf(swmax[0], swmax[1]), fmaxf(swmax[2], swmax[3]));
}

// ---------- Pass 2a: scale = (1/m)^64 (table path) ----------
__global__ __launch_bounds__(256) void k_gmax_pow(const float* __restrict__ blockmax,
                                                  float* __restrict__ scale) {
    __shared__ float sm[4];
    int t = threadIdx.x;
    float m = 0.0f;
    #pragma unroll
    for (int i = 0; i < NBLK / 256; ++i)
        m = fmaxf(m, blockmax[t + i * 256]);
    #pragma unroll
    for (int off = 32; off > 0; off >>= 1)
        m = fmaxf(m, __shfl_xor(m, off));
    if ((t & 63) == 0) sm[t >> 6] = m;
    __syncthreads();
    if (t == 0) {
        m = fmaxf(fmaxf(sm[0], sm[1]), fmaxf(sm[2], sm[3]));
        *scale = pow64(1.0f / m);
    }
}

// ---------- Pass 2b: scale = 1/m64 (fallback path, r64-domain max) ----------
__global__ __launch_bounds__(256) void k_gmax_inv(const float* __restrict__ blockmax,
                                                  float* __restrict__ scale) {
    __shared__ float sm[4];
    int t = threadIdx.x;
    float m = 0.0f;
    #pragma unroll
    for (int i = 0; i < NBLK / 256; ++i)
        m = fmaxf(m, blockmax[t + i * 256]);
    #pragma unroll
    for (int off = 32; off > 0; off >>= 1)
        m = fmaxf(m, __shfl_xor(m, off));
    if ((t & 63) == 0) sm[t >> 6] = m;
    __syncthreads();
    if (t == 0) {
        m = fmaxf(fmaxf(sm[0], sm[1]), fmaxf(sm[2], sm[3]));
        *scale = 1.0f / m;
    }
}

// ---------- Pass 3: build UNNORMALIZED radiance table ----------
__global__ __launch_bounds__(256) void k_build(const float* __restrict__ tabq,
                                               float4* __restrict__ table) {
    __shared__ float smerge[3 * 64 * 7];
    int tid = threadIdx.x, bid = blockIdx.x;
    int b = bid / BPB_BUILD;
    int blk = bid % BPB_BUILD;
    int g = tid >> 6;
    int li = tid & 63;
    int node0 = blk * 128 + li;

    int toff = __builtin_amdgcn_readfirstlane((b * NPAIR + g * GPAIR) * 12);
    const float* Tw = tabq + toff;

    f2 nx2[2], ny2[2], nz2[2];
    #pragma unroll
    for (int k = 0; k < 2; ++k) {
        int node = node0 + k * 64;                 // may overrun NODES (write guarded)
        int i = node / COLS;
        int j = node - i * COLS;
        float phi = (float)i * (PI_F / (float)NPH);
        float th  = (float)j * (2.0f * PI_F / (float)NTH);
        float spv, cpv, stv, ctv;
        sincosf(phi, &spv, &cpv);
        sincosf(th, &stv, &ctv);
        float dx = stv * spv;
        float dy = cpv;
        float dz = -ctv * spv;
        nx2[k] = f2{dx, dx}; ny2[k] = f2{dy, dy}; nz2[k] = f2{dz, dz};
    }

    f2 a0[2], a1[2], a2[2];
    #pragma unroll
    for (int k = 0; k < 2; ++k) { a0[k] = f2{0,0}; a1[k] = f2{0,0}; a2[k] = f2{0,0}; }

    #pragma unroll 4
    for (int j = 0; j < GPAIR; ++j) {
        const f2* P = reinterpret_cast<const f2*>(Tw + j * 12);
        f2 hx2 = P[0], hy2 = P[1], hz2 = P[2];
        f2 e02 = P[3], e12 = P[4], e22 = P[5];
        #pragma unroll
        for (int k = 0; k < 2; ++k) {
            f2 s = __builtin_elementwise_fma(nx2[k], hx2,
                   __builtin_elementwise_fma(ny2[k], hy2, nz2[k] * hz2));
            float sx = fmaxf(s.x, 0.0f);
            float sy = fmaxf(s.y, 0.0f);
            f2 r = {sx, sy};
            f2 r2  = r * r;
            f2 r4  = r2 * r2;
            f2 r8  = r4 * r4;
            f2 r16 = r8 * r8;
            f2 r32 = r16 * r16;
            f2 r64 = r32 * r32;
            a0[k] = __builtin_elementwise_fma(r64, e02, a0[k]);
            a1[k] = __builtin_elementwise_fma(r64, e12, a1[k]);
            a2[k] = __builtin_elementwise_fma(r64, e22, a2[k]);
        }
    }

    float b0[2], b1[2], b2[2];
    #pragma unroll
    for (int k = 0; k < 2; ++k) {
        b0[k] = a0[k].x + a0[k].y;
        b1[k] = a1[k].x + a1[k].y;
        b2[k] = a2[k].x + a2[k].y;
    }

    if (g > 0) {
        float* dst = smerge + (size_t)(g - 1) * (64 * 7) + li * 7;
        #pragma unroll
        for (int k = 0; k < 2; ++k) {
            dst[k * 3 + 0] = b0[k];
            dst[k * 3 + 1] = b1[k];
            dst[k * 3 + 2] = b2[k];
        }
    }
    __syncthreads();

    if (g == 0) {
        #pragma unroll
        for (int gg = 0; gg < 3; ++gg) {
            const float* src = smerge + (size_t)gg * (64 * 7) + li * 7;
            #pragma unroll
            for (int k = 0; k < 2; ++k) {
                b0[k] += src[k * 3 + 0];
                b1[k] += src[k * 3 + 1];
                b2[k] += src[k * 3 + 2];
            }
        }
        #pragma unroll
        for (int k = 0; k < 2; ++k) {
            int node = node0 + k * 64;
            if (node < NODES) {
                float4 v; v.x = b0[k]; v.y = b1[k]; v.z = b2[k]; v.w = 0.0f;
                table[(size_t)b * NODESTRIDE + node] = v;
            }
        }
    }
}

// ---------- Pass 4: per-pixel bilinear lookup * scale ----------
__global__ __launch_bounds__(256) void k_lookup(const float* __restrict__ normal,
                                                const float4* __restrict__ table,
                                                const float* __restrict__ scale,
                                                float* __restrict__ out) {
    int tid = threadIdx.x, bid = blockIdx.x;
    int b = bid >> 10;
    int pix_in_b = (bid & 1023) * 256 + tid;
    float scl = *scale;

    float nx, ny, nz;
    load_normal(normal, (size_t)b * HWPX + pix_in_b, nx, ny, nz);

    float phi = acosf(fminf(fmaxf(ny, -1.0f), 1.0f));
    float th  = atan2f(nx, -nz);
    float fi = phi * ((float)NPH / PI_F);
    float t  = th * (0.5f / PI_F);
    float fj = (t - floorf(t)) * (float)NTH;

    int i0 = (int)fi; i0 = i0 > (NPH - 1) ? (NPH - 1) : i0;
    int j0 = (int)fj; j0 = j0 > (NTH - 1) ? (NTH - 1) : j0;
    float wi = fi - (float)i0;
    float wj = fj - (float)j0;

    const float4* Tb = table + (size_t)b * NODESTRIDE;
    int idx = i0 * COLS + j0;
    float4 t00 = Tb[idx];
    float4 t01 = Tb[idx + 1];
    float4 t10 = Tb[idx + COLS];
    float4 t11 = Tb[idx + COLS + 1];

    float w00 = (1.0f - wi) * (1.0f - wj);
    float w01 = (1.0f - wi) * wj;
    float w10 = wi * (1.0f - wj);
    float w11 = wi * wj;
    float r0 = t00.x * w00 + t01.x * w01 + t10.x * w10 + t11.x * w11;
    float r1 = t00.y * w00 + t01.y * w01 + t10.y * w10 + t11.y * w11;
    float r2 = t00.z * w00 + t01.z * w01 + t10.z * w10 + t11.z * w11;

    float* ob = out + (size_t)b * 3 * HWPX;
    ob[0 * HWPX + pix_in_b] = r0 * scl;
    ob[1 * HWPX + pix_in_b] = r1 * scl;
    ob[2 * HWPX + pix_in_b] = r2 * scl;
}

// ---------- Fallback exact path (R13) ----------
__global__ __launch_bounds__(256) void k_fused_fb(const float* __restrict__ normal,
                                                  const float* __restrict__ tabq,
                                                  float* __restrict__ out,
                                                  float* __restrict__ blockmax) {
    __shared__ float smerge[3 * 64 * 13];
    __shared__ float swmax[4];
    int tid = threadIdx.x, bid = blockIdx.x;
    int bpb = HWPX / 256;
    int b = bid / bpb;
    int g = tid >> 6;
    int li = tid & 63;
    int base_in_b = (bid % bpb) * 256 + li;
    int toff = __builtin_amdgcn_readfirstlane((b * NPAIR + g * GPAIR) * 12);
    const float* Tw = tabq + toff;

    float nxs[4], nys[4], nzs[4];
    #pragma unroll
    for (int k = 0; k < 4; ++k)
        load_normal(normal, (size_t)b * HWPX + base_in_b + k * 64, nxs[k], nys[k], nzs[k]);
    f2 nx2[4], ny2[4], nz2[4];
    #pragma unroll
    for (int k = 0; k < 4; ++k) {
        nx2[k] = f2{nxs[k], nxs[k]};
        ny2[k] = f2{nys[k], nys[k]};
        nz2[k] = f2{nzs[k], nzs[k]};
    }
    float mx64 = 0.0f;
    if (g == 0) {
        #pragma unroll
        for (int k = 0; k < 4; ++k) {
            float s0 = fmaxf((nys[k] + nzs[k]) * INV_SQRT2, 0.0f);
            mx64 = fmaxf(mx64, pow64(s0));
        }
    }
    f2 a0[4], a1[4], a2[4];
    #pragma unroll
    for (int k = 0; k < 4; ++k) { a0[k] = f2{0,0}; a1[k] = f2{0,0}; a2[k] = f2{0,0}; }
    #pragma unroll 4
    for (int j = 0; j < GPAIR; ++j) {
        const f2* P = reinterpret_cast<const f2*>(Tw + j * 12);
        f2 hx2 = P[0], hy2 = P[1], hz2 = P[2];
        f2 e02 = P[3], e12 = P[4], e22 = P[5];
        #pragma unroll
        for (int k = 0; k < 4; ++k) {
            f2 s = __builtin_elementwise_fma(nx2[k], hx2,
                   __builtin_elementwise_fma(ny2[k], hy2, nz2[k] * hz2));
            float sx = fmaxf(s.x, 0.0f);
            float sy = fmaxf(s.y, 0.0f);
            f2 r = {sx, sy};
            f2 r2  = r * r;
            f2 r4  = r2 * r2;
            f2 r8  = r4 * r4;
            f2 r16 = r8 * r8;
            f2 r32 = r16 * r16;
            f2 r64 = r32 * r32;
            mx64 = fmaxf(mx64, fmaxf(r64.x, r64.y));
            a0[k] = __builtin_elementwise_fma(r64, e02, a0[k]);
            a1[k] = __builtin_elementwise_fma(r64, e12, a1[k]);
            a2[k] = __builtin_elementwise_fma(r64, e22, a2[k]);
        }
    }
    float b0[4], b1[4], b2[4];
    #pragma unroll
    for (int k = 0; k < 4; ++k) {
        b0[k] = a0[k].x + a0[k].y;
        b1[k] = a1[k].x + a1[k].y;
        b2[k] = a2[k].x + a2[k].y;
    }
    #pragma unroll
    for (int off = 32; off > 0; off >>= 1)
        mx64 = fmaxf(mx64, __shfl_xor(mx64, off));
    if (li == 0) swmax[g] = mx64;
    if (g > 0) {
        float* dst = smerge + (size_t)(g - 1) * (64 * 13) + li * 13;
        #pragma unroll
        for (int k = 0; k < 4; ++k) {
            dst[k] = b0[k]; dst[k + 4] = b1[k]; dst[k + 8] = b2[k];
        }
    }
    __syncthreads();
    if (tid == 0)
        blockmax[bid] = fmaxf(fmaxf(swmax[0], swmax[1]), fmaxf(swmax[2], swmax[3]));
    if (g == 0) {
        #pragma unroll
        for (int gg = 0; gg < 3; ++gg) {
            const float* src = smerge + (size_t)gg * (64 * 13) + li * 13;
            #pragma unroll
            for (int k = 0; k < 4; ++k) {
                b0[k] += src[k]; b1[k] += src[k + 4]; b2[k] += src[k + 8];
            }
        }
        float* ob = out + (size_t)b * 3 * HWPX;
        #pragma unroll
        for (int k = 0; k < 4; ++k) {
            int p = base_in_b + k * 64;
            ob[0 * HWPX + p] = b0[k];
            ob[1 * HWPX + p] = b1[k];
            ob[2 * HWPX + p] = b2[k];
        }
    }
}

__global__ __launch_bounds__(256) void k_finalize(float* __restrict__ out,
                                                  const float* __restrict__ scale) {
    float scl = *scale;
    int i = blockIdx.x * 256 + (int)threadIdx.x;
    float4* o = reinterpret_cast<float4*>(out);
    float4 v = o[i];
    v.x *= scl; v.y *= scl; v.z *= scl; v.w *= scl;
    o[i] = v;
}

extern "C" void kernel_launch(void* const* d_in, const int* in_sizes, int n_in,
                              void* d_out, int out_size, void* d_ws, size_t ws_size,
                              hipStream_t stream) {
    const float* env    = (const float*)d_in[0];   // (B,16,32,3) f32
    const float* normal = (const float*)d_in[1];   // (B,512,512,3) f32
    float* out = (float*)d_out;                    // (B,3,512,512) f32

    char* ws = (char*)d_ws;
    float* scale = (float*)ws;
    float* tabq = (float*)(ws + 256);
    float4* hvec = (float4*)(ws + 24576);
    float* blockmax = (float*)(ws + 32768);        // aliased by table (dead first)
    float4* table = (float4*)(ws + 32768);

    size_t need = 32768 + (size_t)NB * NODESTRIDE * 16;   // 2412544

    hipLaunchKernelGGL(k_setup, dim3(1), dim3(NL), 0, stream, env, tabq, hvec);

    if (ws_size >= need) {
        hipLaunchKernelGGL(k_max2, dim3(NBLK), dim3(256), 0, stream, normal, hvec, blockmax);
        hipLaunchKernelGGL(k_gmax_pow, dim3(1), dim3(256), 0, stream, blockmax, scale);
        hipLaunchKernelGGL(k_build, dim3(NB * BPB_BUILD), dim3(256), 0, stream, tabq, table);
        hipLaunchKernelGGL(k_lookup, dim3(NBLK), dim3(256), 0, stream, normal, table, scale, out);
    } else {
        int fblocks = (NB * 3 * HWPX) / (4 * 256);
        hipLaunchKernelGGL(k_fused_fb, dim3(NBLK), dim3(256), 0, stream, normal, tabq, out, blockmax);
        hipLaunchKernelGGL(k_gmax_inv, dim3(1), dim3(256), 0, stream, blockmax, scale);
        hipLaunchKernelGGL(k_finalize, dim3(fblocks), dim3(256), 0, stream, out, scale);
    }
}

// Round 17
// 46.427 us; speedup vs baseline: 1.6128x; 1.0802x over previous
//
#include <hip/hip_runtime.h>
#include <math.h>

// Problem constants (match reference)
#define HWPX (512*512)      // pixels per batch
#define NB 2                // batches
#define NL 512              // EH*EW light directions
#define NLS 480             // shadeable lights (phi=0 row: coeff 0)
#define NPAIR 240
#define GPAIR 60
#define NBLK 2048
// radiance-field table (lat-long in the lights' (phi,theta) parametrization)
#define NPH 192
#define NTH 384
#define ROWS (NPH + 1)
#define COLS (NTH + 1)
#define NODES (ROWS * COLS)            // 74305 per batch
#define BPB_BUILD 581
#define NODESTRIDE (BPB_BUILD * 128)   // 74368
constexpr float PI_F   = 3.14159265358979323846f;
constexpr float TWO_PI = 6.28318530717958647692f;
constexpr float INV_SQRT2 = 0.70710678118654752f;

typedef float f2 __attribute__((ext_vector_type(2)));

// ws layout (bytes), main path:
//   [0]      float scale
//   [256]    float blockmax[2048]            (8 KB)
//   [16384]  float4 table[2][NODESTRIDE]     (~2.38 MB unnormalized radiance field)
// Fallback path (ws too small): scale@0, tabq@256, blockmax@24576 (R13 exact).
//
// R16: 4 dispatches (was 5): k_build (in-block light-table gen -> LDS -> write
// unnormalized F table) -> k_render (in-block hvec gen; ONE normal pass doing
// candidate-max AND bilinear lookup, unnormalized out + blockmax) -> k_gmax_pow
// (scale=(1/m)^64) -> k_finalize (out *= scale). Transcendentals via cheap
// polynomials (err <= 1e-4 rad = 0.006 cell).

// fast acos (A&S 4.4.45), |err| <= 6.7e-5 rad
__device__ __forceinline__ float acos_fast(float x) {
    float ax = fabsf(x);
    float r = sqrtf(fmaxf(1.0f - ax, 0.0f)) *
              (1.5707288f + ax * (-0.2121144f + ax * (0.0742610f - ax * 0.0187293f)));
    return x >= 0.0f ? r : PI_F - r;
}

// fast atan2(y,x), |err| ~1e-5 rad
__device__ __forceinline__ float atan2_fast(float y, float x) {
    float ay = fabsf(y), ax = fabsf(x);
    float mx = fmaxf(ay, ax), mn = fminf(ay, ax);
    float a = mn / fmaxf(mx, 1e-30f);
    float s = a * a;
    float r = a * (0.9998660f + s * (-0.3302995f + s * (0.1801410f +
              s * (-0.0851330f + s * 0.0208351f))));
    if (ay > ax) r = 1.5707963f - r;
    if (x < 0.0f) r = PI_F - r;
    return y < 0.0f ? -r : r;
}

// unit half-vector (and sin(phi)) for light index m in [0,512)
__device__ __forceinline__ void light_h(int m, float& hx, float& hy, float& hz, float& sp) {
    int p = m >> 5, t = m & 31;
    float phi = (float)p * (PI_F / 16.0f);
    float th  = (float)t * (TWO_PI / 32.0f);
    float spv, cpv, stv, ctv;
    sincosf(phi, &spv, &cpv);
    sincosf(th, &stv, &ctv);
    float x = stv * spv, y = cpv, z = 1.0f - ctv * spv;
    float inv = rsqrtf(x * x + y * y + z * z);
    hx = x * inv; hy = y * inv; hz = z * inv; sp = spv;
}

__device__ __forceinline__ void load_normal(const float* __restrict__ normal, size_t pix,
                                            float& nx, float& ny, float& nz) {
    const float* p = normal + pix * 3;
    float c0 = p[0], c1 = p[1], c2 = p[2];
    float x = (c2 - 0.5f) * 2.0f;
    float y = (c1 - 0.5f) * 2.0f;
    float z = (c0 - 0.5f) * 2.0f;
    float d2 = x * x + y * y + z * z;
    float inv = d2 > 0.0f ? rsqrtf(d2) : 0.0f;
    nx = x * inv; ny = y * inv; nz = z * inv;
}

__device__ __forceinline__ float pow64(float r) {
    float r2  = r * r;
    float r4  = r2 * r2;
    float r8  = r4 * r4;
    float r16 = r8 * r8;
    float r32 = r16 * r16;
    return r32 * r32;
}

// ---------- Pass 1: build UNNORMALIZED radiance table (in-block light gen) ----------
__global__ __launch_bounds__(256) void k_build(const float* __restrict__ env,
                                               float4* __restrict__ table) {
    __shared__ float tabL[NPAIR * 12];             // 11.25 KB light-paired table
    __shared__ float smerge[3 * 64 * 7];
    int tid = threadIdx.x, bid = blockIdx.x;
    int b = bid / BPB_BUILD;
    int blk = bid % BPB_BUILD;
    int g = tid >> 6;
    int li = tid & 63;
    int node0 = blk * 128 + li;

    // in-block light table generation (<=2 lights per thread)
    for (int ms = tid; ms < NLS; ms += 256) {
        int m = ms + 32;                           // skip phi=0 row
        float hx, hy, hz, sp;
        light_h(m, hx, hy, hz, sp);
        float c = sp * (1.0f / 60.0f);
        const float* e = env + ((size_t)(b * NL + m)) * 3;
        float* dst = tabL + (ms >> 1) * 12 + (ms & 1);
        dst[0]  = hx;
        dst[2]  = hy;
        dst[4]  = hz;
        dst[6]  = e[0] * c;
        dst[8]  = e[1] * c;
        dst[10] = e[2] * c;
    }

    // 2 grid dirs per thread
    f2 nx2[2], ny2[2], nz2[2];
    #pragma unroll
    for (int k = 0; k < 2; ++k) {
        int node = node0 + k * 64;                 // may overrun NODES (write guarded)
        int i = node / COLS;
        int j = node - i * COLS;
        float phi = (float)i * (PI_F / (float)NPH);
        float th  = (float)j * (TWO_PI / (float)NTH);
        float spv, cpv, stv, ctv;
        sincosf(phi, &spv, &cpv);
        sincosf(th, &stv, &ctv);
        float dx = stv * spv;
        float dy = cpv;
        float dz = -ctv * spv;
        nx2[k] = f2{dx, dx}; ny2[k] = f2{dy, dy}; nz2[k] = f2{dz, dz};
    }
    __syncthreads();

    f2 a0[2], a1[2], a2[2];
    #pragma unroll
    for (int k = 0; k < 2; ++k) { a0[k] = f2{0,0}; a1[k] = f2{0,0}; a2[k] = f2{0,0}; }

    const float4* Tg = reinterpret_cast<const float4*>(tabL) + (size_t)g * (GPAIR * 3);
    #pragma unroll 4
    for (int j = 0; j < GPAIR; ++j) {
        float4 A = Tg[j * 3 + 0];                  // {hx0,hx1,hy0,hy1}
        float4 B = Tg[j * 3 + 1];                  // {hz0,hz1,e00,e01}
        float4 C = Tg[j * 3 + 2];                  // {e10,e11,e20,e21}
        f2 hx2 = {A.x, A.y}, hy2 = {A.z, A.w}, hz2 = {B.x, B.y};
        f2 e02 = {B.z, B.w}, e12 = {C.x, C.y}, e22 = {C.z, C.w};
        #pragma unroll
        for (int k = 0; k < 2; ++k) {
            f2 s = __builtin_elementwise_fma(nx2[k], hx2,
                   __builtin_elementwise_fma(ny2[k], hy2, nz2[k] * hz2));
            float sx = fmaxf(s.x, 0.0f);
            float sy = fmaxf(s.y, 0.0f);
            f2 r = {sx, sy};
            f2 r2  = r * r;
            f2 r4  = r2 * r2;
            f2 r8  = r4 * r4;
            f2 r16 = r8 * r8;
            f2 r32 = r16 * r16;
            f2 r64 = r32 * r32;
            a0[k] = __builtin_elementwise_fma(r64, e02, a0[k]);
            a1[k] = __builtin_elementwise_fma(r64, e12, a1[k]);
            a2[k] = __builtin_elementwise_fma(r64, e22, a2[k]);
        }
    }

    float b0[2], b1[2], b2[2];
    #pragma unroll
    for (int k = 0; k < 2; ++k) {
        b0[k] = a0[k].x + a0[k].y;
        b1[k] = a1[k].x + a1[k].y;
        b2[k] = a2[k].x + a2[k].y;
    }

    if (g > 0) {
        float* dst = smerge + (size_t)(g - 1) * (64 * 7) + li * 7;
        #pragma unroll
        for (int k = 0; k < 2; ++k) {
            dst[k * 3 + 0] = b0[k];
            dst[k * 3 + 1] = b1[k];
            dst[k * 3 + 2] = b2[k];
        }
    }
    __syncthreads();

    if (g == 0) {
        #pragma unroll
        for (int gg = 0; gg < 3; ++gg) {
            const float* src = smerge + (size_t)gg * (64 * 7) + li * 7;
            #pragma unroll
            for (int k = 0; k < 2; ++k) {
                b0[k] += src[k * 3 + 0];
                b1[k] += src[k * 3 + 1];
                b2[k] += src[k * 3 + 2];
            }
        }
        #pragma unroll
        for (int k = 0; k < 2; ++k) {
            int node = node0 + k * 64;
            if (node < NODES) {
                float4 v; v.x = b0[k]; v.y = b1[k]; v.z = b2[k]; v.w = 0.0f;
                table[(size_t)b * NODESTRIDE + node] = v;
            }
        }
    }
}

// ---------- Pass 2: fused candidate-max + bilinear lookup (unnormalized) ----------
__global__ __launch_bounds__(256) void k_render(const float* __restrict__ normal,
                                                const float4* __restrict__ table,
                                                float* __restrict__ out,
                                                float* __restrict__ blockmax) {
    __shared__ float4 sh[NL];                      // 8 KB half-vector table
    __shared__ float swmax[4];
    int tid = threadIdx.x, bid = blockIdx.x;
    int b = bid >> 10;
    int pix_in_b = (bid & 1023) * 256 + tid;

    // in-block half-vector generation (2 dirs per thread)
    for (int m = tid; m < NL; m += 256) {
        float hx, hy, hz, sp;
        light_h(m, hx, hy, hz, sp);
        float4 hv; hv.x = hx; hv.y = hy; hv.z = hz; hv.w = 0.0f;
        sh[m] = hv;
    }

    float nx, ny, nz;
    load_normal(normal, (size_t)b * HWPX + pix_in_b, nx, ny, nz);
    __syncthreads();

    // ---- candidate max via reflection l = 2*nz*n - v ----
    float lx = 2.0f * nz * nx;
    float ly = 2.0f * nz * ny;
    float lz = 2.0f * nz * nz - 1.0f;
    float fi = acos_fast(fminf(fmaxf(ly, -1.0f), 1.0f)) * (16.0f / PI_F);
    float th = atan2_fast(lx, -lz);
    float tt = th * (0.5f / PI_F);
    float fj = (tt - floorf(tt)) * 32.0f;
    int i0 = (int)floorf(fi) - 1;
    int j0 = (int)floorf(fj) - 1;

    float mx = 0.0f;
    #pragma unroll
    for (int di = 0; di < 4; ++di) {
        int i = i0 + di;
        i = i < 0 ? 0 : (i > 15 ? 15 : i);
        #pragma unroll
        for (int dj = 0; dj < 4; ++dj) {
            int j = (j0 + dj) & 31;
            float4 h = sh[i * 32 + j];
            mx = fmaxf(mx, fmaf(nx, h.x, fmaf(ny, h.y, nz * h.z)));
        }
    }
    #pragma unroll
    for (int di = 0; di < 3; ++di) {               // singular ring around (8,0)
        int i = 7 + di;
        #pragma unroll
        for (int dj = 0; dj < 5; ++dj) {
            int j = (30 + dj) & 31;
            float4 h = sh[i * 32 + j];
            mx = fmaxf(mx, fmaf(nx, h.x, fmaf(ny, h.y, nz * h.z)));
        }
    }

    #pragma unroll
    for (int off = 32; off > 0; off >>= 1)
        mx = fmaxf(mx, __shfl_xor(mx, off));
    if ((tid & 63) == 0) swmax[tid >> 6] = mx;
    __syncthreads();
    if (tid == 0)
        blockmax[bid] = fmaxf(fmaxf(swmax[0], swmax[1]), fmaxf(swmax[2], swmax[3]));

    // ---- bilinear lookup in normal direction (unnormalized) ----
    float phN = acos_fast(fminf(fmaxf(ny, -1.0f), 1.0f));
    float thN = atan2_fast(nx, -nz);
    float fiN = phN * ((float)NPH / PI_F);
    float tN  = thN * (0.5f / PI_F);
    float fjN = (tN - floorf(tN)) * (float)NTH;

    int iN = (int)fiN; iN = iN > (NPH - 1) ? (NPH - 1) : iN;
    int jN = (int)fjN; jN = jN > (NTH - 1) ? (NTH - 1) : jN;
    float wi = fiN - (float)iN;
    float wj = fjN - (float)jN;

    const float4* Tb = table + (size_t)b * NODESTRIDE;
    int idx = iN * COLS + jN;
    float4 t00 = Tb[idx];
    float4 t01 = Tb[idx + 1];
    float4 t10 = Tb[idx + COLS];
    float4 t11 = Tb[idx + COLS + 1];

    float w00 = (1.0f - wi) * (1.0f - wj);
    float w01 = (1.0f - wi) * wj;
    float w10 = wi * (1.0f - wj);
    float w11 = wi * wj;
    float r0 = t00.x * w00 + t01.x * w01 + t10.x * w10 + t11.x * w11;
    float r1 = t00.y * w00 + t01.y * w01 + t10.y * w10 + t11.y * w11;
    float r2 = t00.z * w00 + t01.z * w01 + t10.z * w10 + t11.z * w11;

    float* ob = out + (size_t)b * 3 * HWPX;
    ob[0 * HWPX + pix_in_b] = r0;                  // unnormalized; k_finalize scales
    ob[1 * HWPX + pix_in_b] = r1;
    ob[2 * HWPX + pix_in_b] = r2;
}

// ---------- Pass 3: scale = (1/m)^64 ----------
__global__ __launch_bounds__(256) void k_gmax_pow(const float* __restrict__ blockmax,
                                                  float* __restrict__ scale) {
    __shared__ float sm[4];
    int t = threadIdx.x;
    float m = 0.0f;
    #pragma unroll
    for (int i = 0; i < NBLK / 256; ++i)
        m = fmaxf(m, blockmax[t + i * 256]);
    #pragma unroll
    for (int off = 32; off > 0; off >>= 1)
        m = fmaxf(m, __shfl_xor(m, off));
    if ((t & 63) == 0) sm[t >> 6] = m;
    __syncthreads();
    if (t == 0) {
        m = fmaxf(fmaxf(sm[0], sm[1]), fmaxf(sm[2], sm[3]));
        *scale = pow64(1.0f / m);
    }
}

// ---------- Pass 4: out *= scale ----------
__global__ __launch_bounds__(256) void k_finalize(float* __restrict__ out,
                                                  const float* __restrict__ scale) {
    float scl = *scale;
    int i = blockIdx.x * 256 + (int)threadIdx.x;
    float4* o = reinterpret_cast<float4*>(out);
    float4 v = o[i];
    v.x *= scl; v.y *= scl; v.z *= scl; v.w *= scl;
    o[i] = v;
}

// ================= Fallback exact path (R13) for small ws =================
__global__ void k_setup_fb(const float* __restrict__ env,
                           float* __restrict__ tabq) {
    int m = threadIdx.x;
    int p = m >> 5;
    if (p < 1) return;
    float hx, hy, hz, sp;
    light_h(m, hx, hy, hz, sp);
    float c = sp * (1.0f / 60.0f);
    int ms = m - 32;
    int j = ms >> 1;
    int slot = ms & 1;
    #pragma unroll
    for (int b = 0; b < NB; ++b) {
        const float* e = env + ((size_t)(b * NL + m)) * 3;
        float* dst = tabq + ((size_t)(b * NPAIR + j)) * 12 + slot;
        dst[0]  = hx;
        dst[2]  = hy;
        dst[4]  = hz;
        dst[6]  = e[0] * c;
        dst[8]  = e[1] * c;
        dst[10] = e[2] * c;
    }
}

__global__ __launch_bounds__(256) void k_fused_fb(const float* __restrict__ normal,
                                                  const float* __restrict__ tabq,
                                                  float* __restrict__ out,
                                                  float* __restrict__ blockmax) {
    __shared__ float smerge[3 * 64 * 13];
    __shared__ float swmax[4];
    int tid = threadIdx.x, bid = blockIdx.x;
    int bpb = HWPX / 256;
    int b = bid / bpb;
    int g = tid >> 6;
    int li = tid & 63;
    int base_in_b = (bid % bpb) * 256 + li;
    int toff = __builtin_amdgcn_readfirstlane((b * NPAIR + g * GPAIR) * 12);
    const float* Tw = tabq + toff;

    float nxs[4], nys[4], nzs[4];
    #pragma unroll
    for (int k = 0; k < 4; ++k)
        load_normal(normal, (size_t)b * HWPX + base_in_b + k * 64, nxs[k], nys[k], nzs[k]);
    f2 nx2[4], ny2[4], nz2[4];
    #pragma unroll
    for (int k = 0; k < 4; ++k) {
        nx2[k] = f2{nxs[k], nxs[k]};
        ny2[k] = f2{nys[k], nys[k]};
        nz2[k] = f2{nzs[k], nzs[k]};
    }
    float mx64 = 0.0f;
    if (g == 0) {
        #pragma unroll
        for (int k = 0; k < 4; ++k) {
            float s0 = fmaxf((nys[k] + nzs[k]) * INV_SQRT2, 0.0f);
            mx64 = fmaxf(mx64, pow64(s0));
        }
    }
    f2 a0[4], a1[4], a2[4];
    #pragma unroll
    for (int k = 0; k < 4; ++k) { a0[k] = f2{0,0}; a1[k] = f2{0,0}; a2[k] = f2{0,0}; }
    #pragma unroll 4
    for (int j = 0; j < GPAIR; ++j) {
        const f2* P = reinterpret_cast<const f2*>(Tw + j * 12);
        f2 hx2 = P[0], hy2 = P[1], hz2 = P[2];
        f2 e02 = P[3], e12 = P[4], e22 = P[5];
        #pragma unroll
        for (int k = 0; k < 4; ++k) {
            f2 s = __builtin_elementwise_fma(nx2[k], hx2,
                   __builtin_elementwise_fma(ny2[k], hy2, nz2[k] * hz2));
            float sx = fmaxf(s.x, 0.0f);
            float sy = fmaxf(s.y, 0.0f);
            f2 r = {sx, sy};
            f2 r2  = r * r;
            f2 r4  = r2 * r2;
            f2 r8  = r4 * r4;
            f2 r16 = r8 * r8;
            f2 r32 = r16 * r16;
            f2 r64 = r32 * r32;
            mx64 = fmaxf(mx64, fmaxf(r64.x, r64.y));
            a0[k] = __builtin_elementwise_fma(r64, e02, a0[k]);
            a1[k] = __builtin_elementwise_fma(r64, e12, a1[k]);
            a2[k] = __builtin_elementwise_fma(r64, e22, a2[k]);
        }
    }
    float b0[4], b1[4], b2[4];
    #pragma unroll
    for (int k = 0; k < 4; ++k) {
        b0[k] = a0[k].x + a0[k].y;
        b1[k] = a1[k].x + a1[k].y;
        b2[k] = a2[k].x + a2[k].y;
    }
    #pragma unroll
    for (int off = 32; off > 0; off >>= 1)
        mx64 = fmaxf(mx64, __shfl_xor(mx64, off));
    if (li == 0) swmax[g] = mx64;
    if (g > 0) {
        float* dst = smerge + (size_t)(g - 1) * (64 * 13) + li * 13;
        #pragma unroll
        for (int k = 0; k < 4; ++k) {
            dst[k] = b0[k]; dst[k + 4] = b1[k]; dst[k + 8] = b2[k];
        }
    }
    __syncthreads();
    if (tid == 0)
        blockmax[bid] = fmaxf(fmaxf(swmax[0], swmax[1]), fmaxf(swmax[2], swmax[3]));
    if (g == 0) {
        #pragma unroll
        for (int gg = 0; gg < 3; ++gg) {
            const float* src = smerge + (size_t)gg * (64 * 13) + li * 13;
            #pragma unroll
            for (int k = 0; k < 4; ++k) {
                b0[k] += src[k]; b1[k] += src[k + 4]; b2[k] += src[k + 8];
            }
        }
        float* ob = out + (size_t)b * 3 * HWPX;
        #pragma unroll
        for (int k = 0; k < 4; ++k) {
            int p = base_in_b + k * 64;
            ob[0 * HWPX + p] = b0[k];
            ob[1 * HWPX + p] = b1[k];
            ob[2 * HWPX + p] = b2[k];
        }
    }
}

__global__ __launch_bounds__(256) void k_gmax_inv(const float* __restrict__ blockmax,
                                                  float* __restrict__ scale) {
    __shared__ float sm[4];
    int t = threadIdx.x;
    float m = 0.0f;
    #pragma unroll
    for (int i = 0; i < NBLK / 256; ++i)
        m = fmaxf(m, blockmax[t + i * 256]);
    #pragma unroll
    for (int off = 32; off > 0; off >>= 1)
        m = fmaxf(m, __shfl_xor(m, off));
    if ((t & 63) == 0) sm[t >> 6] = m;
    __syncthreads();
    if (t == 0) {
        m = fmaxf(fmaxf(sm[0], sm[1]), fmaxf(sm[2], sm[3]));
        *scale = 1.0f / m;
    }
}

extern "C" void kernel_launch(void* const* d_in, const int* in_sizes, int n_in,
                              void* d_out, int out_size, void* d_ws, size_t ws_size,
                              hipStream_t stream) {
    const float* env    = (const float*)d_in[0];   // (B,16,32,3) f32
    const float* normal = (const float*)d_in[1];   // (B,512,512,3) f32
    float* out = (float*)d_out;                    // (B,3,512,512) f32

    char* ws = (char*)d_ws;
    float* scale = (float*)ws;
    int fblocks = (NB * 3 * HWPX) / (4 * 256);     // 1536

    size_t need = 16384 + (size_t)NB * NODESTRIDE * 16;   // ~2.40 MB

    if (ws_size >= need) {
        float* blockmax = (float*)(ws + 256);
        float4* table = (float4*)(ws + 16384);
        hipLaunchKernelGGL(k_build, dim3(NB * BPB_BUILD), dim3(256), 0, stream, env, table);
        hipLaunchKernelGGL(k_render, dim3(NBLK), dim3(256), 0, stream, normal, table, out, blockmax);
        hipLaunchKernelGGL(k_gmax_pow, dim3(1), dim3(256), 0, stream, blockmax, scale);
        hipLaunchKernelGGL(k_finalize, dim3(fblocks), dim3(256), 0, stream, out, scale);
    } else {
        float* tabq = (float*)(ws + 256);
        float* blockmax = (float*)(ws + 24576);
        hipLaunchKernelGGL(k_setup_fb, dim3(1), dim3(NL), 0, stream, env, tabq);
        hipLaunchKernelGGL(k_fused_fb, dim3(NBLK), dim3(256), 0, stream, normal, tabq, out, blockmax);
        hipLaunchKernelGGL(k_gmax_inv, dim3(1), dim3(256), 0, stream, blockmax, scale);
        hipLaunchKernelGGL(k_finalize, dim3(fblocks), dim3(256), 0, stream, out, scale);
    }
}

// Round 18
// 41.600 us; speedup vs baseline: 1.7999x; 1.1160x over previous
//
#include <hip/hip_runtime.h>
#include <math.h>

// Problem constants (match reference)
#define HWPX (512*512)      // pixels per batch
#define NB 2                // batches
#define NL 512              // EH*EW light directions
#define NLS 480             // shadeable lights (phi=0 row: coeff 0)
#define NPAIR 240
#define GPAIR 60
#define NBLK 2048
// radiance-field table (lat-long in the lights' (phi,theta) parametrization)
#define NPH 192
#define NTH 384
#define ROWS (NPH + 1)
#define COLS (NTH + 1)
#define NODES (ROWS * COLS)            // 74305 per batch
#define BPB_BUILD 581
#define NBUILD (NB * BPB_BUILD)        // 1162 build blocks
#define NODESTRIDE (BPB_BUILD * 128)   // 74368
constexpr float PI_F   = 3.14159265358979323846f;
constexpr float TWO_PI = 6.28318530717958647692f;
constexpr float INV_SQRT2 = 0.70710678118654752f;

typedef float f2 __attribute__((ext_vector_type(2)));

// ws layout (bytes), main path:
//   [0]      float scale
//   [256]    float blockmax[2048]            (8 KB)
//   [16384]  float4 table[2][NODESTRIDE]     (~2.38 MB unnormalized radiance field)
// Fallback path (ws too small): scale@0, tabq@256, blockmax@24576 (R13 exact).
//
// R17: 3 dispatches. k_pre = heterogeneous grid: blocks [0,NBUILD) build the
// unnormalized F table (independent of normals); blocks [NBUILD, NBUILD+NBLK)
// run the per-pixel candidate max (independent of env/table) -> blockmax.
// k_gmax_pow: scale=(1/m)^64. k_render: pure bilinear lookup * scale -> final
// output in ONE write (finalize pass deleted: saves 25MB of traffic + 1 launch).

// fast acos (A&S 4.4.45), |err| <= 6.7e-5 rad
__device__ __forceinline__ float acos_fast(float x) {
    float ax = fabsf(x);
    float r = sqrtf(fmaxf(1.0f - ax, 0.0f)) *
              (1.5707288f + ax * (-0.2121144f + ax * (0.0742610f - ax * 0.0187293f)));
    return x >= 0.0f ? r : PI_F - r;
}

// fast atan2(y,x), |err| ~1e-5 rad
__device__ __forceinline__ float atan2_fast(float y, float x) {
    float ay = fabsf(y), ax = fabsf(x);
    float mx = fmaxf(ay, ax), mn = fminf(ay, ax);
    float a = mn / fmaxf(mx, 1e-30f);
    float s = a * a;
    float r = a * (0.9998660f + s * (-0.3302995f + s * (0.1801410f +
              s * (-0.0851330f + s * 0.0208351f))));
    if (ay > ax) r = 1.5707963f - r;
    if (x < 0.0f) r = PI_F - r;
    return y < 0.0f ? -r : r;
}

// unit half-vector (and sin(phi)) for light index m in [0,512)
__device__ __forceinline__ void light_h(int m, float& hx, float& hy, float& hz, float& sp) {
    int p = m >> 5, t = m & 31;
    float phi = (float)p * (PI_F / 16.0f);
    float th  = (float)t * (TWO_PI / 32.0f);
    float spv, cpv, stv, ctv;
    sincosf(phi, &spv, &cpv);
    sincosf(th, &stv, &ctv);
    float x = stv * spv, y = cpv, z = 1.0f - ctv * spv;
    float inv = rsqrtf(x * x + y * y + z * z);
    hx = x * inv; hy = y * inv; hz = z * inv; sp = spv;
}

__device__ __forceinline__ void load_normal(const float* __restrict__ normal, size_t pix,
                                            float& nx, float& ny, float& nz) {
    const float* p = normal + pix * 3;
    float c0 = p[0], c1 = p[1], c2 = p[2];
    float x = (c2 - 0.5f) * 2.0f;
    float y = (c1 - 0.5f) * 2.0f;
    float z = (c0 - 0.5f) * 2.0f;
    float d2 = x * x + y * y + z * z;
    float inv = d2 > 0.0f ? rsqrtf(d2) : 0.0f;
    nx = x * inv; ny = y * inv; nz = z * inv;
}

__device__ __forceinline__ float pow64(float r) {
    float r2  = r * r;
    float r4  = r2 * r2;
    float r8  = r4 * r4;
    float r16 = r8 * r8;
    float r32 = r16 * r16;
    return r32 * r32;
}

// ---------- Pass 1: heterogeneous — table build OR candidate max ----------
__global__ __launch_bounds__(256) void k_pre(const float* __restrict__ env,
                                             const float* __restrict__ normal,
                                             float4* __restrict__ table,
                                             float* __restrict__ blockmax) {
    __shared__ float smem[NPAIR * 12];             // 11.25 KB (build: tabL / max: hvec+swmax)
    int tid = threadIdx.x, bid = blockIdx.x;

    if (bid < NBUILD) {
        // ======== BUILD path ========
        float* tabL = smem;
        __shared__ float smerge[3 * 64 * 7];
        int b = bid / BPB_BUILD;
        int blk = bid % BPB_BUILD;
        int g = tid >> 6;
        int li = tid & 63;
        int node0 = blk * 128 + li;

        for (int ms = tid; ms < NLS; ms += 256) {
            int m = ms + 32;                       // skip phi=0 row
            float hx, hy, hz, sp;
            light_h(m, hx, hy, hz, sp);
            float c = sp * (1.0f / 60.0f);
            const float* e = env + ((size_t)(b * NL + m)) * 3;
            float* dst = tabL + (ms >> 1) * 12 + (ms & 1);
            dst[0]  = hx;
            dst[2]  = hy;
            dst[4]  = hz;
            dst[6]  = e[0] * c;
            dst[8]  = e[1] * c;
            dst[10] = e[2] * c;
        }

        f2 nx2[2], ny2[2], nz2[2];
        #pragma unroll
        for (int k = 0; k < 2; ++k) {
            int node = node0 + k * 64;             // may overrun NODES (write guarded)
            int i = node / COLS;
            int j = node - i * COLS;
            float phi = (float)i * (PI_F / (float)NPH);
            float th  = (float)j * (TWO_PI / (float)NTH);
            float spv, cpv, stv, ctv;
            sincosf(phi, &spv, &cpv);
            sincosf(th, &stv, &ctv);
            float dx = stv * spv;
            float dy = cpv;
            float dz = -ctv * spv;
            nx2[k] = f2{dx, dx}; ny2[k] = f2{dy, dy}; nz2[k] = f2{dz, dz};
        }
        __syncthreads();

        f2 a0[2], a1[2], a2[2];
        #pragma unroll
        for (int k = 0; k < 2; ++k) { a0[k] = f2{0,0}; a1[k] = f2{0,0}; a2[k] = f2{0,0}; }

        const float4* Tg = reinterpret_cast<const float4*>(tabL) + (size_t)g * (GPAIR * 3);
        #pragma unroll 4
        for (int j = 0; j < GPAIR; ++j) {
            float4 A = Tg[j * 3 + 0];
            float4 B = Tg[j * 3 + 1];
            float4 C = Tg[j * 3 + 2];
            f2 hx2 = {A.x, A.y}, hy2 = {A.z, A.w}, hz2 = {B.x, B.y};
            f2 e02 = {B.z, B.w}, e12 = {C.x, C.y}, e22 = {C.z, C.w};
            #pragma unroll
            for (int k = 0; k < 2; ++k) {
                f2 s = __builtin_elementwise_fma(nx2[k], hx2,
                       __builtin_elementwise_fma(ny2[k], hy2, nz2[k] * hz2));
                float sx = fmaxf(s.x, 0.0f);
                float sy = fmaxf(s.y, 0.0f);
                f2 r = {sx, sy};
                f2 r2  = r * r;
                f2 r4  = r2 * r2;
                f2 r8  = r4 * r4;
                f2 r16 = r8 * r8;
                f2 r32 = r16 * r16;
                f2 r64 = r32 * r32;
                a0[k] = __builtin_elementwise_fma(r64, e02, a0[k]);
                a1[k] = __builtin_elementwise_fma(r64, e12, a1[k]);
                a2[k] = __builtin_elementwise_fma(r64, e22, a2[k]);
            }
        }

        float b0[2], b1[2], b2[2];
        #pragma unroll
        for (int k = 0; k < 2; ++k) {
            b0[k] = a0[k].x + a0[k].y;
            b1[k] = a1[k].x + a1[k].y;
            b2[k] = a2[k].x + a2[k].y;
        }

        if (g > 0) {
            float* dst = smerge + (size_t)(g - 1) * (64 * 7) + li * 7;
            #pragma unroll
            for (int k = 0; k < 2; ++k) {
                dst[k * 3 + 0] = b0[k];
                dst[k * 3 + 1] = b1[k];
                dst[k * 3 + 2] = b2[k];
            }
        }
        __syncthreads();

        if (g == 0) {
            #pragma unroll
            for (int gg = 0; gg < 3; ++gg) {
                const float* src = smerge + (size_t)gg * (64 * 7) + li * 7;
                #pragma unroll
                for (int k = 0; k < 2; ++k) {
                    b0[k] += src[k * 3 + 0];
                    b1[k] += src[k * 3 + 1];
                    b2[k] += src[k * 3 + 2];
                }
            }
            #pragma unroll
            for (int k = 0; k < 2; ++k) {
                int node = node0 + k * 64;
                if (node < NODES) {
                    float4 v; v.x = b0[k]; v.y = b1[k]; v.z = b2[k]; v.w = 0.0f;
                    table[(size_t)b * NODESTRIDE + node] = v;
                }
            }
        }
    } else {
        // ======== MAX path ========
        float4* sh = reinterpret_cast<float4*>(smem);   // 8 KB half-vectors
        __shared__ float swmax[4];
        int mbid = bid - NBUILD;                   // 0..NBLK-1
        int b = mbid >> 10;
        int pix_in_b = (mbid & 1023) * 256 + tid;

        for (int m = tid; m < NL; m += 256) {
            float hx, hy, hz, sp;
            light_h(m, hx, hy, hz, sp);
            float4 hv; hv.x = hx; hv.y = hy; hv.z = hz; hv.w = 0.0f;
            sh[m] = hv;
        }

        float nx, ny, nz;
        load_normal(normal, (size_t)b * HWPX + pix_in_b, nx, ny, nz);
        __syncthreads();

        // invert: l = 2*nz*n - v (reflection about h=n)
        float lx = 2.0f * nz * nx;
        float ly = 2.0f * nz * ny;
        float lz = 2.0f * nz * nz - 1.0f;
        float fi = acos_fast(fminf(fmaxf(ly, -1.0f), 1.0f)) * (16.0f / PI_F);
        float th = atan2_fast(lx, -lz);
        float tt = th * (0.5f / PI_F);
        float fj = (tt - floorf(tt)) * 32.0f;
        int i0 = (int)floorf(fi) - 1;
        int j0 = (int)floorf(fj) - 1;

        float mx = 0.0f;
        #pragma unroll
        for (int di = 0; di < 4; ++di) {
            int i = i0 + di;
            i = i < 0 ? 0 : (i > 15 ? 15 : i);
            #pragma unroll
            for (int dj = 0; dj < 4; ++dj) {
                int j = (j0 + dj) & 31;
                float4 h = sh[i * 32 + j];
                mx = fmaxf(mx, fmaf(nx, h.x, fmaf(ny, h.y, nz * h.z)));
            }
        }
        #pragma unroll
        for (int di = 0; di < 3; ++di) {           // singular ring around (8,0)
            int i = 7 + di;
            #pragma unroll
            for (int dj = 0; dj < 5; ++dj) {
                int j = (30 + dj) & 31;
                float4 h = sh[i * 32 + j];
                mx = fmaxf(mx, fmaf(nx, h.x, fmaf(ny, h.y, nz * h.z)));
            }
        }

        #pragma unroll
        for (int off = 32; off > 0; off >>= 1)
            mx = fmaxf(mx, __shfl_xor(mx, off));
        if ((tid & 63) == 0) swmax[tid >> 6] = mx;
        __syncthreads();
        if (tid == 0)
            blockmax[mbid] = fmaxf(fmaxf(swmax[0], swmax[1]), fmaxf(swmax[2], swmax[3]));
    }
}

// ---------- Pass 2: scale = (1/m)^64 ----------
__global__ __launch_bounds__(256) void k_gmax_pow(const float* __restrict__ blockmax,
                                                  float* __restrict__ scale) {
    __shared__ float sm[4];
    int t = threadIdx.x;
    float m = 0.0f;
    #pragma unroll
    for (int i = 0; i < NBLK / 256; ++i)
        m = fmaxf(m, blockmax[t + i * 256]);
    #pragma unroll
    for (int off = 32; off > 0; off >>= 1)
        m = fmaxf(m, __shfl_xor(m, off));
    if ((t & 63) == 0) sm[t >> 6] = m;
    __syncthreads();
    if (t == 0) {
        m = fmaxf(fmaxf(sm[0], sm[1]), fmaxf(sm[2], sm[3]));
        *scale = pow64(1.0f / m);
    }
}

// ---------- Pass 3: bilinear lookup * scale -> final output ----------
__global__ __launch_bounds__(256) void k_render(const float* __restrict__ normal,
                                                const float4* __restrict__ table,
                                                const float* __restrict__ scale,
                                                float* __restrict__ out) {
    int tid = threadIdx.x, bid = blockIdx.x;
    int b = bid >> 10;
    int pix_in_b = (bid & 1023) * 256 + tid;
    float scl = *scale;                            // uniform s_load

    float nx, ny, nz;
    load_normal(normal, (size_t)b * HWPX + pix_in_b, nx, ny, nz);

    float phN = acos_fast(fminf(fmaxf(ny, -1.0f), 1.0f));
    float thN = atan2_fast(nx, -nz);
    float fiN = phN * ((float)NPH / PI_F);
    float tN  = thN * (0.5f / PI_F);
    float fjN = (tN - floorf(tN)) * (float)NTH;

    int iN = (int)fiN; iN = iN > (NPH - 1) ? (NPH - 1) : iN;
    int jN = (int)fjN; jN = jN > (NTH - 1) ? (NTH - 1) : jN;
    float wi = fiN - (float)iN;
    float wj = fjN - (float)jN;

    const float4* Tb = table + (size_t)b * NODESTRIDE;
    int idx = iN * COLS + jN;
    float4 t00 = Tb[idx];
    float4 t01 = Tb[idx + 1];
    float4 t10 = Tb[idx + COLS];
    float4 t11 = Tb[idx + COLS + 1];

    float w00 = (1.0f - wi) * (1.0f - wj);
    float w01 = (1.0f - wi) * wj;
    float w10 = wi * (1.0f - wj);
    float w11 = wi * wj;
    float r0 = t00.x * w00 + t01.x * w01 + t10.x * w10 + t11.x * w11;
    float r1 = t00.y * w00 + t01.y * w01 + t10.y * w10 + t11.y * w11;
    float r2 = t00.z * w00 + t01.z * w01 + t10.z * w10 + t11.z * w11;

    float* ob = out + (size_t)b * 3 * HWPX;
    ob[0 * HWPX + pix_in_b] = r0 * scl;
    ob[1 * HWPX + pix_in_b] = r1 * scl;
    ob[2 * HWPX + pix_in_b] = r2 * scl;
}

// ================= Fallback exact path (R13) for small ws =================
__global__ void k_setup_fb(const float* __restrict__ env,
                           float* __restrict__ tabq) {
    int m = threadIdx.x;
    int p = m >> 5;
    if (p < 1) return;
    float hx, hy, hz, sp;
    light_h(m, hx, hy, hz, sp);
    float c = sp * (1.0f / 60.0f);
    int ms = m - 32;
    int j = ms >> 1;
    int slot = ms & 1;
    #pragma unroll
    for (int b = 0; b < NB; ++b) {
        const float* e = env + ((size_t)(b * NL + m)) * 3;
        float* dst = tabq + ((size_t)(b * NPAIR + j)) * 12 + slot;
        dst[0]  = hx;
        dst[2]  = hy;
        dst[4]  = hz;
        dst[6]  = e[0] * c;
        dst[8]  = e[1] * c;
        dst[10] = e[2] * c;
    }
}

__global__ __launch_bounds__(256) void k_fused_fb(const float* __restrict__ normal,
                                                  const float* __restrict__ tabq,
                                                  float* __restrict__ out,
                                                  float* __restrict__ blockmax) {
    __shared__ float smerge[3 * 64 * 13];
    __shared__ float swmax[4];
    int tid = threadIdx.x, bid = blockIdx.x;
    int bpb = HWPX / 256;
    int b = bid / bpb;
    int g = tid >> 6;
    int li = tid & 63;
    int base_in_b = (bid % bpb) * 256 + li;
    int toff = __builtin_amdgcn_readfirstlane((b * NPAIR + g * GPAIR) * 12);
    const float* Tw = tabq + toff;

    float nxs[4], nys[4], nzs[4];
    #pragma unroll
    for (int k = 0; k < 4; ++k)
        load_normal(normal, (size_t)b * HWPX + base_in_b + k * 64, nxs[k], nys[k], nzs[k]);
    f2 nx2[4], ny2[4], nz2[4];
    #pragma unroll
    for (int k = 0; k < 4; ++k) {
        nx2[k] = f2{nxs[k], nxs[k]};
        ny2[k] = f2{nys[k], nys[k]};
        nz2[k] = f2{nzs[k], nzs[k]};
    }
    float mx64 = 0.0f;
    if (g == 0) {
        #pragma unroll
        for (int k = 0; k < 4; ++k) {
            float s0 = fmaxf((nys[k] + nzs[k]) * INV_SQRT2, 0.0f);
            mx64 = fmaxf(mx64, pow64(s0));
        }
    }
    f2 a0[4], a1[4], a2[4];
    #pragma unroll
    for (int k = 0; k < 4; ++k) { a0[k] = f2{0,0}; a1[k] = f2{0,0}; a2[k] = f2{0,0}; }
    #pragma unroll 4
    for (int j = 0; j < GPAIR; ++j) {
        const f2* P = reinterpret_cast<const f2*>(Tw + j * 12);
        f2 hx2 = P[0], hy2 = P[1], hz2 = P[2];
        f2 e02 = P[3], e12 = P[4], e22 = P[5];
        #pragma unroll
        for (int k = 0; k < 4; ++k) {
            f2 s = __builtin_elementwise_fma(nx2[k], hx2,
                   __builtin_elementwise_fma(ny2[k], hy2, nz2[k] * hz2));
            float sx = fmaxf(s.x, 0.0f);
            float sy = fmaxf(s.y, 0.0f);
            f2 r = {sx, sy};
            f2 r2  = r * r;
            f2 r4  = r2 * r2;
            f2 r8  = r4 * r4;
            f2 r16 = r8 * r8;
            f2 r32 = r16 * r16;
            f2 r64 = r32 * r32;
            mx64 = fmaxf(mx64, fmaxf(r64.x, r64.y));
            a0[k] = __builtin_elementwise_fma(r64, e02, a0[k]);
            a1[k] = __builtin_elementwise_fma(r64, e12, a1[k]);
            a2[k] = __builtin_elementwise_fma(r64, e22, a2[k]);
        }
    }
    float b0[4], b1[4], b2[4];
    #pragma unroll
    for (int k = 0; k < 4; ++k) {
        b0[k] = a0[k].x + a0[k].y;
        b1[k] = a1[k].x + a1[k].y;
        b2[k] = a2[k].x + a2[k].y;
    }
    #pragma unroll
    for (int off = 32; off > 0; off >>= 1)
        mx64 = fmaxf(mx64, __shfl_xor(mx64, off));
    if (li == 0) swmax[g] = mx64;
    if (g > 0) {
        float* dst = smerge + (size_t)(g - 1) * (64 * 13) + li * 13;
        #pragma unroll
        for (int k = 0; k < 4; ++k) {
            dst[k] = b0[k]; dst[k + 4] = b1[k]; dst[k + 8] = b2[k];
        }
    }
    __syncthreads();
    if (tid == 0)
        blockmax[bid] = fmaxf(fmaxf(swmax[0], swmax[1]), fmaxf(swmax[2], swmax[3]));
    if (g == 0) {
        #pragma unroll
        for (int gg = 0; gg < 3; ++gg) {
            const float* src = smerge + (size_t)gg * (64 * 13) + li * 13;
            #pragma unroll
            for (int k = 0; k < 4; ++k) {
                b0[k] += src[k]; b1[k] += src[k + 4]; b2[k] += src[k + 8];
            }
        }
        float* ob = out + (size_t)b * 3 * HWPX;
        #pragma unroll
        for (int k = 0; k < 4; ++k) {
            int p = base_in_b + k * 64;
            ob[0 * HWPX + p] = b0[k];
            ob[1 * HWPX + p] = b1[k];
            ob[2 * HWPX + p] = b2[k];
        }
    }
}

__global__ __launch_bounds__(256) void k_gmax_inv(const float* __restrict__ blockmax,
                                                  float* __restrict__ scale) {
    __shared__ float sm[4];
    int t = threadIdx.x;
    float m = 0.0f;
    #pragma unroll
    for (int i = 0; i < NBLK / 256; ++i)
        m = fmaxf(m, blockmax[t + i * 256]);
    #pragma unroll
    for (int off = 32; off > 0; off >>= 1)
        m = fmaxf(m, __shfl_xor(m, off));
    if ((t & 63) == 0) sm[t >> 6] = m;
    __syncthreads();
    if (t == 0) {
        m = fmaxf(fmaxf(sm[0], sm[1]), fmaxf(sm[2], sm[3]));
        *scale = 1.0f / m;
    }
}

__global__ __launch_bounds__(256) void k_finalize_fb(float* __restrict__ out,
                                                     const float* __restrict__ scale) {
    float scl = *scale;
    int i = blockIdx.x * 256 + (int)threadIdx.x;
    float4* o = reinterpret_cast<float4*>(out);
    float4 v = o[i];
    v.x *= scl; v.y *= scl; v.z *= scl; v.w *= scl;
    o[i] = v;
}

extern "C" void kernel_launch(void* const* d_in, const int* in_sizes, int n_in,
                              void* d_out, int out_size, void* d_ws, size_t ws_size,
                              hipStream_t stream) {
    const float* env    = (const float*)d_in[0];   // (B,16,32,3) f32
    const float* normal = (const float*)d_in[1];   // (B,512,512,3) f32
    float* out = (float*)d_out;                    // (B,3,512,512) f32

    char* ws = (char*)d_ws;
    float* scale = (float*)ws;

    size_t need = 16384 + (size_t)NB * NODESTRIDE * 16;   // ~2.40 MB

    if (ws_size >= need) {
        float* blockmax = (float*)(ws + 256);
        float4* table = (float4*)(ws + 16384);
        hipLaunchKernelGGL(k_pre, dim3(NBUILD + NBLK), dim3(256), 0, stream,
                           env, normal, table, blockmax);
        hipLaunchKernelGGL(k_gmax_pow, dim3(1), dim3(256), 0, stream, blockmax, scale);
        hipLaunchKernelGGL(k_render, dim3(NBLK), dim3(256), 0, stream,
                           normal, table, scale, out);
    } else {
        float* tabq = (float*)(ws + 256);
        float* blockmax = (float*)(ws + 24576);
        int fblocks = (NB * 3 * HWPX) / (4 * 256);
        hipLaunchKernelGGL(k_setup_fb, dim3(1), dim3(NL), 0, stream, env, tabq);
        hipLaunchKernelGGL(k_fused_fb, dim3(NBLK), dim3(256), 0, stream, normal, tabq, out, blockmax);
        hipLaunchKernelGGL(k_gmax_inv, dim3(1), dim3(256), 0, stream, blockmax, scale);
        hipLaunchKernelGGL(k_finalize_fb, dim3(fblocks), dim3(256), 0, stream, out, scale);
    }
}

// Round 19
// 40.537 us; speedup vs baseline: 1.8471x; 1.0262x over previous
//
#include <hip/hip_runtime.h>
#include <math.h>

// Problem constants (match reference)
#define HWPX (512*512)      // pixels per batch
#define NB 2                // batches
#define NL 512              // EH*EW light directions
#define NLS 480             // shadeable lights (phi=0 row: coeff 0)
#define NPAIR 240
#define GPAIR 60
#define NBLK 2048
// radiance-field table (lat-long in the lights' (phi,theta) parametrization)
#define NPH 192
#define NTH 384
#define ROWS (NPH + 1)
#define COLS (NTH + 1)
#define NODES (ROWS * COLS)            // 74305 per batch
#define BPB_BUILD 581
#define NBUILD (NB * BPB_BUILD)        // 1162 build blocks
#define NODESTRIDE (BPB_BUILD * 128)   // 74368
constexpr float PI_F   = 3.14159265358979323846f;
constexpr float TWO_PI = 6.28318530717958647692f;
constexpr float INV_SQRT2 = 0.70710678118654752f;

typedef float f2 __attribute__((ext_vector_type(2)));

// ws layout (bytes), main path:
//   [0]      (unused)
//   [256]    float blockmax[2048]            (8 KB)
//   [16384]  float4 table[2][NODESTRIDE]     (~2.38 MB unnormalized radiance field)
// Fallback path (ws too small): scale@0, tabq@256, blockmax@24576 (R13 exact).
//
// R18: 2 dispatches. k_pre = heterogeneous grid (table build | candidate max
// -> blockmax). k_render = in-block reduce of the 8KB blockmax (L2-resident,
// bit-identical plain-fmax order in every block) -> scale=(1/m)^64 -> bilinear
// lookup * scale -> final write. The 1-block gmax kernel and its launch gap
// are deleted.

// fast acos (A&S 4.4.45), |err| <= 6.7e-5 rad
__device__ __forceinline__ float acos_fast(float x) {
    float ax = fabsf(x);
    float r = sqrtf(fmaxf(1.0f - ax, 0.0f)) *
              (1.5707288f + ax * (-0.2121144f + ax * (0.0742610f - ax * 0.0187293f)));
    return x >= 0.0f ? r : PI_F - r;
}

// fast atan2(y,x), |err| ~1e-5 rad
__device__ __forceinline__ float atan2_fast(float y, float x) {
    float ay = fabsf(y), ax = fabsf(x);
    float mx = fmaxf(ay, ax), mn = fminf(ay, ax);
    float a = mn / fmaxf(mx, 1e-30f);
    float s = a * a;
    float r = a * (0.9998660f + s * (-0.3302995f + s * (0.1801410f +
              s * (-0.0851330f + s * 0.0208351f))));
    if (ay > ax) r = 1.5707963f - r;
    if (x < 0.0f) r = PI_F - r;
    return y < 0.0f ? -r : r;
}

// unit half-vector (and sin(phi)) for light index m in [0,512)
__device__ __forceinline__ void light_h(int m, float& hx, float& hy, float& hz, float& sp) {
    int p = m >> 5, t = m & 31;
    float phi = (float)p * (PI_F / 16.0f);
    float th  = (float)t * (TWO_PI / 32.0f);
    float spv, cpv, stv, ctv;
    sincosf(phi, &spv, &cpv);
    sincosf(th, &stv, &ctv);
    float x = stv * spv, y = cpv, z = 1.0f - ctv * spv;
    float inv = rsqrtf(x * x + y * y + z * z);
    hx = x * inv; hy = y * inv; hz = z * inv; sp = spv;
}

__device__ __forceinline__ void load_normal(const float* __restrict__ normal, size_t pix,
                                            float& nx, float& ny, float& nz) {
    const float* p = normal + pix * 3;
    float c0 = p[0], c1 = p[1], c2 = p[2];
    float x = (c2 - 0.5f) * 2.0f;
    float y = (c1 - 0.5f) * 2.0f;
    float z = (c0 - 0.5f) * 2.0f;
    float d2 = x * x + y * y + z * z;
    float inv = d2 > 0.0f ? rsqrtf(d2) : 0.0f;
    nx = x * inv; ny = y * inv; nz = z * inv;
}

__device__ __forceinline__ float pow64(float r) {
    float r2  = r * r;
    float r4  = r2 * r2;
    float r8  = r4 * r4;
    float r16 = r8 * r8;
    float r32 = r16 * r16;
    return r32 * r32;
}

// ---------- Pass 1: heterogeneous — table build OR candidate max ----------
__global__ __launch_bounds__(256) void k_pre(const float* __restrict__ env,
                                             const float* __restrict__ normal,
                                             float4* __restrict__ table,
                                             float* __restrict__ blockmax) {
    __shared__ float smem[NPAIR * 12];             // 11.25 KB (build: tabL / max: hvec)
    int tid = threadIdx.x, bid = blockIdx.x;

    if (bid < NBUILD) {
        // ======== BUILD path ========
        float* tabL = smem;
        __shared__ float smerge[3 * 64 * 7];
        int b = bid / BPB_BUILD;
        int blk = bid % BPB_BUILD;
        int g = tid >> 6;
        int li = tid & 63;
        int node0 = blk * 128 + li;

        for (int ms = tid; ms < NLS; ms += 256) {
            int m = ms + 32;                       // skip phi=0 row
            float hx, hy, hz, sp;
            light_h(m, hx, hy, hz, sp);
            float c = sp * (1.0f / 60.0f);
            const float* e = env + ((size_t)(b * NL + m)) * 3;
            float* dst = tabL + (ms >> 1) * 12 + (ms & 1);
            dst[0]  = hx;
            dst[2]  = hy;
            dst[4]  = hz;
            dst[6]  = e[0] * c;
            dst[8]  = e[1] * c;
            dst[10] = e[2] * c;
        }

        f2 nx2[2], ny2[2], nz2[2];
        #pragma unroll
        for (int k = 0; k < 2; ++k) {
            int node = node0 + k * 64;             // may overrun NODES (write guarded)
            int i = node / COLS;
            int j = node - i * COLS;
            float phi = (float)i * (PI_F / (float)NPH);
            float th  = (float)j * (TWO_PI / (float)NTH);
            float spv, cpv, stv, ctv;
            sincosf(phi, &spv, &cpv);
            sincosf(th, &stv, &ctv);
            float dx = stv * spv;
            float dy = cpv;
            float dz = -ctv * spv;
            nx2[k] = f2{dx, dx}; ny2[k] = f2{dy, dy}; nz2[k] = f2{dz, dz};
        }
        __syncthreads();

        f2 a0[2], a1[2], a2[2];
        #pragma unroll
        for (int k = 0; k < 2; ++k) { a0[k] = f2{0,0}; a1[k] = f2{0,0}; a2[k] = f2{0,0}; }

        const float4* Tg = reinterpret_cast<const float4*>(tabL) + (size_t)g * (GPAIR * 3);
        #pragma unroll 4
        for (int j = 0; j < GPAIR; ++j) {
            float4 A = Tg[j * 3 + 0];
            float4 B = Tg[j * 3 + 1];
            float4 C = Tg[j * 3 + 2];
            f2 hx2 = {A.x, A.y}, hy2 = {A.z, A.w}, hz2 = {B.x, B.y};
            f2 e02 = {B.z, B.w}, e12 = {C.x, C.y}, e22 = {C.z, C.w};
            #pragma unroll
            for (int k = 0; k < 2; ++k) {
                f2 s = __builtin_elementwise_fma(nx2[k], hx2,
                       __builtin_elementwise_fma(ny2[k], hy2, nz2[k] * hz2));
                float sx = fmaxf(s.x, 0.0f);
                float sy = fmaxf(s.y, 0.0f);
                f2 r = {sx, sy};
                f2 r2  = r * r;
                f2 r4  = r2 * r2;
                f2 r8  = r4 * r4;
                f2 r16 = r8 * r8;
                f2 r32 = r16 * r16;
                f2 r64 = r32 * r32;
                a0[k] = __builtin_elementwise_fma(r64, e02, a0[k]);
                a1[k] = __builtin_elementwise_fma(r64, e12, a1[k]);
                a2[k] = __builtin_elementwise_fma(r64, e22, a2[k]);
            }
        }

        float b0[2], b1[2], b2[2];
        #pragma unroll
        for (int k = 0; k < 2; ++k) {
            b0[k] = a0[k].x + a0[k].y;
            b1[k] = a1[k].x + a1[k].y;
            b2[k] = a2[k].x + a2[k].y;
        }

        if (g > 0) {
            float* dst = smerge + (size_t)(g - 1) * (64 * 7) + li * 7;
            #pragma unroll
            for (int k = 0; k < 2; ++k) {
                dst[k * 3 + 0] = b0[k];
                dst[k * 3 + 1] = b1[k];
                dst[k * 3 + 2] = b2[k];
            }
        }
        __syncthreads();

        if (g == 0) {
            #pragma unroll
            for (int gg = 0; gg < 3; ++gg) {
                const float* src = smerge + (size_t)gg * (64 * 7) + li * 7;
                #pragma unroll
                for (int k = 0; k < 2; ++k) {
                    b0[k] += src[k * 3 + 0];
                    b1[k] += src[k * 3 + 1];
                    b2[k] += src[k * 3 + 2];
                }
            }
            #pragma unroll
            for (int k = 0; k < 2; ++k) {
                int node = node0 + k * 64;
                if (node < NODES) {
                    float4 v; v.x = b0[k]; v.y = b1[k]; v.z = b2[k]; v.w = 0.0f;
                    table[(size_t)b * NODESTRIDE + node] = v;
                }
            }
        }
    } else {
        // ======== MAX path ========
        float4* sh = reinterpret_cast<float4*>(smem);   // 8 KB half-vectors
        __shared__ float swmax[4];
        int mbid = bid - NBUILD;                   // 0..NBLK-1
        int b = mbid >> 10;
        int pix_in_b = (mbid & 1023) * 256 + tid;

        for (int m = tid; m < NL; m += 256) {
            float hx, hy, hz, sp;
            light_h(m, hx, hy, hz, sp);
            float4 hv; hv.x = hx; hv.y = hy; hv.z = hz; hv.w = 0.0f;
            sh[m] = hv;
        }

        float nx, ny, nz;
        load_normal(normal, (size_t)b * HWPX + pix_in_b, nx, ny, nz);
        __syncthreads();

        // invert: l = 2*nz*n - v (reflection about h=n)
        float lx = 2.0f * nz * nx;
        float ly = 2.0f * nz * ny;
        float lz = 2.0f * nz * nz - 1.0f;
        float fi = acos_fast(fminf(fmaxf(ly, -1.0f), 1.0f)) * (16.0f / PI_F);
        float th = atan2_fast(lx, -lz);
        float tt = th * (0.5f / PI_F);
        float fj = (tt - floorf(tt)) * 32.0f;
        int i0 = (int)floorf(fi) - 1;
        int j0 = (int)floorf(fj) - 1;

        float mx = 0.0f;
        #pragma unroll
        for (int di = 0; di < 4; ++di) {
            int i = i0 + di;
            i = i < 0 ? 0 : (i > 15 ? 15 : i);
            #pragma unroll
            for (int dj = 0; dj < 4; ++dj) {
                int j = (j0 + dj) & 31;
                float4 h = sh[i * 32 + j];
                mx = fmaxf(mx, fmaf(nx, h.x, fmaf(ny, h.y, nz * h.z)));
            }
        }
        #pragma unroll
        for (int di = 0; di < 3; ++di) {           // singular ring around (8,0)
            int i = 7 + di;
            #pragma unroll
            for (int dj = 0; dj < 5; ++dj) {
                int j = (30 + dj) & 31;
                float4 h = sh[i * 32 + j];
                mx = fmaxf(mx, fmaf(nx, h.x, fmaf(ny, h.y, nz * h.z)));
            }
        }

        #pragma unroll
        for (int off = 32; off > 0; off >>= 1)
            mx = fmaxf(mx, __shfl_xor(mx, off));
        if ((tid & 63) == 0) swmax[tid >> 6] = mx;
        __syncthreads();
        if (tid == 0)
            blockmax[mbid] = fmaxf(fmaxf(swmax[0], swmax[1]), fmaxf(swmax[2], swmax[3]));
    }
}

// ---------- Pass 2: in-block gmax reduce + bilinear lookup -> final output ----------
__global__ __launch_bounds__(256) void k_render(const float* __restrict__ normal,
                                                const float4* __restrict__ table,
                                                const float* __restrict__ blockmax,
                                                float* __restrict__ out) {
    __shared__ float sred[4];
    int tid = threadIdx.x, bid = blockIdx.x;
    int b = bid >> 10;
    int pix_in_b = (bid & 1023) * 256 + tid;

    // in-block reduction of the 2048 block maxes (L2-resident, 8 loads/thread;
    // same values, same order in every block -> bit-identical scale)
    float m = 0.0f;
    #pragma unroll
    for (int i = 0; i < NBLK / 256; ++i)
        m = fmaxf(m, blockmax[tid + i * 256]);

    float nx, ny, nz;
    load_normal(normal, (size_t)b * HWPX + pix_in_b, nx, ny, nz);

    #pragma unroll
    for (int off = 32; off > 0; off >>= 1)
        m = fmaxf(m, __shfl_xor(m, off));
    if ((tid & 63) == 0) sred[tid >> 6] = m;
    __syncthreads();
    m = fmaxf(fmaxf(sred[0], sred[1]), fmaxf(sred[2], sred[3]));
    float scl = pow64(1.0f / m);

    float phN = acos_fast(fminf(fmaxf(ny, -1.0f), 1.0f));
    float thN = atan2_fast(nx, -nz);
    float fiN = phN * ((float)NPH / PI_F);
    float tN  = thN * (0.5f / PI_F);
    float fjN = (tN - floorf(tN)) * (float)NTH;

    int iN = (int)fiN; iN = iN > (NPH - 1) ? (NPH - 1) : iN;
    int jN = (int)fjN; jN = jN > (NTH - 1) ? (NTH - 1) : jN;
    float wi = fiN - (float)iN;
    float wj = fjN - (float)jN;

    const float4* Tb = table + (size_t)b * NODESTRIDE;
    int idx = iN * COLS + jN;
    float4 t00 = Tb[idx];
    float4 t01 = Tb[idx + 1];
    float4 t10 = Tb[idx + COLS];
    float4 t11 = Tb[idx + COLS + 1];

    float w00 = (1.0f - wi) * (1.0f - wj);
    float w01 = (1.0f - wi) * wj;
    float w10 = wi * (1.0f - wj);
    float w11 = wi * wj;
    float r0 = t00.x * w00 + t01.x * w01 + t10.x * w10 + t11.x * w11;
    float r1 = t00.y * w00 + t01.y * w01 + t10.y * w10 + t11.y * w11;
    float r2 = t00.z * w00 + t01.z * w01 + t10.z * w10 + t11.z * w11;

    float* ob = out + (size_t)b * 3 * HWPX;
    ob[0 * HWPX + pix_in_b] = r0 * scl;
    ob[1 * HWPX + pix_in_b] = r1 * scl;
    ob[2 * HWPX + pix_in_b] = r2 * scl;
}

// ================= Fallback exact path (R13) for small ws =================
__global__ void k_setup_fb(const float* __restrict__ env,
                           float* __restrict__ tabq) {
    int m = threadIdx.x;
    int p = m >> 5;
    if (p < 1) return;
    float hx, hy, hz, sp;
    light_h(m, hx, hy, hz, sp);
    float c = sp * (1.0f / 60.0f);
    int ms = m - 32;
    int j = ms >> 1;
    int slot = ms & 1;
    #pragma unroll
    for (int b = 0; b < NB; ++b) {
        const float* e = env + ((size_t)(b * NL + m)) * 3;
        float* dst = tabq + ((size_t)(b * NPAIR + j)) * 12 + slot;
        dst[0]  = hx;
        dst[2]  = hy;
        dst[4]  = hz;
        dst[6]  = e[0] * c;
        dst[8]  = e[1] * c;
        dst[10] = e[2] * c;
    }
}

__global__ __launch_bounds__(256) void k_fused_fb(const float* __restrict__ normal,
                                                  const float* __restrict__ tabq,
                                                  float* __restrict__ out,
                                                  float* __restrict__ blockmax) {
    __shared__ float smerge[3 * 64 * 13];
    __shared__ float swmax[4];
    int tid = threadIdx.x, bid = blockIdx.x;
    int bpb = HWPX / 256;
    int b = bid / bpb;
    int g = tid >> 6;
    int li = tid & 63;
    int base_in_b = (bid % bpb) * 256 + li;
    int toff = __builtin_amdgcn_readfirstlane((b * NPAIR + g * GPAIR) * 12);
    const float* Tw = tabq + toff;

    float nxs[4], nys[4], nzs[4];
    #pragma unroll
    for (int k = 0; k < 4; ++k)
        load_normal(normal, (size_t)b * HWPX + base_in_b + k * 64, nxs[k], nys[k], nzs[k]);
    f2 nx2[4], ny2[4], nz2[4];
    #pragma unroll
    for (int k = 0; k < 4; ++k) {
        nx2[k] = f2{nxs[k], nxs[k]};
        ny2[k] = f2{nys[k], nys[k]};
        nz2[k] = f2{nzs[k], nzs[k]};
    }
    float mx64 = 0.0f;
    if (g == 0) {
        #pragma unroll
        for (int k = 0; k < 4; ++k) {
            float s0 = fmaxf((nys[k] + nzs[k]) * INV_SQRT2, 0.0f);
            mx64 = fmaxf(mx64, pow64(s0));
        }
    }
    f2 a0[4], a1[4], a2[4];
    #pragma unroll
    for (int k = 0; k < 4; ++k) { a0[k] = f2{0,0}; a1[k] = f2{0,0}; a2[k] = f2{0,0}; }
    #pragma unroll 4
    for (int j = 0; j < GPAIR; ++j) {
        const f2* P = reinterpret_cast<const f2*>(Tw + j * 12);
        f2 hx2 = P[0], hy2 = P[1], hz2 = P[2];
        f2 e02 = P[3], e12 = P[4], e22 = P[5];
        #pragma unroll
        for (int k = 0; k < 4; ++k) {
            f2 s = __builtin_elementwise_fma(nx2[k], hx2,
                   __builtin_elementwise_fma(ny2[k], hy2, nz2[k] * hz2));
            float sx = fmaxf(s.x, 0.0f);
            float sy = fmaxf(s.y, 0.0f);
            f2 r = {sx, sy};
            f2 r2  = r * r;
            f2 r4  = r2 * r2;
            f2 r8  = r4 * r4;
            f2 r16 = r8 * r8;
            f2 r32 = r16 * r16;
            f2 r64 = r32 * r32;
            mx64 = fmaxf(mx64, fmaxf(r64.x, r64.y));
            a0[k] = __builtin_elementwise_fma(r64, e02, a0[k]);
            a1[k] = __builtin_elementwise_fma(r64, e12, a1[k]);
            a2[k] = __builtin_elementwise_fma(r64, e22, a2[k]);
        }
    }
    float b0[4], b1[4], b2[4];
    #pragma unroll
    for (int k = 0; k < 4; ++k) {
        b0[k] = a0[k].x + a0[k].y;
        b1[k] = a1[k].x + a1[k].y;
        b2[k] = a2[k].x + a2[k].y;
    }
    #pragma unroll
    for (int off = 32; off > 0; off >>= 1)
        mx64 = fmaxf(mx64, __shfl_xor(mx64, off));
    if (li == 0) swmax[g] = mx64;
    if (g > 0) {
        float* dst = smerge + (size_t)(g - 1) * (64 * 13) + li * 13;
        #pragma unroll
        for (int k = 0; k < 4; ++k) {
            dst[k] = b0[k]; dst[k + 4] = b1[k]; dst[k + 8] = b2[k];
        }
    }
    __syncthreads();
    if (tid == 0)
        blockmax[bid] = fmaxf(fmaxf(swmax[0], swmax[1]), fmaxf(swmax[2], swmax[3]));
    if (g == 0) {
        #pragma unroll
        for (int gg = 0; gg < 3; ++gg) {
            const float* src = smerge + (size_t)gg * (64 * 13) + li * 13;
            #pragma unroll
            for (int k = 0; k < 4; ++k) {
                b0[k] += src[k]; b1[k] += src[k + 4]; b2[k] += src[k + 8];
            }
        }
        float* ob = out + (size_t)b * 3 * HWPX;
        #pragma unroll
        for (int k = 0; k < 4; ++k) {
            int p = base_in_b + k * 64;
            ob[0 * HWPX + p] = b0[k];
            ob[1 * HWPX + p] = b1[k];
            ob[2 * HWPX + p] = b2[k];
        }
    }
}

__global__ __launch_bounds__(256) void k_gmax_inv(const float* __restrict__ blockmax,
                                                  float* __restrict__ scale) {
    __shared__ float sm[4];
    int t = threadIdx.x;
    float m = 0.0f;
    #pragma unroll
    for (int i = 0; i < NBLK / 256; ++i)
        m = fmaxf(m, blockmax[t + i * 256]);
    #pragma unroll
    for (int off = 32; off > 0; off >>= 1)
        m = fmaxf(m, __shfl_xor(m, off));
    if ((t & 63) == 0) sm[t >> 6] = m;
    __syncthreads();
    if (t == 0) {
        m = fmaxf(fmaxf(sm[0], sm[1]), fmaxf(sm[2], sm[3]));
        *scale = 1.0f / m;
    }
}

__global__ __launch_bounds__(256) void k_finalize_fb(float* __restrict__ out,
                                                     const float* __restrict__ scale) {
    float scl = *scale;
    int i = blockIdx.x * 256 + (int)threadIdx.x;
    float4* o = reinterpret_cast<float4*>(out);
    float4 v = o[i];
    v.x *= scl; v.y *= scl; v.z *= scl; v.w *= scl;
    o[i] = v;
}

extern "C" void kernel_launch(void* const* d_in, const int* in_sizes, int n_in,
                              void* d_out, int out_size, void* d_ws, size_t ws_size,
                              hipStream_t stream) {
    const float* env    = (const float*)d_in[0];   // (B,16,32,3) f32
    const float* normal = (const float*)d_in[1];   // (B,512,512,3) f32
    float* out = (float*)d_out;                    // (B,3,512,512) f32

    char* ws = (char*)d_ws;

    size_t need = 16384 + (size_t)NB * NODESTRIDE * 16;   // ~2.40 MB

    if (ws_size >= need) {
        float* blockmax = (float*)(ws + 256);
        float4* table = (float4*)(ws + 16384);
        hipLaunchKernelGGL(k_pre, dim3(NBUILD + NBLK), dim3(256), 0, stream,
                           env, normal, table, blockmax);
        hipLaunchKernelGGL(k_render, dim3(NBLK), dim3(256), 0, stream,
                           normal, table, blockmax, out);
    } else {
        float* scale = (float*)ws;
        float* tabq = (float*)(ws + 256);
        float* blockmax = (float*)(ws + 24576);
        int fblocks = (NB * 3 * HWPX) / (4 * 256);
        hipLaunchKernelGGL(k_setup_fb, dim3(1), dim3(NL), 0, stream, env, tabq);
        hipLaunchKernelGGL(k_fused_fb, dim3(NBLK), dim3(256), 0, stream, normal, tabq, out, blockmax);
        hipLaunchKernelGGL(k_gmax_inv, dim3(1), dim3(256), 0, stream, blockmax, scale);
        hipLaunchKernelGGL(k_finalize_fb, dim3(fblocks), dim3(256), 0, stream, out, scale);
    }
}

// Round 20
// 26.883 us; speedup vs baseline: 2.7853x; 1.5079x over previous
//
#include <hip/hip_runtime.h>
#include <math.h>

// Problem constants (match reference)
#define HWPX (512*512)      // pixels per batch
#define NB 2                // batches
#define NL 512              // EH*EW light directions
#define NLS 480             // shadeable lights (phi=0 row: coeff 0)
#define NPAIR 240
#define GPAIR 60
#define NBLK 2048
// radiance-field table (lat-long in the lights' (phi,theta) parametrization)
// R19: 96x192 (was 192x384). Bilinear err ~ 1.07*Delta^2/8 = 1.4e-4 abs —
// per-light table contribution is bounded by e*sin(phi)/60 <= 0.017, so the
// cos^64 lobe's curvature is ~1.07 in output units, not 64.
#define NPH 96
#define NTH 192
#define ROWS (NPH + 1)                 // 97
#define COLS (NTH + 1)                 // 193 (theta wrap duplicate)
#define NODES (ROWS * COLS)            // 18721 per batch
#define BPB_BUILD 147                  // ceil(NODES/128)
#define NBUILD (NB * BPB_BUILD)        // 294 build blocks
#define NODESTRIDE (BPB_BUILD * 128)   // 18816
constexpr float PI_F   = 3.14159265358979323846f;
constexpr float TWO_PI = 6.28318530717958647692f;
constexpr float INV_SQRT2 = 0.70710678118654752f;

typedef float f2 __attribute__((ext_vector_type(2)));

// ws layout (bytes), main path:
//   [256]    float blockmax[2048]            (8 KB)
//   [16384]  float4 table[2][NODESTRIDE]     (~600 KB unnormalized radiance field)
// Fallback path (ws too small): scale@0, tabq@256, blockmax@24576 (R13 exact).
//
// 2 dispatches. k_pre = heterogeneous grid (table build | candidate max ->
// blockmax). k_render = in-block reduce of the 8KB blockmax (L2-resident,
// bit-identical plain-fmax order in every block) -> scale=(1/m)^64 -> bilinear
// lookup * scale -> final write.

// fast acos (A&S 4.4.45), |err| <= 6.7e-5 rad
__device__ __forceinline__ float acos_fast(float x) {
    float ax = fabsf(x);
    float r = sqrtf(fmaxf(1.0f - ax, 0.0f)) *
              (1.5707288f + ax * (-0.2121144f + ax * (0.0742610f - ax * 0.0187293f)));
    return x >= 0.0f ? r : PI_F - r;
}

// fast atan2(y,x), |err| ~1e-5 rad
__device__ __forceinline__ float atan2_fast(float y, float x) {
    float ay = fabsf(y), ax = fabsf(x);
    float mx = fmaxf(ay, ax), mn = fminf(ay, ax);
    float a = mn / fmaxf(mx, 1e-30f);
    float s = a * a;
    float r = a * (0.9998660f + s * (-0.3302995f + s * (0.1801410f +
              s * (-0.0851330f + s * 0.0208351f))));
    if (ay > ax) r = 1.5707963f - r;
    if (x < 0.0f) r = PI_F - r;
    return y < 0.0f ? -r : r;
}

// unit half-vector (and sin(phi)) for light index m in [0,512)
__device__ __forceinline__ void light_h(int m, float& hx, float& hy, float& hz, float& sp) {
    int p = m >> 5, t = m & 31;
    float phi = (float)p * (PI_F / 16.0f);
    float th  = (float)t * (TWO_PI / 32.0f);
    float spv, cpv, stv, ctv;
    sincosf(phi, &spv, &cpv);
    sincosf(th, &stv, &ctv);
    float x = stv * spv, y = cpv, z = 1.0f - ctv * spv;
    float inv = rsqrtf(x * x + y * y + z * z);
    hx = x * inv; hy = y * inv; hz = z * inv; sp = spv;
}

__device__ __forceinline__ void load_normal(const float* __restrict__ normal, size_t pix,
                                            float& nx, float& ny, float& nz) {
    const float* p = normal + pix * 3;
    float c0 = p[0], c1 = p[1], c2 = p[2];
    float x = (c2 - 0.5f) * 2.0f;
    float y = (c1 - 0.5f) * 2.0f;
    float z = (c0 - 0.5f) * 2.0f;
    float d2 = x * x + y * y + z * z;
    float inv = d2 > 0.0f ? rsqrtf(d2) : 0.0f;
    nx = x * inv; ny = y * inv; nz = z * inv;
}

__device__ __forceinline__ float pow64(float r) {
    float r2  = r * r;
    float r4  = r2 * r2;
    float r8  = r4 * r4;
    float r16 = r8 * r8;
    float r32 = r16 * r16;
    return r32 * r32;
}

// ---------- Pass 1: heterogeneous — table build OR candidate max ----------
__global__ __launch_bounds__(256) void k_pre(const float* __restrict__ env,
                                             const float* __restrict__ normal,
                                             float4* __restrict__ table,
                                             float* __restrict__ blockmax) {
    __shared__ float smem[NPAIR * 12];             // 11.25 KB (build: tabL / max: hvec)
    int tid = threadIdx.x, bid = blockIdx.x;

    if (bid < NBUILD) {
        // ======== BUILD path ========
        float* tabL = smem;
        __shared__ float smerge[3 * 64 * 7];
        int b = bid / BPB_BUILD;
        int blk = bid % BPB_BUILD;
        int g = tid >> 6;
        int li = tid & 63;
        int node0 = blk * 128 + li;

        for (int ms = tid; ms < NLS; ms += 256) {
            int m = ms + 32;                       // skip phi=0 row
            float hx, hy, hz, sp;
            light_h(m, hx, hy, hz, sp);
            float c = sp * (1.0f / 60.0f);
            const float* e = env + ((size_t)(b * NL + m)) * 3;
            float* dst = tabL + (ms >> 1) * 12 + (ms & 1);
            dst[0]  = hx;
            dst[2]  = hy;
            dst[4]  = hz;
            dst[6]  = e[0] * c;
            dst[8]  = e[1] * c;
            dst[10] = e[2] * c;
        }

        f2 nx2[2], ny2[2], nz2[2];
        #pragma unroll
        for (int k = 0; k < 2; ++k) {
            int node = node0 + k * 64;             // may overrun NODES (write guarded)
            int i = node / COLS;
            int j = node - i * COLS;
            float phi = (float)i * (PI_F / (float)NPH);
            float th  = (float)j * (TWO_PI / (float)NTH);
            float spv, cpv, stv, ctv;
            sincosf(phi, &spv, &cpv);
            sincosf(th, &stv, &ctv);
            float dx = stv * spv;
            float dy = cpv;
            float dz = -ctv * spv;
            nx2[k] = f2{dx, dx}; ny2[k] = f2{dy, dy}; nz2[k] = f2{dz, dz};
        }
        __syncthreads();

        f2 a0[2], a1[2], a2[2];
        #pragma unroll
        for (int k = 0; k < 2; ++k) { a0[k] = f2{0,0}; a1[k] = f2{0,0}; a2[k] = f2{0,0}; }

        const float4* Tg = reinterpret_cast<const float4*>(tabL) + (size_t)g * (GPAIR * 3);
        #pragma unroll 4
        for (int j = 0; j < GPAIR; ++j) {
            float4 A = Tg[j * 3 + 0];
            float4 B = Tg[j * 3 + 1];
            float4 C = Tg[j * 3 + 2];
            f2 hx2 = {A.x, A.y}, hy2 = {A.z, A.w}, hz2 = {B.x, B.y};
            f2 e02 = {B.z, B.w}, e12 = {C.x, C.y}, e22 = {C.z, C.w};
            #pragma unroll
            for (int k = 0; k < 2; ++k) {
                f2 s = __builtin_elementwise_fma(nx2[k], hx2,
                       __builtin_elementwise_fma(ny2[k], hy2, nz2[k] * hz2));
                float sx = fmaxf(s.x, 0.0f);
                float sy = fmaxf(s.y, 0.0f);
                f2 r = {sx, sy};
                f2 r2  = r * r;
                f2 r4  = r2 * r2;
                f2 r8  = r4 * r4;
                f2 r16 = r8 * r8;
                f2 r32 = r16 * r16;
                f2 r64 = r32 * r32;
                a0[k] = __builtin_elementwise_fma(r64, e02, a0[k]);
                a1[k] = __builtin_elementwise_fma(r64, e12, a1[k]);
                a2[k] = __builtin_elementwise_fma(r64, e22, a2[k]);
            }
        }

        float b0[2], b1[2], b2[2];
        #pragma unroll
        for (int k = 0; k < 2; ++k) {
            b0[k] = a0[k].x + a0[k].y;
            b1[k] = a1[k].x + a1[k].y;
            b2[k] = a2[k].x + a2[k].y;
        }

        if (g > 0) {
            float* dst = smerge + (size_t)(g - 1) * (64 * 7) + li * 7;
            #pragma unroll
            for (int k = 0; k < 2; ++k) {
                dst[k * 3 + 0] = b0[k];
                dst[k * 3 + 1] = b1[k];
                dst[k * 3 + 2] = b2[k];
            }
        }
        __syncthreads();

        if (g == 0) {
            #pragma unroll
            for (int gg = 0; gg < 3; ++gg) {
                const float* src = smerge + (size_t)gg * (64 * 7) + li * 7;
                #pragma unroll
                for (int k = 0; k < 2; ++k) {
                    b0[k] += src[k * 3 + 0];
                    b1[k] += src[k * 3 + 1];
                    b2[k] += src[k * 3 + 2];
                }
            }
            #pragma unroll
            for (int k = 0; k < 2; ++k) {
                int node = node0 + k * 64;
                if (node < NODES) {
                    float4 v; v.x = b0[k]; v.y = b1[k]; v.z = b2[k]; v.w = 0.0f;
                    table[(size_t)b * NODESTRIDE + node] = v;
                }
            }
        }
    } else {
        // ======== MAX path ========
        float4* sh = reinterpret_cast<float4*>(smem);   // 8 KB half-vectors
        __shared__ float swmax[4];
        int mbid = bid - NBUILD;                   // 0..NBLK-1
        int b = mbid >> 10;
        int pix_in_b = (mbid & 1023) * 256 + tid;

        for (int m = tid; m < NL; m += 256) {
            float hx, hy, hz, sp;
            light_h(m, hx, hy, hz, sp);
            float4 hv; hv.x = hx; hv.y = hy; hv.z = hz; hv.w = 0.0f;
            sh[m] = hv;
        }

        float nx, ny, nz;
        load_normal(normal, (size_t)b * HWPX + pix_in_b, nx, ny, nz);
        __syncthreads();

        // invert: l = 2*nz*n - v (reflection about h=n)
        float lx = 2.0f * nz * nx;
        float ly = 2.0f * nz * ny;
        float lz = 2.0f * nz * nz - 1.0f;
        float fi = acos_fast(fminf(fmaxf(ly, -1.0f), 1.0f)) * (16.0f / PI_F);
        float th = atan2_fast(lx, -lz);
        float tt = th * (0.5f / PI_F);
        float fj = (tt - floorf(tt)) * 32.0f;
        int i0 = (int)floorf(fi) - 1;
        int j0 = (int)floorf(fj) - 1;

        float mx = 0.0f;
        #pragma unroll
        for (int di = 0; di < 4; ++di) {
            int i = i0 + di;
            i = i < 0 ? 0 : (i > 15 ? 15 : i);
            #pragma unroll
            for (int dj = 0; dj < 4; ++dj) {
                int j = (j0 + dj) & 31;
                float4 h = sh[i * 32 + j];
                mx = fmaxf(mx, fmaf(nx, h.x, fmaf(ny, h.y, nz * h.z)));
            }
        }
        #pragma unroll
        for (int di = 0; di < 3; ++di) {           // singular ring around (8,0)
            int i = 7 + di;
            #pragma unroll
            for (int dj = 0; dj < 5; ++dj) {
                int j = (30 + dj) & 31;
                float4 h = sh[i * 32 + j];
                mx = fmaxf(mx, fmaf(nx, h.x, fmaf(ny, h.y, nz * h.z)));
            }
        }

        #pragma unroll
        for (int off = 32; off > 0; off >>= 1)
            mx = fmaxf(mx, __shfl_xor(mx, off));
        if ((tid & 63) == 0) swmax[tid >> 6] = mx;
        __syncthreads();
        if (tid == 0)
            blockmax[mbid] = fmaxf(fmaxf(swmax[0], swmax[1]), fmaxf(swmax[2], swmax[3]));
    }
}

// ---------- Pass 2: in-block gmax reduce + bilinear lookup -> final output ----------
__global__ __launch_bounds__(256) void k_render(const float* __restrict__ normal,
                                                const float4* __restrict__ table,
                                                const float* __restrict__ blockmax,
                                                float* __restrict__ out) {
    __shared__ float sred[4];
    int tid = threadIdx.x, bid = blockIdx.x;
    int b = bid >> 10;
    int pix_in_b = (bid & 1023) * 256 + tid;

    // in-block reduction of the 2048 block maxes (L2-resident, 8 loads/thread;
    // same values, same order in every block -> bit-identical scale)
    float m = 0.0f;
    #pragma unroll
    for (int i = 0; i < NBLK / 256; ++i)
        m = fmaxf(m, blockmax[tid + i * 256]);

    float nx, ny, nz;
    load_normal(normal, (size_t)b * HWPX + pix_in_b, nx, ny, nz);

    #pragma unroll
    for (int off = 32; off > 0; off >>= 1)
        m = fmaxf(m, __shfl_xor(m, off));
    if ((tid & 63) == 0) sred[tid >> 6] = m;
    __syncthreads();
    m = fmaxf(fmaxf(sred[0], sred[1]), fmaxf(sred[2], sred[3]));
    float scl = pow64(1.0f / m);

    float phN = acos_fast(fminf(fmaxf(ny, -1.0f), 1.0f));
    float thN = atan2_fast(nx, -nz);
    float fiN = phN * ((float)NPH / PI_F);
    float tN  = thN * (0.5f / PI_F);
    float fjN = (tN - floorf(tN)) * (float)NTH;

    int iN = (int)fiN; iN = iN > (NPH - 1) ? (NPH - 1) : iN;
    int jN = (int)fjN; jN = jN > (NTH - 1) ? (NTH - 1) : jN;
    float wi = fiN - (float)iN;
    float wj = fjN - (float)jN;

    const float4* Tb = table + (size_t)b * NODESTRIDE;
    int idx = iN * COLS + jN;
    float4 t00 = Tb[idx];
    float4 t01 = Tb[idx + 1];
    float4 t10 = Tb[idx + COLS];
    float4 t11 = Tb[idx + COLS + 1];

    float w00 = (1.0f - wi) * (1.0f - wj);
    float w01 = (1.0f - wi) * wj;
    float w10 = wi * (1.0f - wj);
    float w11 = wi * wj;
    float r0 = t00.x * w00 + t01.x * w01 + t10.x * w10 + t11.x * w11;
    float r1 = t00.y * w00 + t01.y * w01 + t10.y * w10 + t11.y * w11;
    float r2 = t00.z * w00 + t01.z * w01 + t10.z * w10 + t11.z * w11;

    float* ob = out + (size_t)b * 3 * HWPX;
    ob[0 * HWPX + pix_in_b] = r0 * scl;
    ob[1 * HWPX + pix_in_b] = r1 * scl;
    ob[2 * HWPX + pix_in_b] = r2 * scl;
}

// ================= Fallback exact path (R13) for small ws =================
__global__ void k_setup_fb(const float* __restrict__ env,
                           float* __restrict__ tabq) {
    int m = threadIdx.x;
    int p = m >> 5;
    if (p < 1) return;
    float hx, hy, hz, sp;
    light_h(m, hx, hy, hz, sp);
    float c = sp * (1.0f / 60.0f);
    int ms = m - 32;
    int j = ms >> 1;
    int slot = ms & 1;
    #pragma unroll
    for (int b = 0; b < NB; ++b) {
        const float* e = env + ((size_t)(b * NL + m)) * 3;
        float* dst = tabq + ((size_t)(b * NPAIR + j)) * 12 + slot;
        dst[0]  = hx;
        dst[2]  = hy;
        dst[4]  = hz;
        dst[6]  = e[0] * c;
        dst[8]  = e[1] * c;
        dst[10] = e[2] * c;
    }
}

__global__ __launch_bounds__(256) void k_fused_fb(const float* __restrict__ normal,
                                                  const float* __restrict__ tabq,
                                                  float* __restrict__ out,
                                                  float* __restrict__ blockmax) {
    __shared__ float smerge[3 * 64 * 13];
    __shared__ float swmax[4];
    int tid = threadIdx.x, bid = blockIdx.x;
    int bpb = HWPX / 256;
    int b = bid / bpb;
    int g = tid >> 6;
    int li = tid & 63;
    int base_in_b = (bid % bpb) * 256 + li;
    int toff = __builtin_amdgcn_readfirstlane((b * NPAIR + g * GPAIR) * 12);
    const float* Tw = tabq + toff;

    float nxs[4], nys[4], nzs[4];
    #pragma unroll
    for (int k = 0; k < 4; ++k)
        load_normal(normal, (size_t)b * HWPX + base_in_b + k * 64, nxs[k], nys[k], nzs[k]);
    f2 nx2[4], ny2[4], nz2[4];
    #pragma unroll
    for (int k = 0; k < 4; ++k) {
        nx2[k] = f2{nxs[k], nxs[k]};
        ny2[k] = f2{nys[k], nys[k]};
        nz2[k] = f2{nzs[k], nzs[k]};
    }
    float mx64 = 0.0f;
    if (g == 0) {
        #pragma unroll
        for (int k = 0; k < 4; ++k) {
            float s0 = fmaxf((nys[k] + nzs[k]) * INV_SQRT2, 0.0f);
            mx64 = fmaxf(mx64, pow64(s0));
        }
    }
    f2 a0[4], a1[4], a2[4];
    #pragma unroll
    for (int k = 0; k < 4; ++k) { a0[k] = f2{0,0}; a1[k] = f2{0,0}; a2[k] = f2{0,0}; }
    #pragma unroll 4
    for (int j = 0; j < GPAIR; ++j) {
        const f2* P = reinterpret_cast<const f2*>(Tw + j * 12);
        f2 hx2 = P[0], hy2 = P[1], hz2 = P[2];
        f2 e02 = P[3], e12 = P[4], e22 = P[5];
        #pragma unroll
        for (int k = 0; k < 4; ++k) {
            f2 s = __builtin_elementwise_fma(nx2[k], hx2,
                   __builtin_elementwise_fma(ny2[k], hy2, nz2[k] * hz2));
            float sx = fmaxf(s.x, 0.0f);
            float sy = fmaxf(s.y, 0.0f);
            f2 r = {sx, sy};
            f2 r2  = r * r;
            f2 r4  = r2 * r2;
            f2 r8  = r4 * r4;
            f2 r16 = r8 * r8;
            f2 r32 = r16 * r16;
            f2 r64 = r32 * r32;
            mx64 = fmaxf(mx64, fmaxf(r64.x, r64.y));
            a0[k] = __builtin_elementwise_fma(r64, e02, a0[k]);
            a1[k] = __builtin_elementwise_fma(r64, e12, a1[k]);
            a2[k] = __builtin_elementwise_fma(r64, e22, a2[k]);
        }
    }
    float b0[4], b1[4], b2[4];
    #pragma unroll
    for (int k = 0; k < 4; ++k) {
        b0[k] = a0[k].x + a0[k].y;
        b1[k] = a1[k].x + a1[k].y;
        b2[k] = a2[k].x + a2[k].y;
    }
    #pragma unroll
    for (int off = 32; off > 0; off >>= 1)
        mx64 = fmaxf(mx64, __shfl_xor(mx64, off));
    if (li == 0) swmax[g] = mx64;
    if (g > 0) {
        float* dst = smerge + (size_t)(g - 1) * (64 * 13) + li * 13;
        #pragma unroll
        for (int k = 0; k < 4; ++k) {
            dst[k] = b0[k]; dst[k + 4] = b1[k]; dst[k + 8] = b2[k];
        }
    }
    __syncthreads();
    if (tid == 0)
        blockmax[bid] = fmaxf(fmaxf(swmax[0], swmax[1]), fmaxf(swmax[2], swmax[3]));
    if (g == 0) {
        #pragma unroll
        for (int gg = 0; gg < 3; ++gg) {
            const float* src = smerge + (size_t)gg * (64 * 13) + li * 13;
            #pragma unroll
            for (int k = 0; k < 4; ++k) {
                b0[k] += src[k]; b1[k] += src[k + 4]; b2[k] += src[k + 8];
            }
        }
        float* ob = out + (size_t)b * 3 * HWPX;
        #pragma unroll
        for (int k = 0; k < 4; ++k) {
            int p = base_in_b + k * 64;
            ob[0 * HWPX + p] = b0[k];
            ob[1 * HWPX + p] = b1[k];
            ob[2 * HWPX + p] = b2[k];
        }
    }
}

__global__ __launch_bounds__(256) void k_gmax_inv(const float* __restrict__ blockmax,
                                                  float* __restrict__ scale) {
    __shared__ float sm[4];
    int t = threadIdx.x;
    float m = 0.0f;
    #pragma unroll
    for (int i = 0; i < NBLK / 256; ++i)
        m = fmaxf(m, blockmax[t + i * 256]);
    #pragma unroll
    for (int off = 32; off > 0; off >>= 1)
        m = fmaxf(m, __shfl_xor(m, off));
    if ((t & 63) == 0) sm[t >> 6] = m;
    __syncthreads();
    if (t == 0) {
        m = fmaxf(fmaxf(sm[0], sm[1]), fmaxf(sm[2], sm[3]));
        *scale = 1.0f / m;
    }
}

__global__ __launch_bounds__(256) void k_finalize_fb(float* __restrict__ out,
                                                     const float* __restrict__ scale) {
    float scl = *scale;
    int i = blockIdx.x * 256 + (int)threadIdx.x;
    float4* o = reinterpret_cast<float4*>(out);
    float4 v = o[i];
    v.x *= scl; v.y *= scl; v.z *= scl; v.w *= scl;
    o[i] = v;
}

extern "C" void kernel_launch(void* const* d_in, const int* in_sizes, int n_in,
                              void* d_out, int out_size, void* d_ws, size_t ws_size,
                              hipStream_t stream) {
    const float* env    = (const float*)d_in[0];   // (B,16,32,3) f32
    const float* normal = (const float*)d_in[1];   // (B,512,512,3) f32
    float* out = (float*)d_out;                    // (B,3,512,512) f32

    char* ws = (char*)d_ws;

    size_t need = 16384 + (size_t)NB * NODESTRIDE * 16;   // ~620 KB

    if (ws_size >= need) {
        float* blockmax = (float*)(ws + 256);
        float4* table = (float4*)(ws + 16384);
        hipLaunchKernelGGL(k_pre, dim3(NBUILD + NBLK), dim3(256), 0, stream,
                           env, normal, table, blockmax);
        hipLaunchKernelGGL(k_render, dim3(NBLK), dim3(256), 0, stream,
                           normal, table, blockmax, out);
    } else {
        float* scale = (float*)ws;
        float* tabq = (float*)(ws + 256);
        float* blockmax = (float*)(ws + 24576);
        int fblocks = (NB * 3 * HWPX) / (4 * 256);
        hipLaunchKernelGGL(k_setup_fb, dim3(1), dim3(NL), 0, stream, env, tabq);
        hipLaunchKernelGGL(k_fused_fb, dim3(NBLK), dim3(256), 0, stream, normal, tabq, out, blockmax);
        hipLaunchKernelGGL(k_gmax_inv, dim3(1), dim3(256), 0, stream, blockmax, scale);
        hipLaunchKernelGGL(k_finalize_fb, dim3(fblocks), dim3(256), 0, stream, out, scale);
    }
}

// Round 21
// 24.221 us; speedup vs baseline: 3.0914x; 1.1099x over previous
//
#include <hip/hip_runtime.h>
#include <math.h>

// Problem constants (match reference)
#define HWPX (512*512)      // pixels per batch
#define NB 2                // batches
#define NL 512              // EH*EW light directions
#define NLS 480             // shadeable lights (phi=0 row: coeff 0)
#define NPAIR 240
#define GPAIR 60
#define NBLK 2048
// radiance-field table (lat-long in the lights' (phi,theta) parametrization)
// R20: 64x128 (was 96x192). Calibrated: at 96x192 interp err was <=2e-4
// (absmax stayed at the 4.88e-4 exact-path floor); 64x128 scales Delta^2 by
// 2.25x -> ~4.5e-4 predicted, threshold 2.089e-3.
#define NPH 64
#define NTH 128
#define ROWS (NPH + 1)                 // 65
#define COLS (NTH + 1)                 // 129 (theta wrap duplicate)
#define NODES (ROWS * COLS)            // 8385 per batch
#define BPB_BUILD 132                  // ceil(NODES/64) : 64 nodes per block
#define NBUILD (NB * BPB_BUILD)        // 264 build blocks
#define NODESTRIDE (BPB_BUILD * 64)    // 8448
constexpr float PI_F   = 3.14159265358979323846f;
constexpr float TWO_PI = 6.28318530717958647692f;
constexpr float INV_SQRT2 = 0.70710678118654752f;

typedef float f2 __attribute__((ext_vector_type(2)));

// ws layout (bytes), main path:
//   [256]    float blockmax[2048]            (8 KB)
//   [16384]  float4 table[2][NODESTRIDE]     (~270 KB unnormalized radiance field)
// Fallback path (ws too small): scale@0, tabq@256, blockmax@24576 (R13 exact).
//
// 2 dispatches. k_pre = heterogeneous grid (table build | candidate max ->
// blockmax). Build rebalanced (R20): 64 nodes/block, ONE node per thread
// (f2 packs light-pairs against splatted node dir) -> ~1.35us/block x 264
// blocks ~ 1.03/CU: the build tail hides under the 2048 max blocks.
// k_render = in-block reduce of blockmax -> scale=(1/m)^64 -> bilinear
// lookup * scale -> final write.

// fast acos (A&S 4.4.45), |err| <= 6.7e-5 rad
__device__ __forceinline__ float acos_fast(float x) {
    float ax = fabsf(x);
    float r = sqrtf(fmaxf(1.0f - ax, 0.0f)) *
              (1.5707288f + ax * (-0.2121144f + ax * (0.0742610f - ax * 0.0187293f)));
    return x >= 0.0f ? r : PI_F - r;
}

// fast atan2(y,x), |err| ~1e-5 rad
__device__ __forceinline__ float atan2_fast(float y, float x) {
    float ay = fabsf(y), ax = fabsf(x);
    float mx = fmaxf(ay, ax), mn = fminf(ay, ax);
    float a = mn / fmaxf(mx, 1e-30f);
    float s = a * a;
    float r = a * (0.9998660f + s * (-0.3302995f + s * (0.1801410f +
              s * (-0.0851330f + s * 0.0208351f))));
    if (ay > ax) r = 1.5707963f - r;
    if (x < 0.0f) r = PI_F - r;
    return y < 0.0f ? -r : r;
}

// unit half-vector (and sin(phi)) for light index m in [0,512)
__device__ __forceinline__ void light_h(int m, float& hx, float& hy, float& hz, float& sp) {
    int p = m >> 5, t = m & 31;
    float phi = (float)p * (PI_F / 16.0f);
    float th  = (float)t * (TWO_PI / 32.0f);
    float spv, cpv, stv, ctv;
    sincosf(phi, &spv, &cpv);
    sincosf(th, &stv, &ctv);
    float x = stv * spv, y = cpv, z = 1.0f - ctv * spv;
    float inv = rsqrtf(x * x + y * y + z * z);
    hx = x * inv; hy = y * inv; hz = z * inv; sp = spv;
}

__device__ __forceinline__ void load_normal(const float* __restrict__ normal, size_t pix,
                                            float& nx, float& ny, float& nz) {
    const float* p = normal + pix * 3;
    float c0 = p[0], c1 = p[1], c2 = p[2];
    float x = (c2 - 0.5f) * 2.0f;
    float y = (c1 - 0.5f) * 2.0f;
    float z = (c0 - 0.5f) * 2.0f;
    float d2 = x * x + y * y + z * z;
    float inv = d2 > 0.0f ? rsqrtf(d2) : 0.0f;
    nx = x * inv; ny = y * inv; nz = z * inv;
}

__device__ __forceinline__ float pow64(float r) {
    float r2  = r * r;
    float r4  = r2 * r2;
    float r8  = r4 * r4;
    float r16 = r8 * r8;
    float r32 = r16 * r16;
    return r32 * r32;
}

// ---------- Pass 1: heterogeneous — table build OR candidate max ----------
__global__ __launch_bounds__(256) void k_pre(const float* __restrict__ env,
                                             const float* __restrict__ normal,
                                             float4* __restrict__ table,
                                             float* __restrict__ blockmax) {
    __shared__ float smem[NPAIR * 12];             // 11.25 KB (build: tabL / max: hvec)
    int tid = threadIdx.x, bid = blockIdx.x;

    if (bid < NBUILD) {
        // ======== BUILD path: 64 nodes/block, 1 node/thread ========
        float* tabL = smem;
        __shared__ float smerge[3 * 64 * 5];       // partials, odd stride 5
        int b = bid / BPB_BUILD;
        int blk = bid % BPB_BUILD;
        int g = tid >> 6;                          // light quarter
        int li = tid & 63;                         // node lane
        int node = blk * 64 + li;                  // may overrun NODES (write guarded)

        // in-block light table generation (<=2 lights per thread)
        for (int ms = tid; ms < NLS; ms += 256) {
            int m = ms + 32;                       // skip phi=0 row
            float hx, hy, hz, sp;
            light_h(m, hx, hy, hz, sp);
            float c = sp * (1.0f / 60.0f);
            const float* e = env + ((size_t)(b * NL + m)) * 3;
            float* dst = tabL + (ms >> 1) * 12 + (ms & 1);
            dst[0]  = hx;
            dst[2]  = hy;
            dst[4]  = hz;
            dst[6]  = e[0] * c;
            dst[8]  = e[1] * c;
            dst[10] = e[2] * c;
        }

        // this thread's grid direction (splat into f2 lanes = light-pair lanes)
        int i = node / COLS;
        int j = node - i * COLS;
        float phi = (float)i * (PI_F / (float)NPH);
        float th  = (float)j * (TWO_PI / (float)NTH);
        float spv, cpv, stv, ctv;
        sincosf(phi, &spv, &cpv);
        sincosf(th, &stv, &ctv);
        f2 nx2 = f2{stv * spv, stv * spv};
        f2 ny2 = f2{cpv, cpv};
        f2 nz2 = f2{-ctv * spv, -ctv * spv};
        __syncthreads();

        f2 a0 = f2{0, 0}, a1 = f2{0, 0}, a2 = f2{0, 0};
        const float4* Tg = reinterpret_cast<const float4*>(tabL) + (size_t)g * (GPAIR * 3);
        #pragma unroll 4
        for (int jj = 0; jj < GPAIR; ++jj) {
            float4 A = Tg[jj * 3 + 0];             // {hx0,hx1,hy0,hy1}
            float4 B = Tg[jj * 3 + 1];             // {hz0,hz1,e00,e01}
            float4 C = Tg[jj * 3 + 2];             // {e10,e11,e20,e21}
            f2 hx2 = {A.x, A.y}, hy2 = {A.z, A.w}, hz2 = {B.x, B.y};
            f2 e02 = {B.z, B.w}, e12 = {C.x, C.y}, e22 = {C.z, C.w};
            f2 s = __builtin_elementwise_fma(nx2, hx2,
                   __builtin_elementwise_fma(ny2, hy2, nz2 * hz2));
            float sx = fmaxf(s.x, 0.0f);
            float sy = fmaxf(s.y, 0.0f);
            f2 r = {sx, sy};
            f2 r2  = r * r;
            f2 r4  = r2 * r2;
            f2 r8  = r4 * r4;
            f2 r16 = r8 * r8;
            f2 r32 = r16 * r16;
            f2 r64 = r32 * r32;
            a0 = __builtin_elementwise_fma(r64, e02, a0);
            a1 = __builtin_elementwise_fma(r64, e12, a1);
            a2 = __builtin_elementwise_fma(r64, e22, a2);
        }

        float b0 = a0.x + a0.y;
        float b1 = a1.x + a1.y;
        float b2 = a2.x + a2.y;

        if (g > 0) {
            float* dst = smerge + (size_t)(g - 1) * (64 * 5) + li * 5;
            dst[0] = b0; dst[1] = b1; dst[2] = b2;
        }
        __syncthreads();

        if (g == 0) {
            #pragma unroll
            for (int gg = 0; gg < 3; ++gg) {
                const float* src = smerge + (size_t)gg * (64 * 5) + li * 5;
                b0 += src[0]; b1 += src[1]; b2 += src[2];
            }
            if (node < NODES) {
                float4 v; v.x = b0; v.y = b1; v.z = b2; v.w = 0.0f;
                table[(size_t)b * NODESTRIDE + node] = v;
            }
        }
    } else {
        // ======== MAX path ========
        float4* sh = reinterpret_cast<float4*>(smem);   // 8 KB half-vectors
        __shared__ float swmax[4];
        int mbid = bid - NBUILD;                   // 0..NBLK-1
        int b = mbid >> 10;
        int pix_in_b = (mbid & 1023) * 256 + tid;

        for (int m = tid; m < NL; m += 256) {
            float hx, hy, hz, sp;
            light_h(m, hx, hy, hz, sp);
            float4 hv; hv.x = hx; hv.y = hy; hv.z = hz; hv.w = 0.0f;
            sh[m] = hv;
        }

        float nx, ny, nz;
        load_normal(normal, (size_t)b * HWPX + pix_in_b, nx, ny, nz);
        __syncthreads();

        // invert: l = 2*nz*n - v (reflection about h=n); light grid is 16x32
        float lx = 2.0f * nz * nx;
        float ly = 2.0f * nz * ny;
        float lz = 2.0f * nz * nz - 1.0f;
        float fi = acos_fast(fminf(fmaxf(ly, -1.0f), 1.0f)) * (16.0f / PI_F);
        float th = atan2_fast(lx, -lz);
        float tt = th * (0.5f / PI_F);
        float fj = (tt - floorf(tt)) * 32.0f;
        int i0 = (int)floorf(fi) - 1;
        int j0 = (int)floorf(fj) - 1;

        float mx = 0.0f;
        #pragma unroll
        for (int di = 0; di < 4; ++di) {
            int i = i0 + di;
            i = i < 0 ? 0 : (i > 15 ? 15 : i);
            #pragma unroll
            for (int dj = 0; dj < 4; ++dj) {
                int j = (j0 + dj) & 31;
                float4 h = sh[i * 32 + j];
                mx = fmaxf(mx, fmaf(nx, h.x, fmaf(ny, h.y, nz * h.z)));
            }
        }
        #pragma unroll
        for (int di = 0; di < 3; ++di) {           // singular ring around (8,0)
            int i = 7 + di;
            #pragma unroll
            for (int dj = 0; dj < 5; ++dj) {
                int j = (30 + dj) & 31;
                float4 h = sh[i * 32 + j];
                mx = fmaxf(mx, fmaf(nx, h.x, fmaf(ny, h.y, nz * h.z)));
            }
        }

        #pragma unroll
        for (int off = 32; off > 0; off >>= 1)
            mx = fmaxf(mx, __shfl_xor(mx, off));
        if ((tid & 63) == 0) swmax[tid >> 6] = mx;
        __syncthreads();
        if (tid == 0)
            blockmax[mbid] = fmaxf(fmaxf(swmax[0], swmax[1]), fmaxf(swmax[2], swmax[3]));
    }
}

// ---------- Pass 2: in-block gmax reduce + bilinear lookup -> final output ----------
__global__ __launch_bounds__(256) void k_render(const float* __restrict__ normal,
                                                const float4* __restrict__ table,
                                                const float* __restrict__ blockmax,
                                                float* __restrict__ out) {
    __shared__ float sred[4];
    int tid = threadIdx.x, bid = blockIdx.x;
    int b = bid >> 10;
    int pix_in_b = (bid & 1023) * 256 + tid;

    // in-block reduction of the 2048 block maxes (L2-resident, 8 loads/thread;
    // same values, same order in every block -> bit-identical scale)
    float m = 0.0f;
    #pragma unroll
    for (int i = 0; i < NBLK / 256; ++i)
        m = fmaxf(m, blockmax[tid + i * 256]);

    float nx, ny, nz;
    load_normal(normal, (size_t)b * HWPX + pix_in_b, nx, ny, nz);

    #pragma unroll
    for (int off = 32; off > 0; off >>= 1)
        m = fmaxf(m, __shfl_xor(m, off));
    if ((tid & 63) == 0) sred[tid >> 6] = m;
    __syncthreads();
    m = fmaxf(fmaxf(sred[0], sred[1]), fmaxf(sred[2], sred[3]));
    float scl = pow64(1.0f / m);

    float phN = acos_fast(fminf(fmaxf(ny, -1.0f), 1.0f));
    float thN = atan2_fast(nx, -nz);
    float fiN = phN * ((float)NPH / PI_F);
    float tN  = thN * (0.5f / PI_F);
    float fjN = (tN - floorf(tN)) * (float)NTH;

    int iN = (int)fiN; iN = iN > (NPH - 1) ? (NPH - 1) : iN;
    int jN = (int)fjN; jN = jN > (NTH - 1) ? (NTH - 1) : jN;
    float wi = fiN - (float)iN;
    float wj = fjN - (float)jN;

    const float4* Tb = table + (size_t)b * NODESTRIDE;
    int idx = iN * COLS + jN;
    float4 t00 = Tb[idx];
    float4 t01 = Tb[idx + 1];
    float4 t10 = Tb[idx + COLS];
    float4 t11 = Tb[idx + COLS + 1];

    float w00 = (1.0f - wi) * (1.0f - wj);
    float w01 = (1.0f - wi) * wj;
    float w10 = wi * (1.0f - wj);
    float w11 = wi * wj;
    float r0 = t00.x * w00 + t01.x * w01 + t10.x * w10 + t11.x * w11;
    float r1 = t00.y * w00 + t01.y * w01 + t10.y * w10 + t11.y * w11;
    float r2 = t00.z * w00 + t01.z * w01 + t10.z * w10 + t11.z * w11;

    float* ob = out + (size_t)b * 3 * HWPX;
    ob[0 * HWPX + pix_in_b] = r0 * scl;
    ob[1 * HWPX + pix_in_b] = r1 * scl;
    ob[2 * HWPX + pix_in_b] = r2 * scl;
}

// ================= Fallback exact path (R13) for small ws =================
__global__ void k_setup_fb(const float* __restrict__ env,
                           float* __restrict__ tabq) {
    int m = threadIdx.x;
    int p = m >> 5;
    if (p < 1) return;
    float hx, hy, hz, sp;
    light_h(m, hx, hy, hz, sp);
    float c = sp * (1.0f / 60.0f);
    int ms = m - 32;
    int j = ms >> 1;
    int slot = ms & 1;
    #pragma unroll
    for (int b = 0; b < NB; ++b) {
        const float* e = env + ((size_t)(b * NL + m)) * 3;
        float* dst = tabq + ((size_t)(b * NPAIR + j)) * 12 + slot;
        dst[0]  = hx;
        dst[2]  = hy;
        dst[4]  = hz;
        dst[6]  = e[0] * c;
        dst[8]  = e[1] * c;
        dst[10] = e[2] * c;
    }
}

__global__ __launch_bounds__(256) void k_fused_fb(const float* __restrict__ normal,
                                                  const float* __restrict__ tabq,
                                                  float* __restrict__ out,
                                                  float* __restrict__ blockmax) {
    __shared__ float smerge[3 * 64 * 13];
    __shared__ float swmax[4];
    int tid = threadIdx.x, bid = blockIdx.x;
    int bpb = HWPX / 256;
    int b = bid / bpb;
    int g = tid >> 6;
    int li = tid & 63;
    int base_in_b = (bid % bpb) * 256 + li;
    int toff = __builtin_amdgcn_readfirstlane((b * NPAIR + g * GPAIR) * 12);
    const float* Tw = tabq + toff;

    float nxs[4], nys[4], nzs[4];
    #pragma unroll
    for (int k = 0; k < 4; ++k)
        load_normal(normal, (size_t)b * HWPX + base_in_b + k * 64, nxs[k], nys[k], nzs[k]);
    f2 nx2[4], ny2[4], nz2[4];
    #pragma unroll
    for (int k = 0; k < 4; ++k) {
        nx2[k] = f2{nxs[k], nxs[k]};
        ny2[k] = f2{nys[k], nys[k]};
        nz2[k] = f2{nzs[k], nzs[k]};
    }
    float mx64 = 0.0f;
    if (g == 0) {
        #pragma unroll
        for (int k = 0; k < 4; ++k) {
            float s0 = fmaxf((nys[k] + nzs[k]) * INV_SQRT2, 0.0f);
            mx64 = fmaxf(mx64, pow64(s0));
        }
    }
    f2 a0[4], a1[4], a2[4];
    #pragma unroll
    for (int k = 0; k < 4; ++k) { a0[k] = f2{0,0}; a1[k] = f2{0,0}; a2[k] = f2{0,0}; }
    #pragma unroll 4
    for (int j = 0; j < GPAIR; ++j) {
        const f2* P = reinterpret_cast<const f2*>(Tw + j * 12);
        f2 hx2 = P[0], hy2 = P[1], hz2 = P[2];
        f2 e02 = P[3], e12 = P[4], e22 = P[5];
        #pragma unroll
        for (int k = 0; k < 4; ++k) {
            f2 s = __builtin_elementwise_fma(nx2[k], hx2,
                   __builtin_elementwise_fma(ny2[k], hy2, nz2[k] * hz2));
            float sx = fmaxf(s.x, 0.0f);
            float sy = fmaxf(s.y, 0.0f);
            f2 r = {sx, sy};
            f2 r2  = r * r;
            f2 r4  = r2 * r2;
            f2 r8  = r4 * r4;
            f2 r16 = r8 * r8;
            f2 r32 = r16 * r16;
            f2 r64 = r32 * r32;
            mx64 = fmaxf(mx64, fmaxf(r64.x, r64.y));
            a0[k] = __builtin_elementwise_fma(r64, e02, a0[k]);
            a1[k] = __builtin_elementwise_fma(r64, e12, a1[k]);
            a2[k] = __builtin_elementwise_fma(r64, e22, a2[k]);
        }
    }
    float b0[4], b1[4], b2[4];
    #pragma unroll
    for (int k = 0; k < 4; ++k) {
        b0[k] = a0[k].x + a0[k].y;
        b1[k] = a1[k].x + a1[k].y;
        b2[k] = a2[k].x + a2[k].y;
    }
    #pragma unroll
    for (int off = 32; off > 0; off >>= 1)
        mx64 = fmaxf(mx64, __shfl_xor(mx64, off));
    if (li == 0) swmax[g] = mx64;
    if (g > 0) {
        float* dst = smerge + (size_t)(g - 1) * (64 * 13) + li * 13;
        #pragma unroll
        for (int k = 0; k < 4; ++k) {
            dst[k] = b0[k]; dst[k + 4] = b1[k]; dst[k + 8] = b2[k];
        }
    }
    __syncthreads();
    if (tid == 0)
        blockmax[bid] = fmaxf(fmaxf(swmax[0], swmax[1]), fmaxf(swmax[2], swmax[3]));
    if (g == 0) {
        #pragma unroll
        for (int gg = 0; gg < 3; ++gg) {
            const float* src = smerge + (size_t)gg * (64 * 13) + li * 13;
            #pragma unroll
            for (int k = 0; k < 4; ++k) {
                b0[k] += src[k]; b1[k] += src[k + 4]; b2[k] += src[k + 8];
            }
        }
        float* ob = out + (size_t)b * 3 * HWPX;
        #pragma unroll
        for (int k = 0; k < 4; ++k) {
            int p = base_in_b + k * 64;
            ob[0 * HWPX + p] = b0[k];
            ob[1 * HWPX + p] = b1[k];
            ob[2 * HWPX + p] = b2[k];
        }
    }
}

__global__ __launch_bounds__(256) void k_gmax_inv(const float* __restrict__ blockmax,
                                                  float* __restrict__ scale) {
    __shared__ float sm[4];
    int t = threadIdx.x;
    float m = 0.0f;
    #pragma unroll
    for (int i = 0; i < NBLK / 256; ++i)
        m = fmaxf(m, blockmax[t + i * 256]);
    #pragma unroll
    for (int off = 32; off > 0; off >>= 1)
        m = fmaxf(m, __shfl_xor(m, off));
    if ((t & 63) == 0) sm[t >> 6] = m;
    __syncthreads();
    if (t == 0) {
        m = fmaxf(fmaxf(sm[0], sm[1]), fmaxf(sm[2], sm[3]));
        *scale = 1.0f / m;
    }
}

__global__ __launch_bounds__(256) void k_finalize_fb(float* __restrict__ out,
                                                     const float* __restrict__ scale) {
    float scl = *scale;
    int i = blockIdx.x * 256 + (int)threadIdx.x;
    float4* o = reinterpret_cast<float4*>(out);
    float4 v = o[i];
    v.x *= scl; v.y *= scl; v.z *= scl; v.w *= scl;
    o[i] = v;
}

extern "C" void kernel_launch(void* const* d_in, const int* in_sizes, int n_in,
                              void* d_out, int out_size, void* d_ws, size_t ws_size,
                              hipStream_t stream) {
    const float* env    = (const float*)d_in[0];   // (B,16,32,3) f32
    const float* normal = (const float*)d_in[1];   // (B,512,512,3) f32
    float* out = (float*)d_out;                    // (B,3,512,512) f32

    char* ws = (char*)d_ws;

    size_t need = 16384 + (size_t)NB * NODESTRIDE * 16;   // ~280 KB

    if (ws_size >= need) {
        float* blockmax = (float*)(ws + 256);
        float4* table = (float4*)(ws + 16384);
        hipLaunchKernelGGL(k_pre, dim3(NBUILD + NBLK), dim3(256), 0, stream,
                           env, normal, table, blockmax);
        hipLaunchKernelGGL(k_render, dim3(NBLK), dim3(256), 0, stream,
                           normal, table, blockmax, out);
    } else {
        float* scale = (float*)ws;
        float* tabq = (float*)(ws + 256);
        float* blockmax = (float*)(ws + 24576);
        int fblocks = (NB * 3 * HWPX) / (4 * 256);
        hipLaunchKernelGGL(k_setup_fb, dim3(1), dim3(NL), 0, stream, env, tabq);
        hipLaunchKernelGGL(k_fused_fb, dim3(NBLK), dim3(256), 0, stream, normal, tabq, out, blockmax);
        hipLaunchKernelGGL(k_gmax_inv, dim3(1), dim3(256), 0, stream, blockmax, scale);
        hipLaunchKernelGGL(k_finalize_fb, dim3(fblocks), dim3(256), 0, stream, out, scale);
    }
}

// Round 22
// 24.113 us; speedup vs baseline: 3.1052x; 1.0044x over previous
//
#include <hip/hip_runtime.h>
#include <hip/hip_cooperative_groups.h>
#include <math.h>

namespace cg = cooperative_groups;

// Problem constants (match reference)
#define HWPX (512*512)      // pixels per batch
#define NB 2                // batches
#define NL 512              // EH*EW light directions
#define NLS 480             // shadeable lights (phi=0 row: coeff 0)
#define NPAIR 240
#define GPAIR 60
#define NBLK 2048
// radiance-field table (lat-long, lights' (phi,theta) parametrization), 64x128
#define NPH 64
#define NTH 128
#define ROWS (NPH + 1)                 // 65
#define COLS (NTH + 1)                 // 129 (theta wrap duplicate)
#define NODES (ROWS * COLS)            // 8385 per batch
#define BPB_BUILD 132                  // fallback-path build blocks/batch
#define NBUILD (NB * BPB_BUILD)
#define NODESTRIDE (BPB_BUILD * 64)    // 8448
constexpr float PI_F   = 3.14159265358979323846f;
constexpr float TWO_PI = 6.28318530717958647692f;
constexpr float INV_SQRT2 = 0.70710678118654752f;

typedef float f2 __attribute__((ext_vector_type(2)));

// ws layout (bytes), main path:
//   [256]    float blockmax[2048]            (8 KB)
//   [16384]  float4 table[2][NODESTRIDE]     (~270 KB unnormalized radiance field)
//
// R21: ONE cooperative dispatch (2048 blocks, __launch_bounds__(256,8) ->
// VGPR<=64, LDS 12.6KB -> 8 blocks/CU co-resident = exactly 2048).
// Phase 1: build tabL (stride-13 LDS, conflict-free) -> evenly-spread table
// build (each wave 2-3 nodes, per-lane pair gather) -> hvec gen -> candidate
// max + lookup coords (kept in REGISTERS). grid.sync(). Phase 2: blockmax
// reduce -> scale=(1/m)^64 -> 4 taps -> final write. Normals read ONCE.
// Fallbacks: R20 2-dispatch path (occupancy/ws), R13 exact path (tiny ws).

// fast acos (A&S 4.4.45), |err| <= 6.7e-5 rad
__device__ __forceinline__ float acos_fast(float x) {
    float ax = fabsf(x);
    float r = sqrtf(fmaxf(1.0f - ax, 0.0f)) *
              (1.5707288f + ax * (-0.2121144f + ax * (0.0742610f - ax * 0.0187293f)));
    return x >= 0.0f ? r : PI_F - r;
}

// fast atan2(y,x), |err| ~1e-5 rad
__device__ __forceinline__ float atan2_fast(float y, float x) {
    float ay = fabsf(y), ax = fabsf(x);
    float mx = fmaxf(ay, ax), mn = fminf(ay, ax);
    float a = mn / fmaxf(mx, 1e-30f);
    float s = a * a;
    float r = a * (0.9998660f + s * (-0.3302995f + s * (0.1801410f +
              s * (-0.0851330f + s * 0.0208351f))));
    if (ay > ax) r = 1.5707963f - r;
    if (x < 0.0f) r = PI_F - r;
    return y < 0.0f ? -r : r;
}

// unit half-vector (and sin(phi)) for light index m in [0,512)
__device__ __forceinline__ void light_h(int m, float& hx, float& hy, float& hz, float& sp) {
    int p = m >> 5, t = m & 31;
    float phi = (float)p * (PI_F / 16.0f);
    float th  = (float)t * (TWO_PI / 32.0f);
    float spv, cpv, stv, ctv;
    sincosf(phi, &spv, &cpv);
    sincosf(th, &stv, &ctv);
    float x = stv * spv, y = cpv, z = 1.0f - ctv * spv;
    float inv = rsqrtf(x * x + y * y + z * z);
    hx = x * inv; hy = y * inv; hz = z * inv; sp = spv;
}

__device__ __forceinline__ void load_normal(const float* __restrict__ normal, size_t pix,
                                            float& nx, float& ny, float& nz) {
    const float* p = normal + pix * 3;
    float c0 = p[0], c1 = p[1], c2 = p[2];
    float x = (c2 - 0.5f) * 2.0f;
    float y = (c1 - 0.5f) * 2.0f;
    float z = (c0 - 0.5f) * 2.0f;
    float d2 = x * x + y * y + z * z;
    float inv = d2 > 0.0f ? rsqrtf(d2) : 0.0f;
    nx = x * inv; ny = y * inv; nz = z * inv;
}

__device__ __forceinline__ float pow64(float r) {
    float r2  = r * r;
    float r4  = r2 * r2;
    float r8  = r4 * r4;
    float r16 = r8 * r8;
    float r32 = r16 * r16;
    return r32 * r32;
}

// ================= R21 main path: single cooperative kernel =================
__global__ __launch_bounds__(256, 8) void k_coop(const float* __restrict__ env,
                                                 const float* __restrict__ normal,
                                                 float4* __restrict__ table,
                                                 float* __restrict__ blockmax,
                                                 float* __restrict__ out) {
    __shared__ float4 smem4[784];                  // 12544 B, aliased tabL/hvec
    __shared__ float swred[4];
    float* tabL = reinterpret_cast<float*>(smem4); // [240][13] stride-13 (conflict-free)
    float4* sh  = smem4;                           // [512] half-vectors (after build)

    int tid = threadIdx.x, bid = blockIdx.x;
    int pb = bid >> 10;                            // pixel batch
    int pix_in_b = (bid & 1023) * 256 + tid;

    // normal load issued early; carried in regs through phase 1
    float nx, ny, nz;
    load_normal(normal, (size_t)pb * HWPX + pix_in_b, nx, ny, nz);

    // ---- build tabL for this block's table batch ----
    int tb = bid & 1;
    for (int ms = tid; ms < NLS; ms += 256) {
        int m = ms + 32;                           // skip phi=0 row
        float hx, hy, hz, sp;
        light_h(m, hx, hy, hz, sp);
        float c = sp * (1.0f / 60.0f);
        const float* e = env + ((size_t)(tb * NL + m)) * 3;
        float* dst = tabL + (ms >> 1) * 13 + (ms & 1);
        dst[0]  = hx;
        dst[2]  = hy;
        dst[4]  = hz;
        dst[6]  = e[0] * c;
        dst[8]  = e[1] * c;
        dst[10] = e[2] * c;
    }
    __syncthreads();

    // ---- evenly-spread table build: each wave 2-3 nodes ----
    int wid = tid >> 6, lane = tid & 63;
    for (int n = (bid >> 1) + (wid << 10); n < NODES; n += 4096) {
        int i = n / COLS;
        int j = n - i * COLS;
        float phi = (float)i * (PI_F / (float)NPH);
        float th  = (float)j * (TWO_PI / (float)NTH);
        float spv, cpv, stv, ctv;
        sincosf(phi, &spv, &cpv);
        sincosf(th, &stv, &ctv);
        f2 dx2 = f2{stv * spv, stv * spv};
        f2 dy2 = f2{cpv, cpv};
        f2 dz2 = f2{-ctv * spv, -ctv * spv};

        f2 a0 = f2{0, 0}, a1 = f2{0, 0}, a2 = f2{0, 0};
        #pragma unroll
        for (int pp = 0; pp < 4; ++pp) {           // lane-gathered pairs
            int p = lane + pp * 64;
            if (p < NPAIR) {
                const float* T = tabL + p * 13;
                f2 hx2 = {T[0], T[1]}, hy2 = {T[2], T[3]}, hz2 = {T[4], T[5]};
                f2 e02 = {T[6], T[7]}, e12 = {T[8], T[9]}, e22 = {T[10], T[11]};
                f2 s = __builtin_elementwise_fma(dx2, hx2,
                       __builtin_elementwise_fma(dy2, hy2, dz2 * hz2));
                float sx = fmaxf(s.x, 0.0f);
                float sy = fmaxf(s.y, 0.0f);
                f2 r = {sx, sy};
                f2 r2  = r * r;
                f2 r4  = r2 * r2;
                f2 r8  = r4 * r4;
                f2 r16 = r8 * r8;
                f2 r32 = r16 * r16;
                f2 r64 = r32 * r32;
                a0 = __builtin_elementwise_fma(r64, e02, a0);
                a1 = __builtin_elementwise_fma(r64, e12, a1);
                a2 = __builtin_elementwise_fma(r64, e22, a2);
            }
        }
        float b0 = a0.x + a0.y, b1 = a1.x + a1.y, b2 = a2.x + a2.y;
        #pragma unroll
        for (int off = 32; off > 0; off >>= 1) {   // wave sum-reduce
            b0 += __shfl_xor(b0, off);
            b1 += __shfl_xor(b1, off);
            b2 += __shfl_xor(b2, off);
        }
        if (lane == 0) {
            float4 v; v.x = b0; v.y = b1; v.z = b2; v.w = 0.0f;
            table[(size_t)tb * NODESTRIDE + n] = v;
        }
    }
    __syncthreads();

    // ---- hvec gen (overwrites tabL) ----
    for (int m = tid; m < NL; m += 256) {
        float hx, hy, hz, sp;
        light_h(m, hx, hy, hz, sp);
        float4 hv; hv.x = hx; hv.y = hy; hv.z = hz; hv.w = 0.0f;
        sh[m] = hv;
    }
    __syncthreads();

    // ---- candidate max (reflection inversion) ----
    float lx = 2.0f * nz * nx;
    float ly = 2.0f * nz * ny;
    float lz = 2.0f * nz * nz - 1.0f;
    float fi = acos_fast(fminf(fmaxf(ly, -1.0f), 1.0f)) * (16.0f / PI_F);
    float th = atan2_fast(lx, -lz);
    float tt = th * (0.5f / PI_F);
    float fj = (tt - floorf(tt)) * 32.0f;
    int i0 = (int)floorf(fi) - 1;
    int j0 = (int)floorf(fj) - 1;

    float mx = 0.0f;
    #pragma unroll
    for (int di = 0; di < 4; ++di) {
        int i = i0 + di;
        i = i < 0 ? 0 : (i > 15 ? 15 : i);
        #pragma unroll
        for (int dj = 0; dj < 4; ++dj) {
            int j = (j0 + dj) & 31;
            float4 h = sh[i * 32 + j];
            mx = fmaxf(mx, fmaf(nx, h.x, fmaf(ny, h.y, nz * h.z)));
        }
    }
    #pragma unroll
    for (int di = 0; di < 3; ++di) {               // singular ring around (8,0)
        int i = 7 + di;
        #pragma unroll
        for (int dj = 0; dj < 5; ++dj) {
            int j = (30 + dj) & 31;
            float4 h = sh[i * 32 + j];
            mx = fmaxf(mx, fmaf(nx, h.x, fmaf(ny, h.y, nz * h.z)));
        }
    }
    #pragma unroll
    for (int off = 32; off > 0; off >>= 1)
        mx = fmaxf(mx, __shfl_xor(mx, off));
    if ((tid & 63) == 0) swred[tid >> 6] = mx;
    __syncthreads();
    if (tid == 0)
        blockmax[bid] = fmaxf(fmaxf(swred[0], swred[1]), fmaxf(swred[2], swred[3]));

    // ---- lookup coords for phase 2 (registers persist across grid sync) ----
    float phN = acos_fast(fminf(fmaxf(ny, -1.0f), 1.0f));
    float thN = atan2_fast(nx, -nz);
    float fiN = phN * ((float)NPH / PI_F);
    float tN  = thN * (0.5f / PI_F);
    float fjN = (tN - floorf(tN)) * (float)NTH;
    int iN = (int)fiN; iN = iN > (NPH - 1) ? (NPH - 1) : iN;
    int jN = (int)fjN; jN = jN > (NTH - 1) ? (NTH - 1) : jN;
    float wi = fiN - (float)iN;
    float wj = fjN - (float)jN;

    __threadfence();                               // device-scope visibility
    cg::this_grid().sync();

    // ---- render ----
    float m = 0.0f;
    #pragma unroll
    for (int i = 0; i < NBLK / 256; ++i)
        m = fmaxf(m, blockmax[tid + i * 256]);
    #pragma unroll
    for (int off = 32; off > 0; off >>= 1)
        m = fmaxf(m, __shfl_xor(m, off));
    if ((tid & 63) == 0) swred[tid >> 6] = m;
    __syncthreads();
    m = fmaxf(fmaxf(swred[0], swred[1]), fmaxf(swred[2], swred[3]));
    float scl = pow64(1.0f / m);

    const float4* Tb = table + (size_t)pb * NODESTRIDE;
    int idx = iN * COLS + jN;
    float4 t00 = Tb[idx];
    float4 t01 = Tb[idx + 1];
    float4 t10 = Tb[idx + COLS];
    float4 t11 = Tb[idx + COLS + 1];

    float w00 = (1.0f - wi) * (1.0f - wj);
    float w01 = (1.0f - wi) * wj;
    float w10 = wi * (1.0f - wj);
    float w11 = wi * wj;
    float r0 = t00.x * w00 + t01.x * w01 + t10.x * w10 + t11.x * w11;
    float r1 = t00.y * w00 + t01.y * w01 + t10.y * w10 + t11.y * w11;
    float r2 = t00.z * w00 + t01.z * w01 + t10.z * w10 + t11.z * w11;

    float* ob = out + (size_t)pb * 3 * HWPX;
    ob[0 * HWPX + pix_in_b] = r0 * scl;
    ob[1 * HWPX + pix_in_b] = r1 * scl;
    ob[2 * HWPX + pix_in_b] = r2 * scl;
}

// ================= R20 two-dispatch path (occupancy/ws fallback) =================
__global__ __launch_bounds__(256) void k_pre(const float* __restrict__ env,
                                             const float* __restrict__ normal,
                                             float4* __restrict__ table,
                                             float* __restrict__ blockmax) {
    __shared__ float smem[NPAIR * 12];
    int tid = threadIdx.x, bid = blockIdx.x;

    if (bid < NBUILD) {
        float* tabL = smem;
        __shared__ float smerge[3 * 64 * 5];
        int b = bid / BPB_BUILD;
        int blk = bid % BPB_BUILD;
        int g = tid >> 6;
        int li = tid & 63;
        int node = blk * 64 + li;

        for (int ms = tid; ms < NLS; ms += 256) {
            int m = ms + 32;
            float hx, hy, hz, sp;
            light_h(m, hx, hy, hz, sp);
            float c = sp * (1.0f / 60.0f);
            const float* e = env + ((size_t)(b * NL + m)) * 3;
            float* dst = tabL + (ms >> 1) * 12 + (ms & 1);
            dst[0]  = hx;
            dst[2]  = hy;
            dst[4]  = hz;
            dst[6]  = e[0] * c;
            dst[8]  = e[1] * c;
            dst[10] = e[2] * c;
        }

        int i = node / COLS;
        int j = node - i * COLS;
        float phi = (float)i * (PI_F / (float)NPH);
        float th  = (float)j * (TWO_PI / (float)NTH);
        float spv, cpv, stv, ctv;
        sincosf(phi, &spv, &cpv);
        sincosf(th, &stv, &ctv);
        f2 nx2 = f2{stv * spv, stv * spv};
        f2 ny2 = f2{cpv, cpv};
        f2 nz2 = f2{-ctv * spv, -ctv * spv};
        __syncthreads();

        f2 a0 = f2{0, 0}, a1 = f2{0, 0}, a2 = f2{0, 0};
        const float4* Tg = reinterpret_cast<const float4*>(tabL) + (size_t)g * (GPAIR * 3);
        #pragma unroll 4
        for (int jj = 0; jj < GPAIR; ++jj) {
            float4 A = Tg[jj * 3 + 0];
            float4 B = Tg[jj * 3 + 1];
            float4 C = Tg[jj * 3 + 2];
            f2 hx2 = {A.x, A.y}, hy2 = {A.z, A.w}, hz2 = {B.x, B.y};
            f2 e02 = {B.z, B.w}, e12 = {C.x, C.y}, e22 = {C.z, C.w};
            f2 s = __builtin_elementwise_fma(nx2, hx2,
                   __builtin_elementwise_fma(ny2, hy2, nz2 * hz2));
            float sx = fmaxf(s.x, 0.0f);
            float sy = fmaxf(s.y, 0.0f);
            f2 r = {sx, sy};
            f2 r2  = r * r;
            f2 r4  = r2 * r2;
            f2 r8  = r4 * r4;
            f2 r16 = r8 * r8;
            f2 r32 = r16 * r16;
            f2 r64 = r32 * r32;
            a0 = __builtin_elementwise_fma(r64, e02, a0);
            a1 = __builtin_elementwise_fma(r64, e12, a1);
            a2 = __builtin_elementwise_fma(r64, e22, a2);
        }

        float b0 = a0.x + a0.y;
        float b1 = a1.x + a1.y;
        float b2 = a2.x + a2.y;

        if (g > 0) {
            float* dst = smerge + (size_t)(g - 1) * (64 * 5) + li * 5;
            dst[0] = b0; dst[1] = b1; dst[2] = b2;
        }
        __syncthreads();

        if (g == 0) {
            #pragma unroll
            for (int gg = 0; gg < 3; ++gg) {
                const float* src = smerge + (size_t)gg * (64 * 5) + li * 5;
                b0 += src[0]; b1 += src[1]; b2 += src[2];
            }
            if (node < NODES) {
                float4 v; v.x = b0; v.y = b1; v.z = b2; v.w = 0.0f;
                table[(size_t)b * NODESTRIDE + node] = v;
            }
        }
    } else {
        float4* sh = reinterpret_cast<float4*>(smem);
        __shared__ float swmax[4];
        int mbid = bid - NBUILD;
        int b = mbid >> 10;
        int pix_in_b = (mbid & 1023) * 256 + tid;

        for (int m = tid; m < NL; m += 256) {
            float hx, hy, hz, sp;
            light_h(m, hx, hy, hz, sp);
            float4 hv; hv.x = hx; hv.y = hy; hv.z = hz; hv.w = 0.0f;
            sh[m] = hv;
        }

        float nx, ny, nz;
        load_normal(normal, (size_t)b * HWPX + pix_in_b, nx, ny, nz);
        __syncthreads();

        float lx = 2.0f * nz * nx;
        float ly = 2.0f * nz * ny;
        float lz = 2.0f * nz * nz - 1.0f;
        float fi = acos_fast(fminf(fmaxf(ly, -1.0f), 1.0f)) * (16.0f / PI_F);
        float th = atan2_fast(lx, -lz);
        float tt = th * (0.5f / PI_F);
        float fj = (tt - floorf(tt)) * 32.0f;
        int i0 = (int)floorf(fi) - 1;
        int j0 = (int)floorf(fj) - 1;

        float mx = 0.0f;
        #pragma unroll
        for (int di = 0; di < 4; ++di) {
            int i = i0 + di;
            i = i < 0 ? 0 : (i > 15 ? 15 : i);
            #pragma unroll
            for (int dj = 0; dj < 4; ++dj) {
                int j = (j0 + dj) & 31;
                float4 h = sh[i * 32 + j];
                mx = fmaxf(mx, fmaf(nx, h.x, fmaf(ny, h.y, nz * h.z)));
            }
        }
        #pragma unroll
        for (int di = 0; di < 3; ++di) {
            int i = 7 + di;
            #pragma unroll
            for (int dj = 0; dj < 5; ++dj) {
                int j = (30 + dj) & 31;
                float4 h = sh[i * 32 + j];
                mx = fmaxf(mx, fmaf(nx, h.x, fmaf(ny, h.y, nz * h.z)));
            }
        }

        #pragma unroll
        for (int off = 32; off > 0; off >>= 1)
            mx = fmaxf(mx, __shfl_xor(mx, off));
        if ((tid & 63) == 0) swmax[tid >> 6] = mx;
        __syncthreads();
        if (tid == 0)
            blockmax[mbid] = fmaxf(fmaxf(swmax[0], swmax[1]), fmaxf(swmax[2], swmax[3]));
    }
}

__global__ __launch_bounds__(256) void k_render(const float* __restrict__ normal,
                                                const float4* __restrict__ table,
                                                const float* __restrict__ blockmax,
                                                float* __restrict__ out) {
    __shared__ float sred[4];
    int tid = threadIdx.x, bid = blockIdx.x;
    int b = bid >> 10;
    int pix_in_b = (bid & 1023) * 256 + tid;

    float m = 0.0f;
    #pragma unroll
    for (int i = 0; i < NBLK / 256; ++i)
        m = fmaxf(m, blockmax[tid + i * 256]);

    float nx, ny, nz;
    load_normal(normal, (size_t)b * HWPX + pix_in_b, nx, ny, nz);

    #pragma unroll
    for (int off = 32; off > 0; off >>= 1)
        m = fmaxf(m, __shfl_xor(m, off));
    if ((tid & 63) == 0) sred[tid >> 6] = m;
    __syncthreads();
    m = fmaxf(fmaxf(sred[0], sred[1]), fmaxf(sred[2], sred[3]));
    float scl = pow64(1.0f / m);

    float phN = acos_fast(fminf(fmaxf(ny, -1.0f), 1.0f));
    float thN = atan2_fast(nx, -nz);
    float fiN = phN * ((float)NPH / PI_F);
    float tN  = thN * (0.5f / PI_F);
    float fjN = (tN - floorf(tN)) * (float)NTH;

    int iN = (int)fiN; iN = iN > (NPH - 1) ? (NPH - 1) : iN;
    int jN = (int)fjN; jN = jN > (NTH - 1) ? (NTH - 1) : jN;
    float wi = fiN - (float)iN;
    float wj = fjN - (float)jN;

    const float4* Tb = table + (size_t)b * NODESTRIDE;
    int idx = iN * COLS + jN;
    float4 t00 = Tb[idx];
    float4 t01 = Tb[idx + 1];
    float4 t10 = Tb[idx + COLS];
    float4 t11 = Tb[idx + COLS + 1];

    float w00 = (1.0f - wi) * (1.0f - wj);
    float w01 = (1.0f - wi) * wj;
    float w10 = wi * (1.0f - wj);
    float w11 = wi * wj;
    float r0 = t00.x * w00 + t01.x * w01 + t10.x * w10 + t11.x * w11;
    float r1 = t00.y * w00 + t01.y * w01 + t10.y * w10 + t11.y * w11;
    float r2 = t00.z * w00 + t01.z * w01 + t10.z * w10 + t11.z * w11;

    float* ob = out + (size_t)b * 3 * HWPX;
    ob[0 * HWPX + pix_in_b] = r0 * scl;
    ob[1 * HWPX + pix_in_b] = r1 * scl;
    ob[2 * HWPX + pix_in_b] = r2 * scl;
}

// ================= Exact fallback path (R13) for tiny ws =================
__global__ void k_setup_fb(const float* __restrict__ env,
                           float* __restrict__ tabq) {
    int m = threadIdx.x;
    int p = m >> 5;
    if (p < 1) return;
    float hx, hy, hz, sp;
    light_h(m, hx, hy, hz, sp);
    float c = sp * (1.0f / 60.0f);
    int ms = m - 32;
    int j = ms >> 1;
    int slot = ms & 1;
    #pragma unroll
    for (int b = 0; b < NB; ++b) {
        const float* e = env + ((size_t)(b * NL + m)) * 3;
        float* dst = tabq + ((size_t)(b * NPAIR + j)) * 12 + slot;
        dst[0]  = hx;
        dst[2]  = hy;
        dst[4]  = hz;
        dst[6]  = e[0] * c;
        dst[8]  = e[1] * c;
        dst[10] = e[2] * c;
    }
}

__global__ __launch_bounds__(256) void k_fused_fb(const float* __restrict__ normal,
                                                  const float* __restrict__ tabq,
                                                  float* __restrict__ out,
                                                  float* __restrict__ blockmax) {
    __shared__ float smerge[3 * 64 * 13];
    __shared__ float swmax[4];
    int tid = threadIdx.x, bid = blockIdx.x;
    int bpb = HWPX / 256;
    int b = bid / bpb;
    int g = tid >> 6;
    int li = tid & 63;
    int base_in_b = (bid % bpb) * 256 + li;
    int toff = __builtin_amdgcn_readfirstlane((b * NPAIR + g * GPAIR) * 12);
    const float* Tw = tabq + toff;

    float nxs[4], nys[4], nzs[4];
    #pragma unroll
    for (int k = 0; k < 4; ++k)
        load_normal(normal, (size_t)b * HWPX + base_in_b + k * 64, nxs[k], nys[k], nzs[k]);
    f2 nx2[4], ny2[4], nz2[4];
    #pragma unroll
    for (int k = 0; k < 4; ++k) {
        nx2[k] = f2{nxs[k], nxs[k]};
        ny2[k] = f2{nys[k], nys[k]};
        nz2[k] = f2{nzs[k], nzs[k]};
    }
    float mx64 = 0.0f;
    if (g == 0) {
        #pragma unroll
        for (int k = 0; k < 4; ++k) {
            float s0 = fmaxf((nys[k] + nzs[k]) * INV_SQRT2, 0.0f);
            mx64 = fmaxf(mx64, pow64(s0));
        }
    }
    f2 a0[4], a1[4], a2[4];
    #pragma unroll
    for (int k = 0; k < 4; ++k) { a0[k] = f2{0,0}; a1[k] = f2{0,0}; a2[k] = f2{0,0}; }
    #pragma unroll 4
    for (int j = 0; j < GPAIR; ++j) {
        const f2* P = reinterpret_cast<const f2*>(Tw + j * 12);
        f2 hx2 = P[0], hy2 = P[1], hz2 = P[2];
        f2 e02 = P[3], e12 = P[4], e22 = P[5];
        #pragma unroll
        for (int k = 0; k < 4; ++k) {
            f2 s = __builtin_elementwise_fma(nx2[k], hx2,
                   __builtin_elementwise_fma(ny2[k], hy2, nz2[k] * hz2));
            float sx = fmaxf(s.x, 0.0f);
            float sy = fmaxf(s.y, 0.0f);
            f2 r = {sx, sy};
            f2 r2  = r * r;
            f2 r4  = r2 * r2;
            f2 r8  = r4 * r4;
            f2 r16 = r8 * r8;
            f2 r32 = r16 * r16;
            f2 r64 = r32 * r32;
            mx64 = fmaxf(mx64, fmaxf(r64.x, r64.y));
            a0[k] = __builtin_elementwise_fma(r64, e02, a0[k]);
            a1[k] = __builtin_elementwise_fma(r64, e12, a1[k]);
            a2[k] = __builtin_elementwise_fma(r64, e22, a2[k]);
        }
    }
    float b0[4], b1[4], b2[4];
    #pragma unroll
    for (int k = 0; k < 4; ++k) {
        b0[k] = a0[k].x + a0[k].y;
        b1[k] = a1[k].x + a1[k].y;
        b2[k] = a2[k].x + a2[k].y;
    }
    #pragma unroll
    for (int off = 32; off > 0; off >>= 1)
        mx64 = fmaxf(mx64, __shfl_xor(mx64, off));
    if (li == 0) swmax[g] = mx64;
    if (g > 0) {
        float* dst = smerge + (size_t)(g - 1) * (64 * 13) + li * 13;
        #pragma unroll
        for (int k = 0; k < 4; ++k) {
            dst[k] = b0[k]; dst[k + 4] = b1[k]; dst[k + 8] = b2[k];
        }
    }
    __syncthreads();
    if (tid == 0)
        blockmax[bid] = fmaxf(fmaxf(swmax[0], swmax[1]), fmaxf(swmax[2], swmax[3]));
    if (g == 0) {
        #pragma unroll
        for (int gg = 0; gg < 3; ++gg) {
            const float* src = smerge + (size_t)gg * (64 * 13) + li * 13;
            #pragma unroll
            for (int k = 0; k < 4; ++k) {
                b0[k] += src[k]; b1[k] += src[k + 4]; b2[k] += src[k + 8];
            }
        }
        float* ob = out + (size_t)b * 3 * HWPX;
        #pragma unroll
        for (int k = 0; k < 4; ++k) {
            int p = base_in_b + k * 64;
            ob[0 * HWPX + p] = b0[k];
            ob[1 * HWPX + p] = b1[k];
            ob[2 * HWPX + p] = b2[k];
        }
    }
}

__global__ __launch_bounds__(256) void k_gmax_inv(const float* __restrict__ blockmax,
                                                  float* __restrict__ scale) {
    __shared__ float sm[4];
    int t = threadIdx.x;
    float m = 0.0f;
    #pragma unroll
    for (int i = 0; i < NBLK / 256; ++i)
        m = fmaxf(m, blockmax[t + i * 256]);
    #pragma unroll
    for (int off = 32; off > 0; off >>= 1)
        m = fmaxf(m, __shfl_xor(m, off));
    if ((t & 63) == 0) sm[t >> 6] = m;
    __syncthreads();
    if (t == 0) {
        m = fmaxf(fmaxf(sm[0], sm[1]), fmaxf(sm[2], sm[3]));
        *scale = 1.0f / m;
    }
}

__global__ __launch_bounds__(256) void k_finalize_fb(float* __restrict__ out,
                                                     const float* __restrict__ scale) {
    float scl = *scale;
    int i = blockIdx.x * 256 + (int)threadIdx.x;
    float4* o = reinterpret_cast<float4*>(out);
    float4 v = o[i];
    v.x *= scl; v.y *= scl; v.z *= scl; v.w *= scl;
    o[i] = v;
}

extern "C" void kernel_launch(void* const* d_in, const int* in_sizes, int n_in,
                              void* d_out, int out_size, void* d_ws, size_t ws_size,
                              hipStream_t stream) {
    const float* env    = (const float*)d_in[0];   // (B,16,32,3) f32
    const float* normal = (const float*)d_in[1];   // (B,512,512,3) f32
    float* out = (float*)d_out;                    // (B,3,512,512) f32

    char* ws = (char*)d_ws;
    size_t need = 16384 + (size_t)NB * NODESTRIDE * 16;   // ~280 KB

    if (ws_size >= need) {
        float* blockmax = (float*)(ws + 256);
        float4* table = (float4*)(ws + 16384);

        // co-residency check for the cooperative path (host-side query; no stream op)
        int nb = 0;
        hipError_t e = hipOccupancyMaxActiveBlocksPerMultiprocessor(&nb, k_coop, 256, 0);
        bool coop_ok = (e == hipSuccess) && (nb >= 8);    // 8 blocks/CU x 256 CU = 2048

        if (coop_ok) {
            void* args[] = { (void*)&env, (void*)&normal, (void*)&table,
                             (void*)&blockmax, (void*)&out };
            hipLaunchCooperativeKernel((void*)k_coop, dim3(NBLK), dim3(256),
                                       args, 0, stream);
        } else {
            hipLaunchKernelGGL(k_pre, dim3(NBUILD + NBLK), dim3(256), 0, stream,
                               env, normal, table, blockmax);
            hipLaunchKernelGGL(k_render, dim3(NBLK), dim3(256), 0, stream,
                               normal, table, blockmax, out);
        }
    } else {
        float* scale = (float*)ws;
        float* tabq = (float*)(ws + 256);
        float* blockmax = (float*)(ws + 24576);
        int fblocks = (NB * 3 * HWPX) / (4 * 256);
        hipLaunchKernelGGL(k_setup_fb, dim3(1), dim3(NL), 0, stream, env, tabq);
        hipLaunchKernelGGL(k_fused_fb, dim3(NBLK), dim3(256), 0, stream, normal, tabq, out, blockmax);
        hipLaunchKernelGGL(k_gmax_inv, dim3(1), dim3(256), 0, stream, blockmax, scale);
        hipLaunchKernelGGL(k_finalize_fb, dim3(fblocks), dim3(256), 0, stream, out, scale);
    }
}